// Round 6
// baseline (923.190 us; speedup 1.0000x reference)
//
#include <hip/hip_runtime.h>
#include <math.h>

typedef __attribute__((ext_vector_type(8))) short short8;    // 8 x bf16
typedef __attribute__((ext_vector_type(4))) float f32x4;
typedef __attribute__((ext_vector_type(4))) unsigned short u16x4;

#define DEVINL static __device__ __forceinline__
#define MFMA __builtin_amdgcn_mfma_f32_16x16x32_bf16

DEVINL unsigned short f2bf(float f){
  union { float f; unsigned u; } v; v.f = f;
  unsigned r = v.u + 0x7FFFu + ((v.u >> 16) & 1u);   // RNE
  return (unsigned short)(r >> 16);
}
DEVINL float bf2f(unsigned short h){
  union { unsigned u; float f; } v; v.u = ((unsigned)h) << 16;
  return v.f;
}

// B=4, C=QK=V=512, L=4096
__global__ void rowstats_k(const float* __restrict__ x,
                           float* __restrict__ mean, float* __restrict__ rstd){
  int row = blockIdx.x;
  const float4* p = (const float4*)(x + (long)row * 4096);
  float s = 0.f, ss = 0.f;
  for (int i = threadIdx.x; i < 1024; i += 256){
    float4 v = p[i];
    s  += v.x + v.y + v.z + v.w;
    ss += v.x*v.x + v.y*v.y + v.z*v.z + v.w*v.w;
  }
  for (int o = 32; o > 0; o >>= 1){ s += __shfl_down(s, o); ss += __shfl_down(ss, o); }
  __shared__ float ls[4], lss[4];
  int wv = threadIdx.x >> 6;
  if ((threadIdx.x & 63) == 0){ ls[wv] = s; lss[wv] = ss; }
  __syncthreads();
  if (threadIdx.x == 0){
    s = ls[0]+ls[1]+ls[2]+ls[3]; ss = lss[0]+lss[1]+lss[2]+lss[3];
    float m = s * (1.f/4096.f);
    float var = (ss - s*m) * (1.f/4095.f);
    mean[row] = m;
    rstd[row] = 1.f / sqrtf(var + 1e-5f);
  }
}

__global__ void foldw_k(const float* __restrict__ w, const float* __restrict__ bias,
                        const float* __restrict__ mean, const float* __restrict__ rstd,
                        unsigned short* __restrict__ wh, unsigned short* __restrict__ wl,
                        float* __restrict__ biasp){
  int o = blockIdx.x;
  const float* wr = w + (long)o * 512;
  float part = 0.f;
  for (int c = threadIdx.x; c < 512; c += 256){
    float wv = wr[c] * rstd[c];
    unsigned short h = f2bf(wv);
    wh[(o<<9)+c] = h;
    wl[(o<<9)+c] = f2bf(wv - bf2f(h));
    part += wv * mean[c];
  }
  __shared__ float red[256];
  red[threadIdx.x] = part; __syncthreads();
  for (int st = 128; st > 0; st >>= 1){
    if (threadIdx.x < st) red[threadIdx.x] += red[threadIdx.x + st];
    __syncthreads();
  }
  if (threadIdx.x == 0) biasp[o] = bias[o] - red[0];
}

__global__ void wsplit_k(const float* __restrict__ w,
                         unsigned short* __restrict__ wh, unsigned short* __restrict__ wl){
  int i = blockIdx.x * 256 + threadIdx.x;
  float v = w[i];
  unsigned short h = f2bf(v);
  wh[i] = h; wl[i] = f2bf(v - bf2f(h));
}

// ---------- 3-term conv GEMM, pipelined ----------
template<int MODE>
__global__ __launch_bounds__(512) void conv3_k(
    const float* __restrict__ X,
    const unsigned short* __restrict__ Wh, const unsigned short* __restrict__ Wl,
    const float* __restrict__ biasp,
    unsigned short* __restrict__ oh, unsigned short* __restrict__ ol,
    unsigned short* __restrict__ o2h, unsigned short* __restrict__ o2l)
{
  int ob = blockIdx.y, lb = blockIdx.x;
  __shared__ __align__(16) char csm[36864];
  typedef unsigned short (*XT)[64][72];
  XT Xh = (XT)csm;                 // [2][64][72]
  XT Xl = (XT)(csm + 18432);       // [2][64][72]

  int tid = threadIdx.x, w = tid >> 6, lane = tid & 63, lr = lane & 15, lg = lane >> 4;
  const unsigned short* WhB = Wh + (long)(ob*128 + w*16) * 512;
  const unsigned short* WlB = Wl + (long)(ob*128 + w*16) * 512;
  int sl = tid & 63, scg = tid >> 6;
  const float* Xg = X + (long)(scg*8)*4096 + lb*64 + sl;

  f32x4 acc[4] = {};
  float fA[8], fB[8];
  short8 wA0, wA1, wA2, wA3, wB0, wB1, wB2, wB3;

#define CV_XLOAD(F, CB) { _Pragma("unroll") for (int j=0;j<8;++j) F[j] = Xg[(long)((CB)*64 + j)*4096]; }
#define CV_XWRITE(BUF, F) { short8 hv, lv; _Pragma("unroll") for (int j=0;j<8;++j){ \
    unsigned short h_ = f2bf(F[j]); hv[j] = (short)h_; lv[j] = (short)f2bf(F[j] - bf2f(h_)); } \
    *(short8*)&Xh[BUF][sl][scg*8] = hv; *(short8*)&Xl[BUF][sl][scg*8] = lv; }
#define CV_WLOAD(W0,W1,W2,W3, CB) { \
    W0 = *(const short8*)(WhB + (long)lr*512 + (CB)*64 + lg*8); \
    W1 = *(const short8*)(WhB + (long)lr*512 + (CB)*64 + 32 + lg*8); \
    W2 = *(const short8*)(WlB + (long)lr*512 + (CB)*64 + lg*8); \
    W3 = *(const short8*)(WlB + (long)lr*512 + (CB)*64 + 32 + lg*8); }
#define CV_COMPUTE(BUF, W0,W1,W2,W3) { \
    _Pragma("unroll") for (int ct=0;ct<4;++ct){ \
      short8 bh = *(const short8*)&Xh[BUF][ct*16+lr][lg*8]; \
      short8 bl = *(const short8*)&Xl[BUF][ct*16+lr][lg*8]; \
      acc[ct] = MFMA(W0, bh, acc[ct], 0,0,0); \
      acc[ct] = MFMA(W2, bh, acc[ct], 0,0,0); \
      acc[ct] = MFMA(W0, bl, acc[ct], 0,0,0); } \
    _Pragma("unroll") for (int ct=0;ct<4;++ct){ \
      short8 bh = *(const short8*)&Xh[BUF][ct*16+lr][32+lg*8]; \
      short8 bl = *(const short8*)&Xl[BUF][ct*16+lr][32+lg*8]; \
      acc[ct] = MFMA(W1, bh, acc[ct], 0,0,0); \
      acc[ct] = MFMA(W3, bh, acc[ct], 0,0,0); \
      acc[ct] = MFMA(W1, bl, acc[ct], 0,0,0); } }

  CV_XLOAD(fA, 0); CV_XWRITE(0, fA);
  CV_XLOAD(fA, 1);
  CV_WLOAD(wA0,wA1,wA2,wA3, 0);
  __syncthreads();
  for (int cb = 0; cb < 8; cb += 2){
    if (cb+2 < 8) CV_XLOAD(fB, cb+2);
    CV_WLOAD(wB0,wB1,wB2,wB3, cb+1);
    CV_COMPUTE(0, wA0,wA1,wA2,wA3);
    CV_XWRITE(1, fA);
    __syncthreads();
    if (cb+3 < 8) CV_XLOAD(fA, cb+3);
    if (cb+2 < 8) CV_WLOAD(wA0,wA1,wA2,wA3, cb+2);
    CV_COMPUTE(1, wB0,wB1,wB2,wB3);
    if (cb+2 < 8) CV_XWRITE(0, fB);
    __syncthreads();
  }

  int o4 = ob*128 + w*16 + lg*4;
  float bv[4];
  #pragma unroll
  for (int r = 0; r < 4; ++r) bv[r] = biasp[o4 + r];
  if (MODE == 0){
    #pragma unroll
    for (int ct = 0; ct < 4; ++ct){
      u16x4 ph, pl;
      #pragma unroll
      for (int r = 0; r < 4; ++r){
        float y = acc[ct][r] + bv[r];
        unsigned short h = f2bf(y);
        ph[r] = h; pl[r] = f2bf(y - bf2f(h));
      }
      long base = ((long)(lb*64 + ct*16 + lr)) * 512 + o4;
      *(u16x4*)(oh + base) = ph;
      *(u16x4*)(ol + base) = pl;
    }
  } else {
    unsigned short sh_[16], sl_[16], s2h_[16], s2l_[16];
    #pragma unroll
    for (int ct = 0; ct < 4; ++ct)
      #pragma unroll
      for (int r = 0; r < 4; ++r){
        float y = acc[ct][r] + bv[r];
        unsigned short h = f2bf(y);
        float ve = bf2f(h);
        unsigned short l = f2bf(y - ve);
        ve += bf2f(l);
        float v2 = ve * ve;
        unsigned short h2 = f2bf(v2);
        unsigned short l2 = f2bf(v2 - bf2f(h2));
        sh_[ct*4+r] = h; sl_[ct*4+r] = l; s2h_[ct*4+r] = h2; s2l_[ct*4+r] = l2;
      }
    unsigned short* T = (unsigned short*)csm;   // [128][72]
#define CV_STORE(ARR, DST) { \
    __syncthreads(); \
    _Pragma("unroll") for (int ct=0;ct<4;++ct) \
      _Pragma("unroll") for (int r=0;r<4;++r) \
        T[(w*16+lg*4+r)*72 + ct*16+lr] = ARR[ct*4+r]; \
    __syncthreads(); \
    _Pragma("unroll") for (int s_=0;s_<2;++s_){ \
      int slot = tid + s_*512; int row = slot>>3, ch=(slot&7)*8; \
      *(short8*)(DST + (long)(ob*128+row)*4096 + lb*64 + ch) = *(const short8*)&T[row*72+ch]; } }
    CV_STORE(sh_,  oh);
    CV_STORE(sl_,  ol);
    CV_STORE(s2h_, o2h);
    CV_STORE(s2l_, o2l);
#undef CV_STORE
  }
#undef CV_XLOAD
#undef CV_XWRITE
#undef CV_WLOAD
#undef CV_COMPUTE
}

// ---------- 3-term S GEMM, 1-deep reg prefetch over single LDS buffer ----------
__global__ __launch_bounds__(512, 4) void sgemm3_k(
    const unsigned short* __restrict__ Qh, const unsigned short* __restrict__ Ql,
    const unsigned short* __restrict__ Kh, const unsigned short* __restrict__ Kl,
    float* __restrict__ S, int qbase)
{
  int bx = blockIdx.x, by = blockIdx.y;
  int q0g = qbase + bx*128, k0 = by*128;
  __shared__ unsigned short Qhs[128][72], Qls[128][72], Khs[128][72], Kls[128][72];
  int tid = threadIdx.x, w = tid >> 6, lane = tid & 63, lr = lane & 15, lg = lane >> 4;
  int wr = w & 1, wc = w >> 1;
  int row0 = tid >> 3, cgs = (tid & 7)*8;
  const unsigned short* gqh = Qh + (long)(q0g+row0)*512 + cgs;
  const unsigned short* gql = Ql + (long)(q0g+row0)*512 + cgs;
  const unsigned short* gkh = Kh + (long)(k0 +row0)*512 + cgs;
  const unsigned short* gkl = Kl + (long)(k0 +row0)*512 + cgs;
  const long R1 = (long)64*512;
  short8 r0,r1,r2,r3,r4,r5,r6,r7;
  f32x4 acc[4][2] = {};

#define SG_LOAD(CB) { long o_ = (long)(CB)*64; \
    r0 = *(const short8*)(gqh + o_);      r1 = *(const short8*)(gqh + R1 + o_); \
    r2 = *(const short8*)(gql + o_);      r3 = *(const short8*)(gql + R1 + o_); \
    r4 = *(const short8*)(gkh + o_);      r5 = *(const short8*)(gkh + R1 + o_); \
    r6 = *(const short8*)(gkl + o_);      r7 = *(const short8*)(gkl + R1 + o_); }
#define SG_WRITE { \
    *(short8*)&Qhs[row0][cgs] = r0; *(short8*)&Qhs[row0+64][cgs] = r1; \
    *(short8*)&Qls[row0][cgs] = r2; *(short8*)&Qls[row0+64][cgs] = r3; \
    *(short8*)&Khs[row0][cgs] = r4; *(short8*)&Khs[row0+64][cgs] = r5; \
    *(short8*)&Kls[row0][cgs] = r6; *(short8*)&Kls[row0+64][cgs] = r7; }

  SG_LOAD(0); SG_WRITE;
  __syncthreads();
  for (int cb = 0; cb < 8; ++cb){
    if (cb < 7) SG_LOAD(cb+1);
    #pragma unroll
    for (int kk = 0; kk < 2; ++kk){
      short8 bh[2], bl[2];
      #pragma unroll
      for (int bs = 0; bs < 2; ++bs){
        int krow = wc*32 + bs*16 + lr;
        bh[bs] = *(const short8*)(&Khs[krow][kk*32 + lg*8]);
        bl[bs] = *(const short8*)(&Kls[krow][kk*32 + lg*8]);
      }
      #pragma unroll
      for (int as = 0; as < 4; ++as){
        int qrow = wr*64 + as*16 + lr;
        short8 ah = *(const short8*)(&Qhs[qrow][kk*32 + lg*8]);
        short8 al = *(const short8*)(&Qls[qrow][kk*32 + lg*8]);
        #pragma unroll
        for (int bs = 0; bs < 2; ++bs){
          acc[as][bs] = MFMA(ah, bh[bs], acc[as][bs], 0,0,0);
          acc[as][bs] = MFMA(al, bh[bs], acc[as][bs], 0,0,0);
          acc[as][bs] = MFMA(ah, bl[bs], acc[as][bs], 0,0,0);
        }
      }
    }
    __syncthreads();
    if (cb < 7){ SG_WRITE; __syncthreads(); }
  }
#undef SG_LOAD
#undef SG_WRITE
  #pragma unroll
  for (int as = 0; as < 4; ++as){
    #pragma unroll
    for (int bs = 0; bs < 2; ++bs){
      int q = bx*128 + wr*64 + as*16 + lg*4;
      int k = k0 + wc*32 + bs*16 + lr;
      float* Sp = S + (long)q*4096 + k;
      #pragma unroll
      for (int r = 0; r < 4; ++r) Sp[(long)r*4096] = acc[as][bs][r];
    }
  }
}

// ---------- row softmax ----------
__global__ __launch_bounds__(256) void softmax_k(const float* __restrict__ S,
                                                 unsigned short* __restrict__ Pb, long pitch,
                                                 int row0, float* __restrict__ inv2){
  int row = blockIdx.x;
  const float* Sr = S + (long)row * 4096;
  int t = threadIdx.x;
  f32x4 v[4];
  #pragma unroll
  for (int i = 0; i < 4; ++i) v[i] = *(const f32x4*)(Sr + t*4 + i*1024);
  float mx = v[0][0];
  #pragma unroll
  for (int i = 0; i < 4; ++i)
    #pragma unroll
    for (int j = 0; j < 4; ++j) mx = fmaxf(mx, v[i][j]);
  #pragma unroll
  for (int o = 32; o > 0; o >>= 1) mx = fmaxf(mx, __shfl_xor(mx, o));
  __shared__ float red[4];
  int wid = t >> 6;
  if ((t & 63) == 0) red[wid] = mx;
  __syncthreads();
  mx = fmaxf(fmaxf(red[0], red[1]), fmaxf(red[2], red[3]));
  __syncthreads();
  float p[16]; float d = 0.f;
  #pragma unroll
  for (int i = 0; i < 4; ++i)
    #pragma unroll
    for (int j = 0; j < 4; ++j){ float e = expf(v[i][j] - mx); p[i*4+j] = e; d += e; }
  #pragma unroll
  for (int o = 32; o > 0; o >>= 1) d += __shfl_xor(d, o);
  if ((t & 63) == 0) red[wid] = d;
  __syncthreads();
  d = red[0] + red[1] + red[2] + red[3];
  __syncthreads();
  float invd = 1.f / d;
  unsigned short pb[16]; float d2 = 0.f;
  #pragma unroll
  for (int i = 0; i < 16; ++i){ pb[i] = f2bf(p[i] * invd); d2 += bf2f(pb[i]); }
  #pragma unroll
  for (int o = 32; o > 0; o >>= 1) d2 += __shfl_xor(d2, o);
  if ((t & 63) == 0) red[wid] = d2;
  __syncthreads();
  if (t == 0) inv2[row0 + row] = 1.f / (red[0]+red[1]+red[2]+red[3]);
  unsigned short* Pr = Pb + (long)(row0 + row) * pitch;
  #pragma unroll
  for (int i = 0; i < 4; ++i){
    u16x4 pk;
    #pragma unroll
    for (int j = 0; j < 4; ++j) pk[j] = pb[i*4+j];
    *(u16x4*)(Pr + t*4 + i*1024) = pk;
  }
}

// ---------- PV GEMM + epilogue ----------
// tile 128q x 64vc, k-step 32; wave = 32q x 32vc, FULL k (no cross-wave reduce).
// LDS 61.4 KB -> 2 blocks/CU. 2-deep reg prefetch + double-buffered LDS.
__global__ __launch_bounds__(512, 4) void pv2_k(
    const unsigned short* __restrict__ P, long ppitch,
    const unsigned short* __restrict__ vh, const unsigned short* __restrict__ vl,
    const unsigned short* __restrict__ v2h, const unsigned short* __restrict__ v2l,
    const float* __restrict__ inv2,
    const float* __restrict__ cx, const float* __restrict__ mcx, const float* __restrict__ rcx,
    float* __restrict__ outb, int qP_base, int qG_base)
{
  __shared__ __align__(16) char smem[61440];            // 60 KB
  typedef unsigned short (*PlT)[128][40];               // Pl[2][128][40] : 20480 B
  typedef unsigned short (*VlT)[4][64][40];             // Vl[2][4][64][40] : 40960 B
  PlT Pl = (PlT)smem;
  VlT Vl = (VlT)(smem + 20480);

  int tid = threadIdx.x;
  int l = tid & 63, w = tid >> 6;
  int wq = w >> 1, wv = w & 1;       // wave owns q rows wq*32+, vc cols wv*32+
  int lr = l & 15, lg = l >> 4;
  int qP0 = qP_base + blockIdx.x*128, qG0 = qG_base + blockIdx.x*128;
  int vc0 = blockIdx.y*64;

  // staging roles
  int prow = tid >> 2, pc8 = (tid & 3)*8;               // P: 128 rows x 4 chunks
  const unsigned short* pg = P + (long)(qP0 + prow)*ppitch + pc8;
  int varr = tid >> 7;                                  // 0..3 (wave-uniform)
  int vs = tid & 127;
  int vrow = vs >> 2, vc8 = (vs & 3)*8;                 // rows 0..31 (+32 second)
  const unsigned short* vgp =
      (varr==0 ? vh : varr==1 ? vl : varr==2 ? v2h : v2l)
      + (long)(vc0 + vrow)*4096 + vc8;
  const unsigned short* vgp2 = vgp + (long)32*4096;

  f32x4 accM[2][2] = {}, acc2[2][2] = {};
  short8 pA, v1A, v2A, pB, v1B, v2B;

#define PV_LOAD(PR, V1, V2, TT) { long ko_ = (long)(TT)*32; \
    PR = *(const short8*)(pg + ko_); \
    V1 = *(const short8*)(vgp + ko_); \
    V2 = *(const short8*)(vgp2 + ko_); }
#define PV_WRITE(BUF, PR, V1, V2) { \
    *(short8*)&Pl[BUF][prow][pc8] = PR; \
    *(short8*)&Vl[BUF][varr][vrow][vc8] = V1; \
    *(short8*)&Vl[BUF][varr][vrow+32][vc8] = V2; }
#define PV_COMPUTE(BUF) { \
    short8 fh[2], fl_[2], f2h_[2], f2l_[2]; \
    _Pragma("unroll") for (int bs = 0; bs < 2; ++bs){ \
      int vr = wv*32 + bs*16 + lr; \
      fh[bs]   = *(const short8*)(&Vl[BUF][0][vr][lg*8]); \
      fl_[bs]  = *(const short8*)(&Vl[BUF][1][vr][lg*8]); \
      f2h_[bs] = *(const short8*)(&Vl[BUF][2][vr][lg*8]); \
      f2l_[bs] = *(const short8*)(&Vl[BUF][3][vr][lg*8]); } \
    _Pragma("unroll") for (int aq = 0; aq < 2; ++aq){ \
      short8 pa = *(const short8*)(&Pl[BUF][wq*32 + aq*16 + lr][lg*8]); \
      _Pragma("unroll") for (int bs = 0; bs < 2; ++bs){ \
        accM[aq][bs] = MFMA(pa, fh[bs],   accM[aq][bs], 0,0,0); \
        accM[aq][bs] = MFMA(pa, fl_[bs],  accM[aq][bs], 0,0,0); \
        acc2[aq][bs] = MFMA(pa, f2h_[bs], acc2[aq][bs], 0,0,0); \
        acc2[aq][bs] = MFMA(pa, f2l_[bs], acc2[aq][bs], 0,0,0); } } }

  // prologue: tile0 -> LDS0 ; tile1 -> regs A
  PV_LOAD(pA, v1A, v2A, 0);
  PV_WRITE(0, pA, v1A, v2A);
  PV_LOAD(pA, v1A, v2A, 1);
  __syncthreads();

  for (int t = 0; t < 128; t += 2){
    if (t+2 < 128) PV_LOAD(pB, v1B, v2B, t+2);
    PV_COMPUTE(0);
    PV_WRITE(1, pA, v1A, v2A);
    __syncthreads();
    if (t+3 < 128) PV_LOAD(pA, v1A, v2A, t+3);
    PV_COMPUTE(1);
    if (t+2 < 128) PV_WRITE(0, pB, v1B, v2B);
    __syncthreads();
  }
#undef PV_LOAD
#undef PV_WRITE
#undef PV_COMPUTE

  // ---- epilogue: two one-array transposes ([64][132] = 33.8 KB scratch) ----
  float* Tm = (float*)smem;
  // pass 1: M
  #pragma unroll
  for (int aq = 0; aq < 2; ++aq)
    #pragma unroll
    for (int bs = 0; bs < 2; ++bs){
      int vcl = wv*32 + bs*16 + lr;
      int ql  = wq*32 + aq*16 + lg*4;
      #pragma unroll
      for (int r = 0; r < 4; ++r) Tm[vcl*132 + ql + r] = accM[aq][bs][r];
    }
  __syncthreads();
  f32x4 Mv[4];
  #pragma unroll
  for (int p = 0; p < 4; ++p){
    int chunk = tid + p*512;
    int row = chunk >> 5, c4 = (chunk & 31)*4;
    Mv[p] = *(const f32x4*)&Tm[row*132 + c4];
  }
  __syncthreads();
  // pass 2: M2
  #pragma unroll
  for (int aq = 0; aq < 2; ++aq)
    #pragma unroll
    for (int bs = 0; bs < 2; ++bs){
      int vcl = wv*32 + bs*16 + lr;
      int ql  = wq*32 + aq*16 + lg*4;
      #pragma unroll
      for (int r = 0; r < 4; ++r) Tm[vcl*132 + ql + r] = acc2[aq][bs][r];
    }
  __syncthreads();
  #pragma unroll
  for (int p = 0; p < 4; ++p){
    int chunk = tid + p*512;
    int row = chunk >> 5, c4 = (chunk & 31)*4;
    float mu = mcx[vc0 + row], rs = rcx[vc0 + row];
    f32x4 t2 = *(const f32x4*)&Tm[row*132 + c4];
    f32x4 iv = *(const f32x4*)&inv2[qP0 + c4];
    f32x4 cv = *(const f32x4*)&cx[(long)(vc0+row)*4096 + qG0 + c4];
    f32x4 ov;
    #pragma unroll
    for (int j = 0; j < 4; ++j){
      float M = Mv[p][j]*iv[j], M2 = t2[j]*iv[j];
      float var = M2 - M*M;
      float sd = sqrtf(fmaxf(var, 0.f));
      ov[j] = sd*(cv[j]-mu)*rs + M;
    }
    *(f32x4*)&outb[(long)(vc0+row)*4096 + qG0 + c4] = ov;
  }
}

// ---------- launch ----------
extern "C" void kernel_launch(void* const* d_in, const int* in_sizes, int n_in,
                              void* d_out, int out_size, void* d_ws, size_t ws_size,
                              hipStream_t stream){
  const float* c_x  = (const float*)d_in[0];
  const float* s_x  = (const float*)d_in[1];
  const float* c_1x = (const float*)d_in[2];
  const float* s_1x = (const float*)d_in[3];
  const float* f_w  = (const float*)d_in[4];
  const float* f_b  = (const float*)d_in[5];
  const float* g_w  = (const float*)d_in[6];
  const float* g_b  = (const float*)d_in[7];
  const float* h_w  = (const float*)d_in[8];
  const float* h_b  = (const float*)d_in[9];
  float* out = (float*)d_out;

  char* ws = (char*)d_ws;
  size_t off = 0;
  auto alloc = [&](size_t bytes)->void*{
    void* p = ws + off; off += (bytes + 255) & ~(size_t)255; return p;
  };
  float* meanQ = (float*)alloc(2048*4); float* rstdQ = (float*)alloc(2048*4);
  float* meanK = (float*)alloc(2048*4); float* rstdK = (float*)alloc(2048*4);
  float* meanC = (float*)alloc(2048*4); float* rstdC = (float*)alloc(2048*4);
  float* biasF = (float*)alloc(512*4);  float* biasG = (float*)alloc(512*4);
  unsigned short* Wfh = (unsigned short*)alloc((size_t)512*512*2);
  unsigned short* Wfl = (unsigned short*)alloc((size_t)512*512*2);
  unsigned short* Wgh = (unsigned short*)alloc((size_t)512*512*2);
  unsigned short* Wgl = (unsigned short*)alloc((size_t)512*512*2);
  unsigned short* Whh = (unsigned short*)alloc((size_t)512*512*2);
  unsigned short* Whl = (unsigned short*)alloc((size_t)512*512*2);
  unsigned short* Qh = (unsigned short*)alloc((size_t)4096*512*2);
  unsigned short* Ql = (unsigned short*)alloc((size_t)4096*512*2);
  unsigned short* Kh = (unsigned short*)alloc((size_t)4096*512*2);
  unsigned short* Kl = (unsigned short*)alloc((size_t)4096*512*2);
  unsigned short* vh  = (unsigned short*)alloc((size_t)512*4096*2);
  unsigned short* vl  = (unsigned short*)alloc((size_t)512*4096*2);
  unsigned short* v2h = (unsigned short*)alloc((size_t)512*4096*2);
  unsigned short* v2l = (unsigned short*)alloc((size_t)512*4096*2);
  float* S    = (float*)alloc((size_t)2048*4096*4);   // fp32 S chunk
  float* inv2 = (float*)alloc(4096*4);

  size_t pbytes = (size_t)4096*4096*2;
  bool bigP = (off + pbytes + 256 <= ws_size);
  unsigned short* Pb; long ppitch;
  if (bigP){ Pb = (unsigned short*)alloc(pbytes); ppitch = 4096; }
  else     { Pb = (unsigned short*)S;             ppitch = 8192; }

  rowstats_k<<<2048, 256, 0, stream>>>(c_1x, meanQ, rstdQ);
  rowstats_k<<<2048, 256, 0, stream>>>(s_1x, meanK, rstdK);
  rowstats_k<<<2048, 256, 0, stream>>>(c_x,  meanC, rstdC);
  wsplit_k<<<1024, 256, 0, stream>>>(h_w, Whh, Whl);

  for (int b = 0; b < 4; ++b){
    long xoff = (long)b * 512 * 4096;
    foldw_k<<<512, 256, 0, stream>>>(f_w, f_b, meanQ + b*512, rstdQ + b*512, Wfh, Wfl, biasF);
    foldw_k<<<512, 256, 0, stream>>>(g_w, g_b, meanK + b*512, rstdK + b*512, Wgh, Wgl, biasG);
    conv3_k<0><<<dim3(64,4), 512, 0, stream>>>(c_1x + xoff, Wfh, Wfl, biasF, Qh, Ql, nullptr, nullptr);
    conv3_k<0><<<dim3(64,4), 512, 0, stream>>>(s_1x + xoff, Wgh, Wgl, biasG, Kh, Kl, nullptr, nullptr);
    conv3_k<1><<<dim3(64,4), 512, 0, stream>>>(s_x + xoff, Whh, Whl, h_b, vh, vl, v2h, v2l);
    if (bigP){
      for (int ch = 0; ch < 2; ++ch){
        int qbase = ch * 2048;
        sgemm3_k<<<dim3(16,32), 512, 0, stream>>>(Qh, Ql, Kh, Kl, S, qbase);
        softmax_k<<<2048, 256, 0, stream>>>(S, Pb, 4096, qbase, inv2);
      }
      pv2_k<<<dim3(32,8), 512, 0, stream>>>(Pb, 4096, vh, vl, v2h, v2l, inv2,
                                            c_x + xoff, meanC + b*512, rstdC + b*512,
                                            out + xoff, 0, 0);
    } else {
      for (int ch = 0; ch < 2; ++ch){
        int qbase = ch * 2048;
        sgemm3_k<<<dim3(16,32), 512, 0, stream>>>(Qh, Ql, Kh, Kl, S, qbase);
        softmax_k<<<2048, 256, 0, stream>>>(S, Pb, 8192, 0, inv2);
        pv2_k<<<dim3(16,8), 512, 0, stream>>>(Pb, 8192, vh, vl, v2h, v2l, inv2,
                                              c_x + xoff, meanC + b*512, rstdC + b*512,
                                              out + xoff, 0, qbase);
      }
    }
  }
}

// Round 7
// 828.766 us; speedup vs baseline: 1.1139x; 1.1139x over previous
//
#include <hip/hip_runtime.h>
#include <math.h>

typedef __attribute__((ext_vector_type(8))) short short8;    // 8 x bf16
typedef __attribute__((ext_vector_type(4))) float f32x4;
typedef __attribute__((ext_vector_type(4))) unsigned short u16x4;

#define DEVINL static __device__ __forceinline__
#define MFMA __builtin_amdgcn_mfma_f32_16x16x32_bf16

DEVINL unsigned short f2bf(float f){
  union { float f; unsigned u; } v; v.f = f;
  unsigned r = v.u + 0x7FFFu + ((v.u >> 16) & 1u);   // RNE
  return (unsigned short)(r >> 16);
}
DEVINL float bf2f(unsigned short h){
  union { unsigned u; float f; } v; v.u = ((unsigned)h) << 16;
  return v.f;
}

// B=4, C=QK=V=512, L=4096
__global__ void rowstats_k(const float* __restrict__ x,
                           float* __restrict__ mean, float* __restrict__ rstd){
  int row = blockIdx.x;
  const float4* p = (const float4*)(x + (long)row * 4096);
  float s = 0.f, ss = 0.f;
  for (int i = threadIdx.x; i < 1024; i += 256){
    float4 v = p[i];
    s  += v.x + v.y + v.z + v.w;
    ss += v.x*v.x + v.y*v.y + v.z*v.z + v.w*v.w;
  }
  for (int o = 32; o > 0; o >>= 1){ s += __shfl_down(s, o); ss += __shfl_down(ss, o); }
  __shared__ float ls[4], lss[4];
  int wv = threadIdx.x >> 6;
  if ((threadIdx.x & 63) == 0){ ls[wv] = s; lss[wv] = ss; }
  __syncthreads();
  if (threadIdx.x == 0){
    s = ls[0]+ls[1]+ls[2]+ls[3]; ss = lss[0]+lss[1]+lss[2]+lss[3];
    float m = s * (1.f/4096.f);
    float var = (ss - s*m) * (1.f/4095.f);
    mean[row] = m;
    rstd[row] = 1.f / sqrtf(var + 1e-5f);
  }
}

__global__ void foldw_k(const float* __restrict__ w, const float* __restrict__ bias,
                        const float* __restrict__ mean, const float* __restrict__ rstd,
                        unsigned short* __restrict__ wh, unsigned short* __restrict__ wl,
                        float* __restrict__ biasp){
  int o = blockIdx.x;
  const float* wr = w + (long)o * 512;
  float part = 0.f;
  for (int c = threadIdx.x; c < 512; c += 256){
    float wv = wr[c] * rstd[c];
    unsigned short h = f2bf(wv);
    wh[(o<<9)+c] = h;
    wl[(o<<9)+c] = f2bf(wv - bf2f(h));
    part += wv * mean[c];
  }
  __shared__ float red[256];
  red[threadIdx.x] = part; __syncthreads();
  for (int st = 128; st > 0; st >>= 1){
    if (threadIdx.x < st) red[threadIdx.x] += red[threadIdx.x + st];
    __syncthreads();
  }
  if (threadIdx.x == 0) biasp[o] = bias[o] - red[0];
}

__global__ void wsplit_k(const float* __restrict__ w,
                         unsigned short* __restrict__ wh, unsigned short* __restrict__ wl){
  int i = blockIdx.x * 256 + threadIdx.x;
  float v = w[i];
  unsigned short h = f2bf(v);
  wh[i] = h; wl[i] = f2bf(v - bf2f(h));
}

// ---------- 3-term conv GEMM, pipelined ----------
template<int MODE>
__global__ __launch_bounds__(512) void conv3_k(
    const float* __restrict__ X,
    const unsigned short* __restrict__ Wh, const unsigned short* __restrict__ Wl,
    const float* __restrict__ biasp,
    unsigned short* __restrict__ oh, unsigned short* __restrict__ ol,
    unsigned short* __restrict__ o2h, unsigned short* __restrict__ o2l)
{
  int ob = blockIdx.y, lb = blockIdx.x;
  __shared__ __align__(16) char csm[36864];
  typedef unsigned short (*XT)[64][72];
  XT Xh = (XT)csm;                 // [2][64][72]
  XT Xl = (XT)(csm + 18432);       // [2][64][72]

  int tid = threadIdx.x, w = tid >> 6, lane = tid & 63, lr = lane & 15, lg = lane >> 4;
  const unsigned short* WhB = Wh + (long)(ob*128 + w*16) * 512;
  const unsigned short* WlB = Wl + (long)(ob*128 + w*16) * 512;
  int sl = tid & 63, scg = tid >> 6;
  const float* Xg = X + (long)(scg*8)*4096 + lb*64 + sl;

  f32x4 acc[4] = {};
  float fA[8], fB[8];
  short8 wA0, wA1, wA2, wA3, wB0, wB1, wB2, wB3;

#define CV_XLOAD(F, CB) { _Pragma("unroll") for (int j=0;j<8;++j) F[j] = Xg[(long)((CB)*64 + j)*4096]; }
#define CV_XWRITE(BUF, F) { short8 hv, lv; _Pragma("unroll") for (int j=0;j<8;++j){ \
    unsigned short h_ = f2bf(F[j]); hv[j] = (short)h_; lv[j] = (short)f2bf(F[j] - bf2f(h_)); } \
    *(short8*)&Xh[BUF][sl][scg*8] = hv; *(short8*)&Xl[BUF][sl][scg*8] = lv; }
#define CV_WLOAD(W0,W1,W2,W3, CB) { \
    W0 = *(const short8*)(WhB + (long)lr*512 + (CB)*64 + lg*8); \
    W1 = *(const short8*)(WhB + (long)lr*512 + (CB)*64 + 32 + lg*8); \
    W2 = *(const short8*)(WlB + (long)lr*512 + (CB)*64 + lg*8); \
    W3 = *(const short8*)(WlB + (long)lr*512 + (CB)*64 + 32 + lg*8); }
#define CV_COMPUTE(BUF, W0,W1,W2,W3) { \
    _Pragma("unroll") for (int ct=0;ct<4;++ct){ \
      short8 bh = *(const short8*)&Xh[BUF][ct*16+lr][lg*8]; \
      short8 bl = *(const short8*)&Xl[BUF][ct*16+lr][lg*8]; \
      acc[ct] = MFMA(W0, bh, acc[ct], 0,0,0); \
      acc[ct] = MFMA(W2, bh, acc[ct], 0,0,0); \
      acc[ct] = MFMA(W0, bl, acc[ct], 0,0,0); } \
    _Pragma("unroll") for (int ct=0;ct<4;++ct){ \
      short8 bh = *(const short8*)&Xh[BUF][ct*16+lr][32+lg*8]; \
      short8 bl = *(const short8*)&Xl[BUF][ct*16+lr][32+lg*8]; \
      acc[ct] = MFMA(W1, bh, acc[ct], 0,0,0); \
      acc[ct] = MFMA(W3, bh, acc[ct], 0,0,0); \
      acc[ct] = MFMA(W1, bl, acc[ct], 0,0,0); } }

  CV_XLOAD(fA, 0); CV_XWRITE(0, fA);
  CV_XLOAD(fA, 1);
  CV_WLOAD(wA0,wA1,wA2,wA3, 0);
  __syncthreads();
  for (int cb = 0; cb < 8; cb += 2){
    if (cb+2 < 8) CV_XLOAD(fB, cb+2);
    CV_WLOAD(wB0,wB1,wB2,wB3, cb+1);
    CV_COMPUTE(0, wA0,wA1,wA2,wA3);
    CV_XWRITE(1, fA);
    __syncthreads();
    if (cb+3 < 8) CV_XLOAD(fA, cb+3);
    if (cb+2 < 8) CV_WLOAD(wA0,wA1,wA2,wA3, cb+2);
    CV_COMPUTE(1, wB0,wB1,wB2,wB3);
    if (cb+2 < 8) CV_XWRITE(0, fB);
    __syncthreads();
  }

  int o4 = ob*128 + w*16 + lg*4;
  float bv[4];
  #pragma unroll
  for (int r = 0; r < 4; ++r) bv[r] = biasp[o4 + r];
  if (MODE == 0){
    #pragma unroll
    for (int ct = 0; ct < 4; ++ct){
      u16x4 ph, pl;
      #pragma unroll
      for (int r = 0; r < 4; ++r){
        float y = acc[ct][r] + bv[r];
        unsigned short h = f2bf(y);
        ph[r] = h; pl[r] = f2bf(y - bf2f(h));
      }
      long base = ((long)(lb*64 + ct*16 + lr)) * 512 + o4;
      *(u16x4*)(oh + base) = ph;
      *(u16x4*)(ol + base) = pl;
    }
  } else {
    unsigned short sh_[16], sl_[16], s2h_[16], s2l_[16];
    #pragma unroll
    for (int ct = 0; ct < 4; ++ct)
      #pragma unroll
      for (int r = 0; r < 4; ++r){
        float y = acc[ct][r] + bv[r];
        unsigned short h = f2bf(y);
        float ve = bf2f(h);
        unsigned short l = f2bf(y - ve);
        ve += bf2f(l);
        float v2 = ve * ve;
        unsigned short h2 = f2bf(v2);
        unsigned short l2 = f2bf(v2 - bf2f(h2));
        sh_[ct*4+r] = h; sl_[ct*4+r] = l; s2h_[ct*4+r] = h2; s2l_[ct*4+r] = l2;
      }
    unsigned short* T = (unsigned short*)csm;   // [128][72]
#define CV_STORE(ARR, DST) { \
    __syncthreads(); \
    _Pragma("unroll") for (int ct=0;ct<4;++ct) \
      _Pragma("unroll") for (int r=0;r<4;++r) \
        T[(w*16+lg*4+r)*72 + ct*16+lr] = ARR[ct*4+r]; \
    __syncthreads(); \
    _Pragma("unroll") for (int s_=0;s_<2;++s_){ \
      int slot = tid + s_*512; int row = slot>>3, ch=(slot&7)*8; \
      *(short8*)(DST + (long)(ob*128+row)*4096 + lb*64 + ch) = *(const short8*)&T[row*72+ch]; } }
    CV_STORE(sh_,  oh);
    CV_STORE(sl_,  ol);
    CV_STORE(s2h_, o2h);
    CV_STORE(s2l_, o2l);
#undef CV_STORE
  }
#undef CV_XLOAD
#undef CV_XWRITE
#undef CV_WLOAD
#undef CV_COMPUTE
}

// ---------- 3-term S GEMM: 128q x 256k tile, wave = 64x64 (as=4 x bs=4) ----------
// LDS 108 KB single-buffered; 1-deep register prefetch; grid 256 blocks (1/CU).
__global__ __launch_bounds__(512) void sgemm3_k(
    const unsigned short* __restrict__ Qh, const unsigned short* __restrict__ Ql,
    const unsigned short* __restrict__ Kh, const unsigned short* __restrict__ Kl,
    float* __restrict__ S, int qbase)
{
  int bx = blockIdx.x, by = blockIdx.y;
  int q0g = qbase + bx*128, k0 = by*256;
  __shared__ unsigned short Qhs[128][72], Qls[128][72];
  __shared__ unsigned short Khs[256][72], Kls[256][72];
  int tid = threadIdx.x, w = tid >> 6, lane = tid & 63, lr = lane & 15, lg = lane >> 4;
  int wr = w & 1, wc = w >> 1;            // wr: q-half (64), wc: k-quarter (64)
  int srow = tid >> 3, sch = (tid & 7)*8; // staging: 64 rows x 8 chunks per 512-slot pass
  short8 qr[4], kr[8];
  f32x4 acc[4][4] = {};

#define SG_LOAD(CB) { long c0_ = (long)(CB)*64 + sch; \
    _Pragma("unroll") for (int i = 0; i < 4; ++i){ \
      const unsigned short* src = (i < 2 ? Qh : Ql); \
      qr[i] = *(const short8*)(src + (long)(q0g + srow + (i&1)*64)*512 + c0_); } \
    _Pragma("unroll") for (int i = 0; i < 8; ++i){ \
      const unsigned short* src = (i < 4 ? Kh : Kl); \
      kr[i] = *(const short8*)(src + (long)(k0 + srow + (i&3)*64)*512 + c0_); } }
#define SG_WRITE { \
    _Pragma("unroll") for (int i = 0; i < 4; ++i){ \
      if (i < 2) *(short8*)&Qhs[srow + (i&1)*64][sch] = qr[i]; \
      else       *(short8*)&Qls[srow + (i&1)*64][sch] = qr[i]; } \
    _Pragma("unroll") for (int i = 0; i < 8; ++i){ \
      if (i < 4) *(short8*)&Khs[srow + (i&3)*64][sch] = kr[i]; \
      else       *(short8*)&Kls[srow + (i&3)*64][sch] = kr[i]; } }

  SG_LOAD(0); SG_WRITE;
  __syncthreads();
  for (int cb = 0; cb < 8; ++cb){
    if (cb < 7) SG_LOAD(cb+1);
    #pragma unroll
    for (int kk = 0; kk < 2; ++kk){
      short8 bh[4], bl[4];
      #pragma unroll
      for (int bs = 0; bs < 4; ++bs){
        int krow = wc*64 + bs*16 + lr;
        bh[bs] = *(const short8*)(&Khs[krow][kk*32 + lg*8]);
        bl[bs] = *(const short8*)(&Kls[krow][kk*32 + lg*8]);
      }
      #pragma unroll
      for (int as = 0; as < 4; ++as){
        int qrow = wr*64 + as*16 + lr;
        short8 ah = *(const short8*)(&Qhs[qrow][kk*32 + lg*8]);
        short8 al = *(const short8*)(&Qls[qrow][kk*32 + lg*8]);
        #pragma unroll
        for (int bs = 0; bs < 4; ++bs){
          acc[as][bs] = MFMA(ah, bh[bs], acc[as][bs], 0,0,0);
          acc[as][bs] = MFMA(al, bh[bs], acc[as][bs], 0,0,0);
          acc[as][bs] = MFMA(ah, bl[bs], acc[as][bs], 0,0,0);
        }
      }
    }
    __syncthreads();
    if (cb < 7){ SG_WRITE; __syncthreads(); }
  }
#undef SG_LOAD
#undef SG_WRITE
  #pragma unroll
  for (int as = 0; as < 4; ++as){
    #pragma unroll
    for (int bs = 0; bs < 4; ++bs){
      int q = bx*128 + wr*64 + as*16 + lg*4;
      int k = k0 + wc*64 + bs*16 + lr;
      float* Sp = S + (long)q*4096 + k;
      #pragma unroll
      for (int r = 0; r < 4; ++r) Sp[(long)r*4096] = acc[as][bs][r];
    }
  }
}

// ---------- row softmax ----------
__global__ __launch_bounds__(256) void softmax_k(const float* __restrict__ S,
                                                 unsigned short* __restrict__ Pb, long pitch,
                                                 int row0, float* __restrict__ inv2){
  int row = blockIdx.x;
  const float* Sr = S + (long)row * 4096;
  int t = threadIdx.x;
  f32x4 v[4];
  #pragma unroll
  for (int i = 0; i < 4; ++i) v[i] = *(const f32x4*)(Sr + t*4 + i*1024);
  float mx = v[0][0];
  #pragma unroll
  for (int i = 0; i < 4; ++i)
    #pragma unroll
    for (int j = 0; j < 4; ++j) mx = fmaxf(mx, v[i][j]);
  #pragma unroll
  for (int o = 32; o > 0; o >>= 1) mx = fmaxf(mx, __shfl_xor(mx, o));
  __shared__ float red[4];
  int wid = t >> 6;
  if ((t & 63) == 0) red[wid] = mx;
  __syncthreads();
  mx = fmaxf(fmaxf(red[0], red[1]), fmaxf(red[2], red[3]));
  __syncthreads();
  float p[16]; float d = 0.f;
  #pragma unroll
  for (int i = 0; i < 4; ++i)
    #pragma unroll
    for (int j = 0; j < 4; ++j){ float e = expf(v[i][j] - mx); p[i*4+j] = e; d += e; }
  #pragma unroll
  for (int o = 32; o > 0; o >>= 1) d += __shfl_xor(d, o);
  if ((t & 63) == 0) red[wid] = d;
  __syncthreads();
  d = red[0] + red[1] + red[2] + red[3];
  __syncthreads();
  float invd = 1.f / d;
  unsigned short pb[16]; float d2 = 0.f;
  #pragma unroll
  for (int i = 0; i < 16; ++i){ pb[i] = f2bf(p[i] * invd); d2 += bf2f(pb[i]); }
  #pragma unroll
  for (int o = 32; o > 0; o >>= 1) d2 += __shfl_xor(d2, o);
  if ((t & 63) == 0) red[wid] = d2;
  __syncthreads();
  if (t == 0) inv2[row0 + row] = 1.f / (red[0]+red[1]+red[2]+red[3]);
  unsigned short* Pr = Pb + (long)(row0 + row) * pitch;
  #pragma unroll
  for (int i = 0; i < 4; ++i){
    u16x4 pk;
    #pragma unroll
    for (int j = 0; j < 4; ++j) pk[j] = pb[i*4+j];
    *(u16x4*)(Pr + t*4 + i*1024) = pk;
  }
}

// ---------- PV GEMM + epilogue, 2-deep reg prefetch, double-buffered LDS (r4 proven) ----------
__global__ __launch_bounds__(512, 2) void pv2_k(
    const unsigned short* __restrict__ P, long ppitch,
    const unsigned short* __restrict__ vh, const unsigned short* __restrict__ vl,
    const unsigned short* __restrict__ v2h, const unsigned short* __restrict__ v2l,
    const float* __restrict__ inv2,
    const float* __restrict__ cx, const float* __restrict__ mcx, const float* __restrict__ rcx,
    float* __restrict__ outb, int qP_base, int qG_base)
{
  __shared__ __align__(16) char smem[110592];           // 108 KB
  typedef unsigned short (*PlT)[128][72];               // Pl[2][128][72]
  typedef unsigned short (*VlT)[4][64][72];             // Vl[2][4][64][72]
  PlT Pl = (PlT)smem;
  VlT Vl = (VlT)(smem + 36864);
  float* R = (float*)smem;

  int tid = threadIdx.x;
  int l = tid & 63, w = tid >> 6;
  int s = w & 1, wv = (w >> 1) & 1, wq = w >> 2;
  int lr = l & 15, lg = l >> 4;
  int qP0 = qP_base + blockIdx.x*128, qG0 = qG_base + blockIdx.x*128;
  int vc0 = blockIdx.y*64;

  int rowA = tid >> 3, c8 = (tid & 7)*8;
  const unsigned short* pgA = P + (long)(qP0 + rowA)*ppitch + c8;
  const unsigned short* pgB = pgA + (long)64*ppitch;
  long vgo = (long)(vc0 + rowA)*4096 + c8;
  const unsigned short* vg0 = vh  + vgo;
  const unsigned short* vg1 = vl  + vgo;
  const unsigned short* vg2 = v2h + vgo;
  const unsigned short* vg3 = v2l + vgo;

  f32x4 accM[4][2] = {}, acc2[4][2] = {};
  short8 pA0,pA1,vA0,vA1,vA2,vA3, pB0,pB1,vB0,vB1,vB2,vB3;
  int kc = s*32 + lg*8;

#define PV_LOAD(P0,P1,V0,V1,V2,V3, TT) { long ko_ = (long)(TT)*64; \
    P0 = *(const short8*)(pgA + ko_); P1 = *(const short8*)(pgB + ko_); \
    V0 = *(const short8*)(vg0 + ko_); V1 = *(const short8*)(vg1 + ko_); \
    V2 = *(const short8*)(vg2 + ko_); V3 = *(const short8*)(vg3 + ko_); }
#define PV_WRITE(BUF, P0,P1,V0,V1,V2,V3) { \
    *(short8*)&Pl[BUF][rowA][c8] = P0;    *(short8*)&Pl[BUF][rowA+64][c8] = P1; \
    *(short8*)&Vl[BUF][0][rowA][c8] = V0; *(short8*)&Vl[BUF][1][rowA][c8] = V1; \
    *(short8*)&Vl[BUF][2][rowA][c8] = V2; *(short8*)&Vl[BUF][3][rowA][c8] = V3; }
#define PV_COMPUTE(BUF) { \
    short8 fh[2], fl2[2], f2h[2], f2l[2]; \
    _Pragma("unroll") for (int bs = 0; bs < 2; ++bs){ \
      int vrow = wv*32 + bs*16 + lr; \
      fh[bs]  = *(const short8*)(&Vl[BUF][0][vrow][kc]); \
      fl2[bs] = *(const short8*)(&Vl[BUF][1][vrow][kc]); \
      f2h[bs] = *(const short8*)(&Vl[BUF][2][vrow][kc]); \
      f2l[bs] = *(const short8*)(&Vl[BUF][3][vrow][kc]); } \
    _Pragma("unroll") for (int aq = 0; aq < 4; ++aq){ \
      short8 pa = *(const short8*)(&Pl[BUF][wq*64 + aq*16 + lr][kc]); \
      _Pragma("unroll") for (int bs = 0; bs < 2; ++bs){ \
        accM[aq][bs] = MFMA(pa, fh[bs],  accM[aq][bs], 0,0,0); \
        accM[aq][bs] = MFMA(pa, fl2[bs], accM[aq][bs], 0,0,0); \
        acc2[aq][bs] = MFMA(pa, f2h[bs], acc2[aq][bs], 0,0,0); \
        acc2[aq][bs] = MFMA(pa, f2l[bs], acc2[aq][bs], 0,0,0); } } }

  PV_LOAD(pA0,pA1,vA0,vA1,vA2,vA3, 0);
  PV_WRITE(0, pA0,pA1,vA0,vA1,vA2,vA3);
  PV_LOAD(pA0,pA1,vA0,vA1,vA2,vA3, 1);
  __syncthreads();

  for (int t = 0; t < 64; t += 2){
    if (t+2 < 64) PV_LOAD(pB0,pB1,vB0,vB1,vB2,vB3, t+2);
    PV_COMPUTE(0);
    PV_WRITE(1, pA0,pA1,vA0,vA1,vA2,vA3);
    __syncthreads();
    if (t+3 < 64) PV_LOAD(pA0,pA1,vA0,vA1,vA2,vA3, t+3);
    PV_COMPUTE(1);
    if (t+2 < 64) PV_WRITE(0, pB0,pB1,vB0,vB1,vB2,vB3);
    __syncthreads();
  }
#undef PV_LOAD
#undef PV_WRITE
#undef PV_COMPUTE

  if (s == 1){
    float* Rb = R + (w>>1)*4096 + l*64;
    #pragma unroll
    for (int aq = 0; aq < 4; ++aq)
      #pragma unroll
      for (int bs = 0; bs < 2; ++bs)
        #pragma unroll
        for (int r = 0; r < 4; ++r){
          Rb[(aq*2+bs)*4 + r]      = accM[aq][bs][r];
          Rb[32 + (aq*2+bs)*4 + r] = acc2[aq][bs][r];
        }
  }
  __syncthreads();
  if (s == 0){
    const float* Rb = R + (w>>1)*4096 + l*64;
    #pragma unroll
    for (int aq = 0; aq < 4; ++aq)
      #pragma unroll
      for (int bs = 0; bs < 2; ++bs)
        #pragma unroll
        for (int r = 0; r < 4; ++r){
          accM[aq][bs][r] += Rb[(aq*2+bs)*4 + r];
          acc2[aq][bs][r] += Rb[32 + (aq*2+bs)*4 + r];
        }
  }
  __syncthreads();
  float* Tm = R;
  float* T2 = R + 64*132;
  if (s == 0){
    #pragma unroll
    for (int aq = 0; aq < 4; ++aq)
      #pragma unroll
      for (int bs = 0; bs < 2; ++bs){
        int vcl = wv*32 + bs*16 + lr;
        int ql = wq*64 + aq*16 + lg*4;
        #pragma unroll
        for (int r = 0; r < 4; ++r){
          Tm[vcl*132 + ql + r] = accM[aq][bs][r];
          T2[vcl*132 + ql + r] = acc2[aq][bs][r];
        }
      }
  }
  __syncthreads();
  #pragma unroll
  for (int p = 0; p < 4; ++p){
    int chunk = tid + p*512;
    int row = chunk >> 5, c4 = (chunk & 31)*4;
    float mu = mcx[vc0 + row], rs = rcx[vc0 + row];
    f32x4 tm = *(const f32x4*)&Tm[row*132 + c4];
    f32x4 t2 = *(const f32x4*)&T2[row*132 + c4];
    f32x4 iv = *(const f32x4*)&inv2[qP0 + c4];
    f32x4 cv = *(const f32x4*)&cx[(long)(vc0+row)*4096 + qG0 + c4];
    f32x4 ov;
    #pragma unroll
    for (int j = 0; j < 4; ++j){
      float M = tm[j]*iv[j], M2 = t2[j]*iv[j];
      float var = M2 - M*M;
      float sd = sqrtf(fmaxf(var, 0.f));
      ov[j] = sd*(cv[j]-mu)*rs + M;
    }
    *(f32x4*)&outb[(long)(vc0+row)*4096 + qG0 + c4] = ov;
  }
}

// ---------- launch ----------
extern "C" void kernel_launch(void* const* d_in, const int* in_sizes, int n_in,
                              void* d_out, int out_size, void* d_ws, size_t ws_size,
                              hipStream_t stream){
  const float* c_x  = (const float*)d_in[0];
  const float* s_x  = (const float*)d_in[1];
  const float* c_1x = (const float*)d_in[2];
  const float* s_1x = (const float*)d_in[3];
  const float* f_w  = (const float*)d_in[4];
  const float* f_b  = (const float*)d_in[5];
  const float* g_w  = (const float*)d_in[6];
  const float* g_b  = (const float*)d_in[7];
  const float* h_w  = (const float*)d_in[8];
  const float* h_b  = (const float*)d_in[9];
  float* out = (float*)d_out;

  char* ws = (char*)d_ws;
  size_t off = 0;
  auto alloc = [&](size_t bytes)->void*{
    void* p = ws + off; off += (bytes + 255) & ~(size_t)255; return p;
  };
  float* meanQ = (float*)alloc(2048*4); float* rstdQ = (float*)alloc(2048*4);
  float* meanK = (float*)alloc(2048*4); float* rstdK = (float*)alloc(2048*4);
  float* meanC = (float*)alloc(2048*4); float* rstdC = (float*)alloc(2048*4);
  float* biasF = (float*)alloc(512*4);  float* biasG = (float*)alloc(512*4);
  unsigned short* Wfh = (unsigned short*)alloc((size_t)512*512*2);
  unsigned short* Wfl = (unsigned short*)alloc((size_t)512*512*2);
  unsigned short* Wgh = (unsigned short*)alloc((size_t)512*512*2);
  unsigned short* Wgl = (unsigned short*)alloc((size_t)512*512*2);
  unsigned short* Whh = (unsigned short*)alloc((size_t)512*512*2);
  unsigned short* Whl = (unsigned short*)alloc((size_t)512*512*2);
  unsigned short* Qh = (unsigned short*)alloc((size_t)4096*512*2);
  unsigned short* Ql = (unsigned short*)alloc((size_t)4096*512*2);
  unsigned short* Kh = (unsigned short*)alloc((size_t)4096*512*2);
  unsigned short* Kl = (unsigned short*)alloc((size_t)4096*512*2);
  unsigned short* vh  = (unsigned short*)alloc((size_t)512*4096*2);
  unsigned short* vl  = (unsigned short*)alloc((size_t)512*4096*2);
  unsigned short* v2h = (unsigned short*)alloc((size_t)512*4096*2);
  unsigned short* v2l = (unsigned short*)alloc((size_t)512*4096*2);
  float* S    = (float*)alloc((size_t)2048*4096*4);   // fp32 S chunk
  float* inv2 = (float*)alloc(4096*4);

  size_t pbytes = (size_t)4096*4096*2;
  bool bigP = (off + pbytes + 256 <= ws_size);
  unsigned short* Pb; long ppitch;
  if (bigP){ Pb = (unsigned short*)alloc(pbytes); ppitch = 4096; }
  else     { Pb = (unsigned short*)S;             ppitch = 8192; }

  rowstats_k<<<2048, 256, 0, stream>>>(c_1x, meanQ, rstdQ);
  rowstats_k<<<2048, 256, 0, stream>>>(s_1x, meanK, rstdK);
  rowstats_k<<<2048, 256, 0, stream>>>(c_x,  meanC, rstdC);
  wsplit_k<<<1024, 256, 0, stream>>>(h_w, Whh, Whl);

  for (int b = 0; b < 4; ++b){
    long xoff = (long)b * 512 * 4096;
    foldw_k<<<512, 256, 0, stream>>>(f_w, f_b, meanQ + b*512, rstdQ + b*512, Wfh, Wfl, biasF);
    foldw_k<<<512, 256, 0, stream>>>(g_w, g_b, meanK + b*512, rstdK + b*512, Wgh, Wgl, biasG);
    conv3_k<0><<<dim3(64,4), 512, 0, stream>>>(c_1x + xoff, Wfh, Wfl, biasF, Qh, Ql, nullptr, nullptr);
    conv3_k<0><<<dim3(64,4), 512, 0, stream>>>(s_1x + xoff, Wgh, Wgl, biasG, Kh, Kl, nullptr, nullptr);
    conv3_k<1><<<dim3(64,4), 512, 0, stream>>>(s_x + xoff, Whh, Whl, h_b, vh, vl, v2h, v2l);
    if (bigP){
      for (int ch = 0; ch < 2; ++ch){
        int qbase = ch * 2048;
        sgemm3_k<<<dim3(16,16), 512, 0, stream>>>(Qh, Ql, Kh, Kl, S, qbase);
        softmax_k<<<2048, 256, 0, stream>>>(S, Pb, 4096, qbase, inv2);
      }
      pv2_k<<<dim3(32,8), 512, 0, stream>>>(Pb, 4096, vh, vl, v2h, v2l, inv2,
                                            c_x + xoff, meanC + b*512, rstdC + b*512,
                                            out + xoff, 0, 0);
    } else {
      for (int ch = 0; ch < 2; ++ch){
        int qbase = ch * 2048;
        sgemm3_k<<<dim3(16,16), 512, 0, stream>>>(Qh, Ql, Kh, Kl, S, qbase);
        softmax_k<<<2048, 256, 0, stream>>>(S, Pb, 8192, 0, inv2);
        pv2_k<<<dim3(16,8), 512, 0, stream>>>(Pb, 8192, vh, vl, v2h, v2l, inv2,
                                              c_x + xoff, meanC + b*512, rstdC + b*512,
                                              out + xoff, 0, qbase);
      }
    }
  }
}

// Round 8
// 827.727 us; speedup vs baseline: 1.1153x; 1.0013x over previous
//
#include <hip/hip_runtime.h>
#include <math.h>

typedef __attribute__((ext_vector_type(8))) short short8;    // 8 x bf16
typedef __attribute__((ext_vector_type(4))) float f32x4;
typedef __attribute__((ext_vector_type(4))) unsigned short u16x4;

#define DEVINL static __device__ __forceinline__
#define MFMA __builtin_amdgcn_mfma_f32_16x16x32_bf16

DEVINL unsigned short f2bf(float f){
  union { float f; unsigned u; } v; v.f = f;
  unsigned r = v.u + 0x7FFFu + ((v.u >> 16) & 1u);   // RNE
  return (unsigned short)(r >> 16);
}
DEVINL float bf2f(unsigned short h){
  union { unsigned u; float f; } v; v.u = ((unsigned)h) << 16;
  return v.f;
}

// B=4, C=QK=V=512, L=4096
__global__ void rowstats_k(const float* __restrict__ x,
                           float* __restrict__ mean, float* __restrict__ rstd){
  int row = blockIdx.x;
  const float4* p = (const float4*)(x + (long)row * 4096);
  float s = 0.f, ss = 0.f;
  for (int i = threadIdx.x; i < 1024; i += 256){
    float4 v = p[i];
    s  += v.x + v.y + v.z + v.w;
    ss += v.x*v.x + v.y*v.y + v.z*v.z + v.w*v.w;
  }
  for (int o = 32; o > 0; o >>= 1){ s += __shfl_down(s, o); ss += __shfl_down(ss, o); }
  __shared__ float ls[4], lss[4];
  int wv = threadIdx.x >> 6;
  if ((threadIdx.x & 63) == 0){ ls[wv] = s; lss[wv] = ss; }
  __syncthreads();
  if (threadIdx.x == 0){
    s = ls[0]+ls[1]+ls[2]+ls[3]; ss = lss[0]+lss[1]+lss[2]+lss[3];
    float m = s * (1.f/4096.f);
    float var = (ss - s*m) * (1.f/4095.f);
    mean[row] = m;
    rstd[row] = 1.f / sqrtf(var + 1e-5f);
  }
}

__global__ void foldw_k(const float* __restrict__ w, const float* __restrict__ bias,
                        const float* __restrict__ mean, const float* __restrict__ rstd,
                        unsigned short* __restrict__ wh, unsigned short* __restrict__ wl,
                        float* __restrict__ biasp){
  int o = blockIdx.x;
  const float* wr = w + (long)o * 512;
  float part = 0.f;
  for (int c = threadIdx.x; c < 512; c += 256){
    float wv = wr[c] * rstd[c];
    unsigned short h = f2bf(wv);
    wh[(o<<9)+c] = h;
    wl[(o<<9)+c] = f2bf(wv - bf2f(h));
    part += wv * mean[c];
  }
  __shared__ float red[256];
  red[threadIdx.x] = part; __syncthreads();
  for (int st = 128; st > 0; st >>= 1){
    if (threadIdx.x < st) red[threadIdx.x] += red[threadIdx.x + st];
    __syncthreads();
  }
  if (threadIdx.x == 0) biasp[o] = bias[o] - red[0];
}

__global__ void wsplit_k(const float* __restrict__ w,
                         unsigned short* __restrict__ wh, unsigned short* __restrict__ wl){
  int i = blockIdx.x * 256 + threadIdx.x;
  float v = w[i];
  unsigned short h = f2bf(v);
  wh[i] = h; wl[i] = f2bf(v - bf2f(h));
}

// ---------- 3-term conv GEMM, pipelined ----------
template<int MODE>
__global__ __launch_bounds__(512) void conv3_k(
    const float* __restrict__ X,
    const unsigned short* __restrict__ Wh, const unsigned short* __restrict__ Wl,
    const float* __restrict__ biasp,
    unsigned short* __restrict__ oh, unsigned short* __restrict__ ol,
    unsigned short* __restrict__ o2h, unsigned short* __restrict__ o2l)
{
  int ob = blockIdx.y, lb = blockIdx.x;
  __shared__ __align__(16) char csm[36864];
  typedef unsigned short (*XT)[64][72];
  XT Xh = (XT)csm;                 // [2][64][72]
  XT Xl = (XT)(csm + 18432);       // [2][64][72]

  int tid = threadIdx.x, w = tid >> 6, lane = tid & 63, lr = lane & 15, lg = lane >> 4;
  const unsigned short* WhB = Wh + (long)(ob*128 + w*16) * 512;
  const unsigned short* WlB = Wl + (long)(ob*128 + w*16) * 512;
  int sl = tid & 63, scg = tid >> 6;
  const float* Xg = X + (long)(scg*8)*4096 + lb*64 + sl;

  f32x4 acc[4] = {};
  float fA[8], fB[8];
  short8 wA0, wA1, wA2, wA3, wB0, wB1, wB2, wB3;

#define CV_XLOAD(F, CB) { _Pragma("unroll") for (int j=0;j<8;++j) F[j] = Xg[(long)((CB)*64 + j)*4096]; }
#define CV_XWRITE(BUF, F) { short8 hv, lv; _Pragma("unroll") for (int j=0;j<8;++j){ \
    unsigned short h_ = f2bf(F[j]); hv[j] = (short)h_; lv[j] = (short)f2bf(F[j] - bf2f(h_)); } \
    *(short8*)&Xh[BUF][sl][scg*8] = hv; *(short8*)&Xl[BUF][sl][scg*8] = lv; }
#define CV_WLOAD(W0,W1,W2,W3, CB) { \
    W0 = *(const short8*)(WhB + (long)lr*512 + (CB)*64 + lg*8); \
    W1 = *(const short8*)(WhB + (long)lr*512 + (CB)*64 + 32 + lg*8); \
    W2 = *(const short8*)(WlB + (long)lr*512 + (CB)*64 + lg*8); \
    W3 = *(const short8*)(WlB + (long)lr*512 + (CB)*64 + 32 + lg*8); }
#define CV_COMPUTE(BUF, W0,W1,W2,W3) { \
    _Pragma("unroll") for (int ct=0;ct<4;++ct){ \
      short8 bh = *(const short8*)&Xh[BUF][ct*16+lr][lg*8]; \
      short8 bl = *(const short8*)&Xl[BUF][ct*16+lr][lg*8]; \
      acc[ct] = MFMA(W0, bh, acc[ct], 0,0,0); \
      acc[ct] = MFMA(W2, bh, acc[ct], 0,0,0); \
      acc[ct] = MFMA(W0, bl, acc[ct], 0,0,0); } \
    _Pragma("unroll") for (int ct=0;ct<4;++ct){ \
      short8 bh = *(const short8*)&Xh[BUF][ct*16+lr][32+lg*8]; \
      short8 bl = *(const short8*)&Xl[BUF][ct*16+lr][32+lg*8]; \
      acc[ct] = MFMA(W1, bh, acc[ct], 0,0,0); \
      acc[ct] = MFMA(W3, bh, acc[ct], 0,0,0); \
      acc[ct] = MFMA(W1, bl, acc[ct], 0,0,0); } }

  CV_XLOAD(fA, 0); CV_XWRITE(0, fA);
  CV_XLOAD(fA, 1);
  CV_WLOAD(wA0,wA1,wA2,wA3, 0);
  __syncthreads();
  for (int cb = 0; cb < 8; cb += 2){
    if (cb+2 < 8) CV_XLOAD(fB, cb+2);
    CV_WLOAD(wB0,wB1,wB2,wB3, cb+1);
    CV_COMPUTE(0, wA0,wA1,wA2,wA3);
    CV_XWRITE(1, fA);
    __syncthreads();
    if (cb+3 < 8) CV_XLOAD(fA, cb+3);
    if (cb+2 < 8) CV_WLOAD(wA0,wA1,wA2,wA3, cb+2);
    CV_COMPUTE(1, wB0,wB1,wB2,wB3);
    if (cb+2 < 8) CV_XWRITE(0, fB);
    __syncthreads();
  }

  int o4 = ob*128 + w*16 + lg*4;
  float bv[4];
  #pragma unroll
  for (int r = 0; r < 4; ++r) bv[r] = biasp[o4 + r];
  if (MODE == 0){
    #pragma unroll
    for (int ct = 0; ct < 4; ++ct){
      u16x4 ph, pl;
      #pragma unroll
      for (int r = 0; r < 4; ++r){
        float y = acc[ct][r] + bv[r];
        unsigned short h = f2bf(y);
        ph[r] = h; pl[r] = f2bf(y - bf2f(h));
      }
      long base = ((long)(lb*64 + ct*16 + lr)) * 512 + o4;
      *(u16x4*)(oh + base) = ph;
      *(u16x4*)(ol + base) = pl;
    }
  } else {
    unsigned short sh_[16], sl_[16], s2h_[16], s2l_[16];
    #pragma unroll
    for (int ct = 0; ct < 4; ++ct)
      #pragma unroll
      for (int r = 0; r < 4; ++r){
        float y = acc[ct][r] + bv[r];
        unsigned short h = f2bf(y);
        float ve = bf2f(h);
        unsigned short l = f2bf(y - ve);
        ve += bf2f(l);
        float v2 = ve * ve;
        unsigned short h2 = f2bf(v2);
        unsigned short l2 = f2bf(v2 - bf2f(h2));
        sh_[ct*4+r] = h; sl_[ct*4+r] = l; s2h_[ct*4+r] = h2; s2l_[ct*4+r] = l2;
      }
    unsigned short* T = (unsigned short*)csm;   // [128][72]
#define CV_STORE(ARR, DST) { \
    __syncthreads(); \
    _Pragma("unroll") for (int ct=0;ct<4;++ct) \
      _Pragma("unroll") for (int r=0;r<4;++r) \
        T[(w*16+lg*4+r)*72 + ct*16+lr] = ARR[ct*4+r]; \
    __syncthreads(); \
    _Pragma("unroll") for (int s_=0;s_<2;++s_){ \
      int slot = tid + s_*512; int row = slot>>3, ch=(slot&7)*8; \
      *(short8*)(DST + (long)(ob*128+row)*4096 + lb*64 + ch) = *(const short8*)&T[row*72+ch]; } }
    CV_STORE(sh_,  oh);
    CV_STORE(sl_,  ol);
    CV_STORE(s2h_, o2h);
    CV_STORE(s2l_, o2l);
#undef CV_STORE
  }
#undef CV_XLOAD
#undef CV_XWRITE
#undef CV_WLOAD
#undef CV_COMPUTE
}

// ---------- 3-term S GEMM: 128q x 256k tile, wave = 64x64 (as=4 x bs=4) ----------
// pitch 64 + XOR 16B-unit swizzle (u ^= row&7): conflict-free, LDS 96 KB.
__global__ __launch_bounds__(512) void sgemm3_k(
    const unsigned short* __restrict__ Qh, const unsigned short* __restrict__ Ql,
    const unsigned short* __restrict__ Kh, const unsigned short* __restrict__ Kl,
    float* __restrict__ S, int qbase)
{
  int bx = blockIdx.x, by = blockIdx.y;
  int q0g = qbase + bx*128, k0 = by*256;
  __shared__ unsigned short Qhs[128][64], Qls[128][64];
  __shared__ unsigned short Khs[256][64], Kls[256][64];
  int tid = threadIdx.x, w = tid >> 6, lane = tid & 63, lr = lane & 15, lg = lane >> 4;
  int wr = w & 1, wc = w >> 1;
  int srow = tid >> 3, sch = (tid & 7)*8;
  int swu = ((tid & 7) ^ (srow & 7)) * 8;       // swizzled LDS write offset (shorts)
  int lr7 = lr & 7;
  short8 qr[4], kr[8];
  f32x4 acc[4][4] = {};

#define SG_LOAD(CB) { long c0_ = (long)(CB)*64 + sch; \
    _Pragma("unroll") for (int i = 0; i < 4; ++i){ \
      const unsigned short* src = (i < 2 ? Qh : Ql); \
      qr[i] = *(const short8*)(src + (long)(q0g + srow + (i&1)*64)*512 + c0_); } \
    _Pragma("unroll") for (int i = 0; i < 8; ++i){ \
      const unsigned short* src = (i < 4 ? Kh : Kl); \
      kr[i] = *(const short8*)(src + (long)(k0 + srow + (i&3)*64)*512 + c0_); } }
#define SG_WRITE { \
    _Pragma("unroll") for (int i = 0; i < 4; ++i){ \
      if (i < 2) *(short8*)&Qhs[srow + (i&1)*64][swu] = qr[i]; \
      else       *(short8*)&Qls[srow + (i&1)*64][swu] = qr[i]; } \
    _Pragma("unroll") for (int i = 0; i < 8; ++i){ \
      if (i < 4) *(short8*)&Khs[srow + (i&3)*64][swu] = kr[i]; \
      else       *(short8*)&Kls[srow + (i&3)*64][swu] = kr[i]; } }

  SG_LOAD(0); SG_WRITE;
  __syncthreads();
  for (int cb = 0; cb < 8; ++cb){
    if (cb < 7) SG_LOAD(cb+1);
    #pragma unroll
    for (int kk = 0; kk < 2; ++kk){
      int un = ((kk*4 + lg) ^ lr7) * 8;         // swizzled read offset
      short8 bh[4], bl[4];
      #pragma unroll
      for (int bs = 0; bs < 4; ++bs){
        int krow = wc*64 + bs*16 + lr;
        bh[bs] = *(const short8*)(&Khs[krow][un]);
        bl[bs] = *(const short8*)(&Kls[krow][un]);
      }
      #pragma unroll
      for (int as = 0; as < 4; ++as){
        int qrow = wr*64 + as*16 + lr;
        short8 ah = *(const short8*)(&Qhs[qrow][un]);
        short8 al = *(const short8*)(&Qls[qrow][un]);
        #pragma unroll
        for (int bs = 0; bs < 4; ++bs){
          acc[as][bs] = MFMA(ah, bh[bs], acc[as][bs], 0,0,0);
          acc[as][bs] = MFMA(al, bh[bs], acc[as][bs], 0,0,0);
          acc[as][bs] = MFMA(ah, bl[bs], acc[as][bs], 0,0,0);
        }
      }
    }
    __syncthreads();
    if (cb < 7){ SG_WRITE; __syncthreads(); }
  }
#undef SG_LOAD
#undef SG_WRITE
  #pragma unroll
  for (int as = 0; as < 4; ++as){
    #pragma unroll
    for (int bs = 0; bs < 4; ++bs){
      int q = bx*128 + wr*64 + as*16 + lg*4;
      int k = k0 + wc*64 + bs*16 + lr;
      float* Sp = S + (long)q*4096 + k;
      #pragma unroll
      for (int r = 0; r < 4; ++r) Sp[(long)r*4096] = acc[as][bs][r];
    }
  }
}

// ---------- row softmax ----------
__global__ __launch_bounds__(256) void softmax_k(const float* __restrict__ S,
                                                 unsigned short* __restrict__ Pb, long pitch,
                                                 int row0, float* __restrict__ inv2){
  int row = blockIdx.x;
  const float* Sr = S + (long)row * 4096;
  int t = threadIdx.x;
  f32x4 v[4];
  #pragma unroll
  for (int i = 0; i < 4; ++i) v[i] = *(const f32x4*)(Sr + t*4 + i*1024);
  float mx = v[0][0];
  #pragma unroll
  for (int i = 0; i < 4; ++i)
    #pragma unroll
    for (int j = 0; j < 4; ++j) mx = fmaxf(mx, v[i][j]);
  #pragma unroll
  for (int o = 32; o > 0; o >>= 1) mx = fmaxf(mx, __shfl_xor(mx, o));
  __shared__ float red[4];
  int wid = t >> 6;
  if ((t & 63) == 0) red[wid] = mx;
  __syncthreads();
  mx = fmaxf(fmaxf(red[0], red[1]), fmaxf(red[2], red[3]));
  __syncthreads();
  float p[16]; float d = 0.f;
  #pragma unroll
  for (int i = 0; i < 4; ++i)
    #pragma unroll
    for (int j = 0; j < 4; ++j){ float e = expf(v[i][j] - mx); p[i*4+j] = e; d += e; }
  #pragma unroll
  for (int o = 32; o > 0; o >>= 1) d += __shfl_xor(d, o);
  if ((t & 63) == 0) red[wid] = d;
  __syncthreads();
  d = red[0] + red[1] + red[2] + red[3];
  __syncthreads();
  float invd = 1.f / d;
  unsigned short pb[16]; float d2 = 0.f;
  #pragma unroll
  for (int i = 0; i < 16; ++i){ pb[i] = f2bf(p[i] * invd); d2 += bf2f(pb[i]); }
  #pragma unroll
  for (int o = 32; o > 0; o >>= 1) d2 += __shfl_xor(d2, o);
  if ((t & 63) == 0) red[wid] = d2;
  __syncthreads();
  if (t == 0) inv2[row0 + row] = 1.f / (red[0]+red[1]+red[2]+red[3]);
  unsigned short* Pr = Pb + (long)(row0 + row) * pitch;
  #pragma unroll
  for (int i = 0; i < 4; ++i){
    u16x4 pk;
    #pragma unroll
    for (int j = 0; j < 4; ++j) pk[j] = pb[i*4+j];
    *(u16x4*)(Pr + t*4 + i*1024) = pk;
  }
}

// ---------- PV GEMM + epilogue, 2-deep reg prefetch, dbuf LDS ----------
// pitch 64 + XOR 16B-unit swizzle: conflict-free, LDS 96 KB.
__global__ __launch_bounds__(512, 2) void pv2_k(
    const unsigned short* __restrict__ P, long ppitch,
    const unsigned short* __restrict__ vh, const unsigned short* __restrict__ vl,
    const unsigned short* __restrict__ v2h, const unsigned short* __restrict__ v2l,
    const float* __restrict__ inv2,
    const float* __restrict__ cx, const float* __restrict__ mcx, const float* __restrict__ rcx,
    float* __restrict__ outb, int qP_base, int qG_base)
{
  __shared__ __align__(16) char smem[98304];            // 96 KB
  typedef unsigned short (*PlT)[128][64];               // Pl[2][128][64] : 32768 B
  typedef unsigned short (*VlT)[4][64][64];             // Vl[2][4][64][64] : 65536 B
  PlT Pl = (PlT)smem;
  VlT Vl = (VlT)(smem + 32768);
  float* R = (float*)smem;                              // epilogue scratch (<= 67.5 KB used)

  int tid = threadIdx.x;
  int l = tid & 63, w = tid >> 6;
  int s = w & 1, wv = (w >> 1) & 1, wq = w >> 2;
  int lr = l & 15, lg = l >> 4;
  int qP0 = qP_base + blockIdx.x*128, qG0 = qG_base + blockIdx.x*128;
  int vc0 = blockIdx.y*64;

  int rowA = tid >> 3, c8 = (tid & 7)*8;
  int wu = ((tid & 7) ^ (rowA & 7)) * 8;                // swizzled LDS write offset
  int un = ((s*4 + lg) ^ (lr & 7)) * 8;                 // swizzled LDS read offset
  const unsigned short* pgA = P + (long)(qP0 + rowA)*ppitch + c8;
  const unsigned short* pgB = pgA + (long)64*ppitch;
  long vgo = (long)(vc0 + rowA)*4096 + c8;
  const unsigned short* vg0 = vh  + vgo;
  const unsigned short* vg1 = vl  + vgo;
  const unsigned short* vg2 = v2h + vgo;
  const unsigned short* vg3 = v2l + vgo;

  f32x4 accM[4][2] = {}, acc2[4][2] = {};
  short8 pA0,pA1,vA0,vA1,vA2,vA3, pB0,pB1,vB0,vB1,vB2,vB3;

#define PV_LOAD(P0,P1,V0,V1,V2,V3, TT) { long ko_ = (long)(TT)*64; \
    P0 = *(const short8*)(pgA + ko_); P1 = *(const short8*)(pgB + ko_); \
    V0 = *(const short8*)(vg0 + ko_); V1 = *(const short8*)(vg1 + ko_); \
    V2 = *(const short8*)(vg2 + ko_); V3 = *(const short8*)(vg3 + ko_); }
#define PV_WRITE(BUF, P0,P1,V0,V1,V2,V3) { \
    *(short8*)&Pl[BUF][rowA][wu] = P0;    *(short8*)&Pl[BUF][rowA+64][wu] = P1; \
    *(short8*)&Vl[BUF][0][rowA][wu] = V0; *(short8*)&Vl[BUF][1][rowA][wu] = V1; \
    *(short8*)&Vl[BUF][2][rowA][wu] = V2; *(short8*)&Vl[BUF][3][rowA][wu] = V3; }
#define PV_COMPUTE(BUF) { \
    short8 fh[2], fl2[2], f2h[2], f2l[2]; \
    _Pragma("unroll") for (int bs = 0; bs < 2; ++bs){ \
      int vrow = wv*32 + bs*16 + lr; \
      fh[bs]  = *(const short8*)(&Vl[BUF][0][vrow][un]); \
      fl2[bs] = *(const short8*)(&Vl[BUF][1][vrow][un]); \
      f2h[bs] = *(const short8*)(&Vl[BUF][2][vrow][un]); \
      f2l[bs] = *(const short8*)(&Vl[BUF][3][vrow][un]); } \
    _Pragma("unroll") for (int aq = 0; aq < 4; ++aq){ \
      short8 pa = *(const short8*)(&Pl[BUF][wq*64 + aq*16 + lr][un]); \
      _Pragma("unroll") for (int bs = 0; bs < 2; ++bs){ \
        accM[aq][bs] = MFMA(pa, fh[bs],  accM[aq][bs], 0,0,0); \
        accM[aq][bs] = MFMA(pa, fl2[bs], accM[aq][bs], 0,0,0); \
        acc2[aq][bs] = MFMA(pa, f2h[bs], acc2[aq][bs], 0,0,0); \
        acc2[aq][bs] = MFMA(pa, f2l[bs], acc2[aq][bs], 0,0,0); } } }

  PV_LOAD(pA0,pA1,vA0,vA1,vA2,vA3, 0);
  PV_WRITE(0, pA0,pA1,vA0,vA1,vA2,vA3);
  PV_LOAD(pA0,pA1,vA0,vA1,vA2,vA3, 1);
  __syncthreads();

  for (int t = 0; t < 64; t += 2){
    if (t+2 < 64) PV_LOAD(pB0,pB1,vB0,vB1,vB2,vB3, t+2);
    PV_COMPUTE(0);
    PV_WRITE(1, pA0,pA1,vA0,vA1,vA2,vA3);
    __syncthreads();
    if (t+3 < 64) PV_LOAD(pA0,pA1,vA0,vA1,vA2,vA3, t+3);
    PV_COMPUTE(1);
    if (t+2 < 64) PV_WRITE(0, pB0,pB1,vB0,vB1,vB2,vB3);
    __syncthreads();
  }
#undef PV_LOAD
#undef PV_WRITE
#undef PV_COMPUTE

  if (s == 1){
    float* Rb = R + (w>>1)*4096 + l*64;
    #pragma unroll
    for (int aq = 0; aq < 4; ++aq)
      #pragma unroll
      for (int bs = 0; bs < 2; ++bs)
        #pragma unroll
        for (int r = 0; r < 4; ++r){
          Rb[(aq*2+bs)*4 + r]      = accM[aq][bs][r];
          Rb[32 + (aq*2+bs)*4 + r] = acc2[aq][bs][r];
        }
  }
  __syncthreads();
  if (s == 0){
    const float* Rb = R + (w>>1)*4096 + l*64;
    #pragma unroll
    for (int aq = 0; aq < 4; ++aq)
      #pragma unroll
      for (int bs = 0; bs < 2; ++bs)
        #pragma unroll
        for (int r = 0; r < 4; ++r){
          accM[aq][bs][r] += Rb[(aq*2+bs)*4 + r];
          acc2[aq][bs][r] += Rb[32 + (aq*2+bs)*4 + r];
        }
  }
  __syncthreads();
  float* Tm = R;
  float* T2 = R + 64*132;
  if (s == 0){
    #pragma unroll
    for (int aq = 0; aq < 4; ++aq)
      #pragma unroll
      for (int bs = 0; bs < 2; ++bs){
        int vcl = wv*32 + bs*16 + lr;
        int ql = wq*64 + aq*16 + lg*4;
        #pragma unroll
        for (int r = 0; r < 4; ++r){
          Tm[vcl*132 + ql + r] = accM[aq][bs][r];
          T2[vcl*132 + ql + r] = acc2[aq][bs][r];
        }
      }
  }
  __syncthreads();
  #pragma unroll
  for (int p = 0; p < 4; ++p){
    int chunk = tid + p*512;
    int row = chunk >> 5, c4 = (chunk & 31)*4;
    float mu = mcx[vc0 + row], rs = rcx[vc0 + row];
    f32x4 tm = *(const f32x4*)&Tm[row*132 + c4];
    f32x4 t2 = *(const f32x4*)&T2[row*132 + c4];
    f32x4 iv = *(const f32x4*)&inv2[qP0 + c4];
    f32x4 cv = *(const f32x4*)&cx[(long)(vc0+row)*4096 + qG0 + c4];
    f32x4 ov;
    #pragma unroll
    for (int j = 0; j < 4; ++j){
      float M = tm[j]*iv[j], M2 = t2[j]*iv[j];
      float var = M2 - M*M;
      float sd = sqrtf(fmaxf(var, 0.f));
      ov[j] = sd*(cv[j]-mu)*rs + M;
    }
    *(f32x4*)&outb[(long)(vc0+row)*4096 + qG0 + c4] = ov;
  }
}

// ---------- launch ----------
extern "C" void kernel_launch(void* const* d_in, const int* in_sizes, int n_in,
                              void* d_out, int out_size, void* d_ws, size_t ws_size,
                              hipStream_t stream){
  const float* c_x  = (const float*)d_in[0];
  const float* s_x  = (const float*)d_in[1];
  const float* c_1x = (const float*)d_in[2];
  const float* s_1x = (const float*)d_in[3];
  const float* f_w  = (const float*)d_in[4];
  const float* f_b  = (const float*)d_in[5];
  const float* g_w  = (const float*)d_in[6];
  const float* g_b  = (const float*)d_in[7];
  const float* h_w  = (const float*)d_in[8];
  const float* h_b  = (const float*)d_in[9];
  float* out = (float*)d_out;

  char* ws = (char*)d_ws;
  size_t off = 0;
  auto alloc = [&](size_t bytes)->void*{
    void* p = ws + off; off += (bytes + 255) & ~(size_t)255; return p;
  };
  float* meanQ = (float*)alloc(2048*4); float* rstdQ = (float*)alloc(2048*4);
  float* meanK = (float*)alloc(2048*4); float* rstdK = (float*)alloc(2048*4);
  float* meanC = (float*)alloc(2048*4); float* rstdC = (float*)alloc(2048*4);
  float* biasF = (float*)alloc(512*4);  float* biasG = (float*)alloc(512*4);
  unsigned short* Wfh = (unsigned short*)alloc((size_t)512*512*2);
  unsigned short* Wfl = (unsigned short*)alloc((size_t)512*512*2);
  unsigned short* Wgh = (unsigned short*)alloc((size_t)512*512*2);
  unsigned short* Wgl = (unsigned short*)alloc((size_t)512*512*2);
  unsigned short* Whh = (unsigned short*)alloc((size_t)512*512*2);
  unsigned short* Whl = (unsigned short*)alloc((size_t)512*512*2);
  unsigned short* Qh = (unsigned short*)alloc((size_t)4096*512*2);
  unsigned short* Ql = (unsigned short*)alloc((size_t)4096*512*2);
  unsigned short* Kh = (unsigned short*)alloc((size_t)4096*512*2);
  unsigned short* Kl = (unsigned short*)alloc((size_t)4096*512*2);
  unsigned short* vh  = (unsigned short*)alloc((size_t)512*4096*2);
  unsigned short* vl  = (unsigned short*)alloc((size_t)512*4096*2);
  unsigned short* v2h = (unsigned short*)alloc((size_t)512*4096*2);
  unsigned short* v2l = (unsigned short*)alloc((size_t)512*4096*2);
  float* S    = (float*)alloc((size_t)2048*4096*4);   // fp32 S chunk
  float* inv2 = (float*)alloc(4096*4);

  size_t pbytes = (size_t)4096*4096*2;
  bool bigP = (off + pbytes + 256 <= ws_size);
  unsigned short* Pb; long ppitch;
  if (bigP){ Pb = (unsigned short*)alloc(pbytes); ppitch = 4096; }
  else     { Pb = (unsigned short*)S;             ppitch = 8192; }

  rowstats_k<<<2048, 256, 0, stream>>>(c_1x, meanQ, rstdQ);
  rowstats_k<<<2048, 256, 0, stream>>>(s_1x, meanK, rstdK);
  rowstats_k<<<2048, 256, 0, stream>>>(c_x,  meanC, rstdC);
  wsplit_k<<<1024, 256, 0, stream>>>(h_w, Whh, Whl);

  for (int b = 0; b < 4; ++b){
    long xoff = (long)b * 512 * 4096;
    foldw_k<<<512, 256, 0, stream>>>(f_w, f_b, meanQ + b*512, rstdQ + b*512, Wfh, Wfl, biasF);
    foldw_k<<<512, 256, 0, stream>>>(g_w, g_b, meanK + b*512, rstdK + b*512, Wgh, Wgl, biasG);
    conv3_k<0><<<dim3(64,4), 512, 0, stream>>>(c_1x + xoff, Wfh, Wfl, biasF, Qh, Ql, nullptr, nullptr);
    conv3_k<0><<<dim3(64,4), 512, 0, stream>>>(s_1x + xoff, Wgh, Wgl, biasG, Kh, Kl, nullptr, nullptr);
    conv3_k<1><<<dim3(64,4), 512, 0, stream>>>(s_x + xoff, Whh, Whl, h_b, vh, vl, v2h, v2l);
    if (bigP){
      for (int ch = 0; ch < 2; ++ch){
        int qbase = ch * 2048;
        sgemm3_k<<<dim3(16,16), 512, 0, stream>>>(Qh, Ql, Kh, Kl, S, qbase);
        softmax_k<<<2048, 256, 0, stream>>>(S, Pb, 4096, qbase, inv2);
      }
      pv2_k<<<dim3(32,8), 512, 0, stream>>>(Pb, 4096, vh, vl, v2h, v2l, inv2,
                                            c_x + xoff, meanC + b*512, rstdC + b*512,
                                            out + xoff, 0, 0);
    } else {
      for (int ch = 0; ch < 2; ++ch){
        int qbase = ch * 2048;
        sgemm3_k<<<dim3(16,16), 512, 0, stream>>>(Qh, Ql, Kh, Kl, S, qbase);
        softmax_k<<<2048, 256, 0, stream>>>(S, Pb, 8192, 0, inv2);
        pv2_k<<<dim3(16,8), 512, 0, stream>>>(Pb, 8192, vh, vl, v2h, v2l, inv2,
                                              c_x + xoff, meanC + b*512, rstdC + b*512,
                                              out + xoff, 0, qbase);
      }
    }
  }
}

// Round 9
// 823.293 us; speedup vs baseline: 1.1213x; 1.0054x over previous
//
#include <hip/hip_runtime.h>
#include <math.h>

typedef __attribute__((ext_vector_type(8))) short short8;    // 8 x bf16
typedef __attribute__((ext_vector_type(4))) float f32x4;
typedef __attribute__((ext_vector_type(4))) unsigned short u16x4;

#define DEVINL static __device__ __forceinline__
#define MFMA __builtin_amdgcn_mfma_f32_16x16x32_bf16

DEVINL unsigned short f2bf(float f){
  union { float f; unsigned u; } v; v.f = f;
  unsigned r = v.u + 0x7FFFu + ((v.u >> 16) & 1u);   // RNE
  return (unsigned short)(r >> 16);
}
DEVINL float bf2f(unsigned short h){
  union { unsigned u; float f; } v; v.u = ((unsigned)h) << 16;
  return v.f;
}
DEVINL void gload16(const void* g, void* l){
  __builtin_amdgcn_global_load_lds(
      (const __attribute__((address_space(1))) void*)g,
      (__attribute__((address_space(3))) void*)l, 16, 0, 0);
}

// B=4, C=QK=V=512, L=4096
__global__ void rowstats_k(const float* __restrict__ x,
                           float* __restrict__ mean, float* __restrict__ rstd){
  int row = blockIdx.x;
  const float4* p = (const float4*)(x + (long)row * 4096);
  float s = 0.f, ss = 0.f;
  for (int i = threadIdx.x; i < 1024; i += 256){
    float4 v = p[i];
    s  += v.x + v.y + v.z + v.w;
    ss += v.x*v.x + v.y*v.y + v.z*v.z + v.w*v.w;
  }
  for (int o = 32; o > 0; o >>= 1){ s += __shfl_down(s, o); ss += __shfl_down(ss, o); }
  __shared__ float ls[4], lss[4];
  int wv = threadIdx.x >> 6;
  if ((threadIdx.x & 63) == 0){ ls[wv] = s; lss[wv] = ss; }
  __syncthreads();
  if (threadIdx.x == 0){
    s = ls[0]+ls[1]+ls[2]+ls[3]; ss = lss[0]+lss[1]+lss[2]+lss[3];
    float m = s * (1.f/4096.f);
    float var = (ss - s*m) * (1.f/4095.f);
    mean[row] = m;
    rstd[row] = 1.f / sqrtf(var + 1e-5f);
  }
}

__global__ void foldw_k(const float* __restrict__ w, const float* __restrict__ bias,
                        const float* __restrict__ mean, const float* __restrict__ rstd,
                        unsigned short* __restrict__ wh, unsigned short* __restrict__ wl,
                        float* __restrict__ biasp){
  int o = blockIdx.x;
  const float* wr = w + (long)o * 512;
  float part = 0.f;
  for (int c = threadIdx.x; c < 512; c += 256){
    float wv = wr[c] * rstd[c];
    unsigned short h = f2bf(wv);
    wh[(o<<9)+c] = h;
    wl[(o<<9)+c] = f2bf(wv - bf2f(h));
    part += wv * mean[c];
  }
  __shared__ float red[256];
  red[threadIdx.x] = part; __syncthreads();
  for (int st = 128; st > 0; st >>= 1){
    if (threadIdx.x < st) red[threadIdx.x] += red[threadIdx.x + st];
    __syncthreads();
  }
  if (threadIdx.x == 0) biasp[o] = bias[o] - red[0];
}

__global__ void wsplit_k(const float* __restrict__ w,
                         unsigned short* __restrict__ wh, unsigned short* __restrict__ wl){
  int i = blockIdx.x * 256 + threadIdx.x;
  float v = w[i];
  unsigned short h = f2bf(v);
  wh[i] = h; wl[i] = f2bf(v - bf2f(h));
}

// ---------- 3-term conv GEMM, pipelined ----------
template<int MODE>
__global__ __launch_bounds__(512) void conv3_k(
    const float* __restrict__ X,
    const unsigned short* __restrict__ Wh, const unsigned short* __restrict__ Wl,
    const float* __restrict__ biasp,
    unsigned short* __restrict__ oh, unsigned short* __restrict__ ol,
    unsigned short* __restrict__ o2h, unsigned short* __restrict__ o2l)
{
  int ob = blockIdx.y, lb = blockIdx.x;
  __shared__ __align__(16) char csm[36864];
  typedef unsigned short (*XT)[64][72];
  XT Xh = (XT)csm;                 // [2][64][72]
  XT Xl = (XT)(csm + 18432);       // [2][64][72]

  int tid = threadIdx.x, w = tid >> 6, lane = tid & 63, lr = lane & 15, lg = lane >> 4;
  const unsigned short* WhB = Wh + (long)(ob*128 + w*16) * 512;
  const unsigned short* WlB = Wl + (long)(ob*128 + w*16) * 512;
  int sl = tid & 63, scg = tid >> 6;
  const float* Xg = X + (long)(scg*8)*4096 + lb*64 + sl;

  f32x4 acc[4] = {};
  float fA[8], fB[8];
  short8 wA0, wA1, wA2, wA3, wB0, wB1, wB2, wB3;

#define CV_XLOAD(F, CB) { _Pragma("unroll") for (int j=0;j<8;++j) F[j] = Xg[(long)((CB)*64 + j)*4096]; }
#define CV_XWRITE(BUF, F) { short8 hv, lv; _Pragma("unroll") for (int j=0;j<8;++j){ \
    unsigned short h_ = f2bf(F[j]); hv[j] = (short)h_; lv[j] = (short)f2bf(F[j] - bf2f(h_)); } \
    *(short8*)&Xh[BUF][sl][scg*8] = hv; *(short8*)&Xl[BUF][sl][scg*8] = lv; }
#define CV_WLOAD(W0,W1,W2,W3, CB) { \
    W0 = *(const short8*)(WhB + (long)lr*512 + (CB)*64 + lg*8); \
    W1 = *(const short8*)(WhB + (long)lr*512 + (CB)*64 + 32 + lg*8); \
    W2 = *(const short8*)(WlB + (long)lr*512 + (CB)*64 + lg*8); \
    W3 = *(const short8*)(WlB + (long)lr*512 + (CB)*64 + 32 + lg*8); }
#define CV_COMPUTE(BUF, W0,W1,W2,W3) { \
    _Pragma("unroll") for (int ct=0;ct<4;++ct){ \
      short8 bh = *(const short8*)&Xh[BUF][ct*16+lr][lg*8]; \
      short8 bl = *(const short8*)&Xl[BUF][ct*16+lr][lg*8]; \
      acc[ct] = MFMA(W0, bh, acc[ct], 0,0,0); \
      acc[ct] = MFMA(W2, bh, acc[ct], 0,0,0); \
      acc[ct] = MFMA(W0, bl, acc[ct], 0,0,0); } \
    _Pragma("unroll") for (int ct=0;ct<4;++ct){ \
      short8 bh = *(const short8*)&Xh[BUF][ct*16+lr][32+lg*8]; \
      short8 bl = *(const short8*)&Xl[BUF][ct*16+lr][32+lg*8]; \
      acc[ct] = MFMA(W1, bh, acc[ct], 0,0,0); \
      acc[ct] = MFMA(W3, bh, acc[ct], 0,0,0); \
      acc[ct] = MFMA(W1, bl, acc[ct], 0,0,0); } }

  CV_XLOAD(fA, 0); CV_XWRITE(0, fA);
  CV_XLOAD(fA, 1);
  CV_WLOAD(wA0,wA1,wA2,wA3, 0);
  __syncthreads();
  for (int cb = 0; cb < 8; cb += 2){
    if (cb+2 < 8) CV_XLOAD(fB, cb+2);
    CV_WLOAD(wB0,wB1,wB2,wB3, cb+1);
    CV_COMPUTE(0, wA0,wA1,wA2,wA3);
    CV_XWRITE(1, fA);
    __syncthreads();
    if (cb+3 < 8) CV_XLOAD(fA, cb+3);
    if (cb+2 < 8) CV_WLOAD(wA0,wA1,wA2,wA3, cb+2);
    CV_COMPUTE(1, wB0,wB1,wB2,wB3);
    if (cb+2 < 8) CV_XWRITE(0, fB);
    __syncthreads();
  }

  int o4 = ob*128 + w*16 + lg*4;
  float bv[4];
  #pragma unroll
  for (int r = 0; r < 4; ++r) bv[r] = biasp[o4 + r];
  if (MODE == 0){
    #pragma unroll
    for (int ct = 0; ct < 4; ++ct){
      u16x4 ph, pl;
      #pragma unroll
      for (int r = 0; r < 4; ++r){
        float y = acc[ct][r] + bv[r];
        unsigned short h = f2bf(y);
        ph[r] = h; pl[r] = f2bf(y - bf2f(h));
      }
      long base = ((long)(lb*64 + ct*16 + lr)) * 512 + o4;
      *(u16x4*)(oh + base) = ph;
      *(u16x4*)(ol + base) = pl;
    }
  } else {
    unsigned short sh_[16], sl_[16], s2h_[16], s2l_[16];
    #pragma unroll
    for (int ct = 0; ct < 4; ++ct)
      #pragma unroll
      for (int r = 0; r < 4; ++r){
        float y = acc[ct][r] + bv[r];
        unsigned short h = f2bf(y);
        float ve = bf2f(h);
        unsigned short l = f2bf(y - ve);
        ve += bf2f(l);
        float v2 = ve * ve;
        unsigned short h2 = f2bf(v2);
        unsigned short l2 = f2bf(v2 - bf2f(h2));
        sh_[ct*4+r] = h; sl_[ct*4+r] = l; s2h_[ct*4+r] = h2; s2l_[ct*4+r] = l2;
      }
    unsigned short* T = (unsigned short*)csm;   // [128][72]
#define CV_STORE(ARR, DST) { \
    __syncthreads(); \
    _Pragma("unroll") for (int ct=0;ct<4;++ct) \
      _Pragma("unroll") for (int r=0;r<4;++r) \
        T[(w*16+lg*4+r)*72 + ct*16+lr] = ARR[ct*4+r]; \
    __syncthreads(); \
    _Pragma("unroll") for (int s_=0;s_<2;++s_){ \
      int slot = tid + s_*512; int row = slot>>3, ch=(slot&7)*8; \
      *(short8*)(DST + (long)(ob*128+row)*4096 + lb*64 + ch) = *(const short8*)&T[row*72+ch]; } }
    CV_STORE(sh_,  oh);
    CV_STORE(sl_,  ol);
    CV_STORE(s2h_, o2h);
    CV_STORE(s2l_, o2l);
#undef CV_STORE
  }
#undef CV_XLOAD
#undef CV_XWRITE
#undef CV_WLOAD
#undef CV_COMPUTE
}

// ---------- 3-term S GEMM: 128q x 256k tile, wave = 64x64 (as=4 x bs=4) ----------
// pitch 64 + XOR 16B-unit swizzle (u ^= row&7): conflict-free, LDS 96 KB.
__global__ __launch_bounds__(512) void sgemm3_k(
    const unsigned short* __restrict__ Qh, const unsigned short* __restrict__ Ql,
    const unsigned short* __restrict__ Kh, const unsigned short* __restrict__ Kl,
    float* __restrict__ S, int qbase)
{
  int bx = blockIdx.x, by = blockIdx.y;
  int q0g = qbase + bx*128, k0 = by*256;
  __shared__ unsigned short Qhs[128][64], Qls[128][64];
  __shared__ unsigned short Khs[256][64], Kls[256][64];
  int tid = threadIdx.x, w = tid >> 6, lane = tid & 63, lr = lane & 15, lg = lane >> 4;
  int wr = w & 1, wc = w >> 1;
  int srow = tid >> 3, sch = (tid & 7)*8;
  int swu = ((tid & 7) ^ (srow & 7)) * 8;       // swizzled LDS write offset (shorts)
  int lr7 = lr & 7;
  short8 qr[4], kr[8];
  f32x4 acc[4][4] = {};

#define SG_LOAD(CB) { long c0_ = (long)(CB)*64 + sch; \
    _Pragma("unroll") for (int i = 0; i < 4; ++i){ \
      const unsigned short* src = (i < 2 ? Qh : Ql); \
      qr[i] = *(const short8*)(src + (long)(q0g + srow + (i&1)*64)*512 + c0_); } \
    _Pragma("unroll") for (int i = 0; i < 8; ++i){ \
      const unsigned short* src = (i < 4 ? Kh : Kl); \
      kr[i] = *(const short8*)(src + (long)(k0 + srow + (i&3)*64)*512 + c0_); } }
#define SG_WRITE { \
    _Pragma("unroll") for (int i = 0; i < 4; ++i){ \
      if (i < 2) *(short8*)&Qhs[srow + (i&1)*64][swu] = qr[i]; \
      else       *(short8*)&Qls[srow + (i&1)*64][swu] = qr[i]; } \
    _Pragma("unroll") for (int i = 0; i < 8; ++i){ \
      if (i < 4) *(short8*)&Khs[srow + (i&3)*64][swu] = kr[i]; \
      else       *(short8*)&Kls[srow + (i&3)*64][swu] = kr[i]; } }

  SG_LOAD(0); SG_WRITE;
  __syncthreads();
  for (int cb = 0; cb < 8; ++cb){
    if (cb < 7) SG_LOAD(cb+1);
    #pragma unroll
    for (int kk = 0; kk < 2; ++kk){
      int un = ((kk*4 + lg) ^ lr7) * 8;         // swizzled read offset
      short8 bh[4], bl[4];
      #pragma unroll
      for (int bs = 0; bs < 4; ++bs){
        int krow = wc*64 + bs*16 + lr;
        bh[bs] = *(const short8*)(&Khs[krow][un]);
        bl[bs] = *(const short8*)(&Kls[krow][un]);
      }
      #pragma unroll
      for (int as = 0; as < 4; ++as){
        int qrow = wr*64 + as*16 + lr;
        short8 ah = *(const short8*)(&Qhs[qrow][un]);
        short8 al = *(const short8*)(&Qls[qrow][un]);
        #pragma unroll
        for (int bs = 0; bs < 4; ++bs){
          acc[as][bs] = MFMA(ah, bh[bs], acc[as][bs], 0,0,0);
          acc[as][bs] = MFMA(al, bh[bs], acc[as][bs], 0,0,0);
          acc[as][bs] = MFMA(ah, bl[bs], acc[as][bs], 0,0,0);
        }
      }
    }
    __syncthreads();
    if (cb < 7){ SG_WRITE; __syncthreads(); }
  }
#undef SG_LOAD
#undef SG_WRITE
  #pragma unroll
  for (int as = 0; as < 4; ++as){
    #pragma unroll
    for (int bs = 0; bs < 4; ++bs){
      int q = bx*128 + wr*64 + as*16 + lg*4;
      int k = k0 + wc*64 + bs*16 + lr;
      float* Sp = S + (long)q*4096 + k;
      #pragma unroll
      for (int r = 0; r < 4; ++r) Sp[(long)r*4096] = acc[as][bs][r];
    }
  }
}

// ---------- row softmax ----------
__global__ __launch_bounds__(256) void softmax_k(const float* __restrict__ S,
                                                 unsigned short* __restrict__ Pb, long pitch,
                                                 int row0, float* __restrict__ inv2){
  int row = blockIdx.x;
  const float* Sr = S + (long)row * 4096;
  int t = threadIdx.x;
  f32x4 v[4];
  #pragma unroll
  for (int i = 0; i < 4; ++i) v[i] = *(const f32x4*)(Sr + t*4 + i*1024);
  float mx = v[0][0];
  #pragma unroll
  for (int i = 0; i < 4; ++i)
    #pragma unroll
    for (int j = 0; j < 4; ++j) mx = fmaxf(mx, v[i][j]);
  #pragma unroll
  for (int o = 32; o > 0; o >>= 1) mx = fmaxf(mx, __shfl_xor(mx, o));
  __shared__ float red[4];
  int wid = t >> 6;
  if ((t & 63) == 0) red[wid] = mx;
  __syncthreads();
  mx = fmaxf(fmaxf(red[0], red[1]), fmaxf(red[2], red[3]));
  __syncthreads();
  float p[16]; float d = 0.f;
  #pragma unroll
  for (int i = 0; i < 4; ++i)
    #pragma unroll
    for (int j = 0; j < 4; ++j){ float e = expf(v[i][j] - mx); p[i*4+j] = e; d += e; }
  #pragma unroll
  for (int o = 32; o > 0; o >>= 1) d += __shfl_xor(d, o);
  if ((t & 63) == 0) red[wid] = d;
  __syncthreads();
  d = red[0] + red[1] + red[2] + red[3];
  __syncthreads();
  float invd = 1.f / d;
  unsigned short pb[16]; float d2 = 0.f;
  #pragma unroll
  for (int i = 0; i < 16; ++i){ pb[i] = f2bf(p[i] * invd); d2 += bf2f(pb[i]); }
  #pragma unroll
  for (int o = 32; o > 0; o >>= 1) d2 += __shfl_xor(d2, o);
  if ((t & 63) == 0) red[wid] = d2;
  __syncthreads();
  if (t == 0) inv2[row0 + row] = 1.f / (red[0]+red[1]+red[2]+red[3]);
  unsigned short* Pr = Pb + (long)(row0 + row) * pitch;
  #pragma unroll
  for (int i = 0; i < 4; ++i){
    u16x4 pk;
    #pragma unroll
    for (int j = 0; j < 4; ++j) pk[j] = pb[i*4+j];
    *(u16x4*)(Pr + t*4 + i*1024) = pk;
  }
}

// ---------- PV GEMM + epilogue ----------
// global_load_lds width-16 staging (linear LDS dest, pre-swizzled global source),
// single-barrier 2-phase double buffer. LDS contents identical to r8 layout.
__global__ __launch_bounds__(512, 2) void pv2_k(
    const unsigned short* __restrict__ P, long ppitch,
    const unsigned short* __restrict__ vh, const unsigned short* __restrict__ vl,
    const unsigned short* __restrict__ v2h, const unsigned short* __restrict__ v2l,
    const float* __restrict__ inv2,
    const float* __restrict__ cx, const float* __restrict__ mcx, const float* __restrict__ rcx,
    float* __restrict__ outb, int qP_base, int qG_base)
{
  __shared__ __align__(16) char smem[98304];            // 96 KB
  typedef unsigned short (*PlT)[128][64];               // Pl[2][128][64] : 32768 B
  typedef unsigned short (*VlT)[4][64][64];             // Vl[2][4][64][64] : 65536 B
  PlT Pl = (PlT)smem;
  VlT Vl = (VlT)(smem + 32768);
  float* R = (float*)smem;                              // epilogue scratch (<= 67.5 KB used)

  int tid = threadIdx.x;
  int l = tid & 63, w = tid >> 6;
  int s = w & 1, wv = (w >> 1) & 1, wq = w >> 2;
  int lr = l & 15, lg = l >> 4;
  int qP0 = qP_base + blockIdx.x*128, qG0 = qG_base + blockIdx.x*128;
  int vc0 = blockIdx.y*64;

  // staging: lane writes LDS at wave_base + lane*16 (hardware rule); source column
  // pre-swizzled so LDS[row][u] == G[row][u ^ (row&7)*8], matching r8's layout.
  int rowA = tid >> 3, c8 = (tid & 7)*8;
  int srcc = c8 ^ ((rowA & 7) * 8);                     // pre-swizzled source column
  int wb = w * 8;                                       // wave-uniform first staged row
  int un = ((s*4 + lg) ^ (lr & 7)) * 8;                 // swizzled LDS read offset
  const unsigned short* pgA = P + (long)(qP0 + rowA)*ppitch + srcc;
  const unsigned short* pgB = pgA + (long)64*ppitch;
  long vgo = (long)(vc0 + rowA)*4096 + srcc;
  const unsigned short* vg0 = vh  + vgo;
  const unsigned short* vg1 = vl  + vgo;
  const unsigned short* vg2 = v2h + vgo;
  const unsigned short* vg3 = v2l + vgo;

  f32x4 accM[4][2] = {}, acc2[4][2] = {};

#define PV_STAGE(BUF, TT) { long ko_ = (long)(TT)*64; \
    gload16(pgA + ko_, &Pl[BUF][wb][0]); \
    gload16(pgB + ko_, &Pl[BUF][64 + wb][0]); \
    gload16(vg0 + ko_, &Vl[BUF][0][wb][0]); \
    gload16(vg1 + ko_, &Vl[BUF][1][wb][0]); \
    gload16(vg2 + ko_, &Vl[BUF][2][wb][0]); \
    gload16(vg3 + ko_, &Vl[BUF][3][wb][0]); }
#define PV_COMPUTE(BUF) { \
    short8 fh[2], fl2[2], f2h[2], f2l[2]; \
    _Pragma("unroll") for (int bs = 0; bs < 2; ++bs){ \
      int vrow = wv*32 + bs*16 + lr; \
      fh[bs]  = *(const short8*)(&Vl[BUF][0][vrow][un]); \
      fl2[bs] = *(const short8*)(&Vl[BUF][1][vrow][un]); \
      f2h[bs] = *(const short8*)(&Vl[BUF][2][vrow][un]); \
      f2l[bs] = *(const short8*)(&Vl[BUF][3][vrow][un]); } \
    _Pragma("unroll") for (int aq = 0; aq < 4; ++aq){ \
      short8 pa = *(const short8*)(&Pl[BUF][wq*64 + aq*16 + lr][un]); \
      _Pragma("unroll") for (int bs = 0; bs < 2; ++bs){ \
        accM[aq][bs] = MFMA(pa, fh[bs],  accM[aq][bs], 0,0,0); \
        accM[aq][bs] = MFMA(pa, fl2[bs], accM[aq][bs], 0,0,0); \
        acc2[aq][bs] = MFMA(pa, f2h[bs], acc2[aq][bs], 0,0,0); \
        acc2[aq][bs] = MFMA(pa, f2l[bs], acc2[aq][bs], 0,0,0); } } }

  PV_STAGE(0, 0);
  __syncthreads();                       // drains the 6 gload_lds (vmcnt 0)
  int cur = 0;
  for (int t = 0; t < 64; ++t){
    if (t < 63) PV_STAGE(cur ^ 1, t+1);  // issue next tile; lands during compute
    PV_COMPUTE(cur);
    __syncthreads();                     // implicit vmcnt(0)+lgkmcnt(0): next buf ready
    cur ^= 1;
  }
#undef PV_STAGE
#undef PV_COMPUTE

  // ---- k-substep reduce: s=1 waves dump, s=0 partners add ----
  if (s == 1){
    float* Rb = R + (w>>1)*4096 + l*64;
    #pragma unroll
    for (int aq = 0; aq < 4; ++aq)
      #pragma unroll
      for (int bs = 0; bs < 2; ++bs)
        #pragma unroll
        for (int r = 0; r < 4; ++r){
          Rb[(aq*2+bs)*4 + r]      = accM[aq][bs][r];
          Rb[32 + (aq*2+bs)*4 + r] = acc2[aq][bs][r];
        }
  }
  __syncthreads();
  if (s == 0){
    const float* Rb = R + (w>>1)*4096 + l*64;
    #pragma unroll
    for (int aq = 0; aq < 4; ++aq)
      #pragma unroll
      for (int bs = 0; bs < 2; ++bs)
        #pragma unroll
        for (int r = 0; r < 4; ++r){
          accM[aq][bs][r] += Rb[(aq*2+bs)*4 + r];
          acc2[aq][bs][r] += Rb[32 + (aq*2+bs)*4 + r];
        }
  }
  __syncthreads();
  float* Tm = R;
  float* T2 = R + 64*132;
  if (s == 0){
    #pragma unroll
    for (int aq = 0; aq < 4; ++aq)
      #pragma unroll
      for (int bs = 0; bs < 2; ++bs){
        int vcl = wv*32 + bs*16 + lr;
        int ql = wq*64 + aq*16 + lg*4;
        #pragma unroll
        for (int r = 0; r < 4; ++r){
          Tm[vcl*132 + ql + r] = accM[aq][bs][r];
          T2[vcl*132 + ql + r] = acc2[aq][bs][r];
        }
      }
  }
  __syncthreads();
  #pragma unroll
  for (int p = 0; p < 4; ++p){
    int chunk = tid + p*512;
    int row = chunk >> 5, c4 = (chunk & 31)*4;
    float mu = mcx[vc0 + row], rs = rcx[vc0 + row];
    f32x4 tm = *(const f32x4*)&Tm[row*132 + c4];
    f32x4 t2 = *(const f32x4*)&T2[row*132 + c4];
    f32x4 iv = *(const f32x4*)&inv2[qP0 + c4];
    f32x4 cv = *(const f32x4*)&cx[(long)(vc0+row)*4096 + qG0 + c4];
    f32x4 ov;
    #pragma unroll
    for (int j = 0; j < 4; ++j){
      float M = tm[j]*iv[j], M2 = t2[j]*iv[j];
      float var = M2 - M*M;
      float sd = sqrtf(fmaxf(var, 0.f));
      ov[j] = sd*(cv[j]-mu)*rs + M;
    }
    *(f32x4*)&outb[(long)(vc0+row)*4096 + qG0 + c4] = ov;
  }
}

// ---------- launch ----------
extern "C" void kernel_launch(void* const* d_in, const int* in_sizes, int n_in,
                              void* d_out, int out_size, void* d_ws, size_t ws_size,
                              hipStream_t stream){
  const float* c_x  = (const float*)d_in[0];
  const float* s_x  = (const float*)d_in[1];
  const float* c_1x = (const float*)d_in[2];
  const float* s_1x = (const float*)d_in[3];
  const float* f_w  = (const float*)d_in[4];
  const float* f_b  = (const float*)d_in[5];
  const float* g_w  = (const float*)d_in[6];
  const float* g_b  = (const float*)d_in[7];
  const float* h_w  = (const float*)d_in[8];
  const float* h_b  = (const float*)d_in[9];
  float* out = (float*)d_out;

  char* ws = (char*)d_ws;
  size_t off = 0;
  auto alloc = [&](size_t bytes)->void*{
    void* p = ws + off; off += (bytes + 255) & ~(size_t)255; return p;
  };
  float* meanQ = (float*)alloc(2048*4); float* rstdQ = (float*)alloc(2048*4);
  float* meanK = (float*)alloc(2048*4); float* rstdK = (float*)alloc(2048*4);
  float* meanC = (float*)alloc(2048*4); float* rstdC = (float*)alloc(2048*4);
  float* biasF = (float*)alloc(512*4);  float* biasG = (float*)alloc(512*4);
  unsigned short* Wfh = (unsigned short*)alloc((size_t)512*512*2);
  unsigned short* Wfl = (unsigned short*)alloc((size_t)512*512*2);
  unsigned short* Wgh = (unsigned short*)alloc((size_t)512*512*2);
  unsigned short* Wgl = (unsigned short*)alloc((size_t)512*512*2);
  unsigned short* Whh = (unsigned short*)alloc((size_t)512*512*2);
  unsigned short* Whl = (unsigned short*)alloc((size_t)512*512*2);
  unsigned short* Qh = (unsigned short*)alloc((size_t)4096*512*2);
  unsigned short* Ql = (unsigned short*)alloc((size_t)4096*512*2);
  unsigned short* Kh = (unsigned short*)alloc((size_t)4096*512*2);
  unsigned short* Kl = (unsigned short*)alloc((size_t)4096*512*2);
  unsigned short* vh  = (unsigned short*)alloc((size_t)512*4096*2);
  unsigned short* vl  = (unsigned short*)alloc((size_t)512*4096*2);
  unsigned short* v2h = (unsigned short*)alloc((size_t)512*4096*2);
  unsigned short* v2l = (unsigned short*)alloc((size_t)512*4096*2);
  float* S    = (float*)alloc((size_t)2048*4096*4);   // fp32 S chunk
  float* inv2 = (float*)alloc(4096*4);

  size_t pbytes = (size_t)4096*4096*2;
  bool bigP = (off + pbytes + 256 <= ws_size);
  unsigned short* Pb; long ppitch;
  if (bigP){ Pb = (unsigned short*)alloc(pbytes); ppitch = 4096; }
  else     { Pb = (unsigned short*)S;             ppitch = 8192; }

  rowstats_k<<<2048, 256, 0, stream>>>(c_1x, meanQ, rstdQ);
  rowstats_k<<<2048, 256, 0, stream>>>(s_1x, meanK, rstdK);
  rowstats_k<<<2048, 256, 0, stream>>>(c_x,  meanC, rstdC);
  wsplit_k<<<1024, 256, 0, stream>>>(h_w, Whh, Whl);

  for (int b = 0; b < 4; ++b){
    long xoff = (long)b * 512 * 4096;
    foldw_k<<<512, 256, 0, stream>>>(f_w, f_b, meanQ + b*512, rstdQ + b*512, Wfh, Wfl, biasF);
    foldw_k<<<512, 256, 0, stream>>>(g_w, g_b, meanK + b*512, rstdK + b*512, Wgh, Wgl, biasG);
    conv3_k<0><<<dim3(64,4), 512, 0, stream>>>(c_1x + xoff, Wfh, Wfl, biasF, Qh, Ql, nullptr, nullptr);
    conv3_k<0><<<dim3(64,4), 512, 0, stream>>>(s_1x + xoff, Wgh, Wgl, biasG, Kh, Kl, nullptr, nullptr);
    conv3_k<1><<<dim3(64,4), 512, 0, stream>>>(s_x + xoff, Whh, Whl, h_b, vh, vl, v2h, v2l);
    if (bigP){
      for (int ch = 0; ch < 2; ++ch){
        int qbase = ch * 2048;
        sgemm3_k<<<dim3(16,16), 512, 0, stream>>>(Qh, Ql, Kh, Kl, S, qbase);
        softmax_k<<<2048, 256, 0, stream>>>(S, Pb, 4096, qbase, inv2);
      }
      pv2_k<<<dim3(32,8), 512, 0, stream>>>(Pb, 4096, vh, vl, v2h, v2l, inv2,
                                            c_x + xoff, meanC + b*512, rstdC + b*512,
                                            out + xoff, 0, 0);
    } else {
      for (int ch = 0; ch < 2; ++ch){
        int qbase = ch * 2048;
        sgemm3_k<<<dim3(16,16), 512, 0, stream>>>(Qh, Ql, Kh, Kl, S, qbase);
        softmax_k<<<2048, 256, 0, stream>>>(S, Pb, 8192, 0, inv2);
        pv2_k<<<dim3(16,8), 512, 0, stream>>>(Pb, 8192, vh, vl, v2h, v2l, inv2,
                                              c_x + xoff, meanC + b*512, rstdC + b*512,
                                              out + xoff, 0, qbase);
      }
    }
  }
}

// Round 10
// 798.008 us; speedup vs baseline: 1.1569x; 1.0317x over previous
//
#include <hip/hip_runtime.h>
#include <math.h>

typedef __attribute__((ext_vector_type(8))) short short8;    // 8 x bf16
typedef __attribute__((ext_vector_type(4))) float f32x4;
typedef __attribute__((ext_vector_type(4))) unsigned short u16x4;

#define DEVINL static __device__ __forceinline__
#define MFMA __builtin_amdgcn_mfma_f32_16x16x32_bf16

DEVINL unsigned short f2bf(float f){
  union { float f; unsigned u; } v; v.f = f;
  unsigned r = v.u + 0x7FFFu + ((v.u >> 16) & 1u);   // RNE
  return (unsigned short)(r >> 16);
}
DEVINL float bf2f(unsigned short h){
  union { unsigned u; float f; } v; v.u = ((unsigned)h) << 16;
  return v.f;
}
DEVINL void gload16(const void* g, void* l){
  __builtin_amdgcn_global_load_lds(
      (const __attribute__((address_space(1))) void*)g,
      (__attribute__((address_space(3))) void*)l, 16, 0, 0);
}

// B=4, C=QK=V=512, L=4096
__global__ void rowstats_k(const float* __restrict__ x,
                           float* __restrict__ mean, float* __restrict__ rstd){
  int row = blockIdx.x;
  const float4* p = (const float4*)(x + (long)row * 4096);
  float s = 0.f, ss = 0.f;
  for (int i = threadIdx.x; i < 1024; i += 256){
    float4 v = p[i];
    s  += v.x + v.y + v.z + v.w;
    ss += v.x*v.x + v.y*v.y + v.z*v.z + v.w*v.w;
  }
  for (int o = 32; o > 0; o >>= 1){ s += __shfl_down(s, o); ss += __shfl_down(ss, o); }
  __shared__ float ls[4], lss[4];
  int wv = threadIdx.x >> 6;
  if ((threadIdx.x & 63) == 0){ ls[wv] = s; lss[wv] = ss; }
  __syncthreads();
  if (threadIdx.x == 0){
    s = ls[0]+ls[1]+ls[2]+ls[3]; ss = lss[0]+lss[1]+lss[2]+lss[3];
    float m = s * (1.f/4096.f);
    float var = (ss - s*m) * (1.f/4095.f);
    mean[row] = m;
    rstd[row] = 1.f / sqrtf(var + 1e-5f);
  }
}

__global__ void foldw_k(const float* __restrict__ w, const float* __restrict__ bias,
                        const float* __restrict__ mean, const float* __restrict__ rstd,
                        unsigned short* __restrict__ wh, unsigned short* __restrict__ wl,
                        float* __restrict__ biasp){
  int o = blockIdx.x;
  const float* wr = w + (long)o * 512;
  float part = 0.f;
  for (int c = threadIdx.x; c < 512; c += 256){
    float wv = wr[c] * rstd[c];
    unsigned short h = f2bf(wv);
    wh[(o<<9)+c] = h;
    wl[(o<<9)+c] = f2bf(wv - bf2f(h));
    part += wv * mean[c];
  }
  __shared__ float red[256];
  red[threadIdx.x] = part; __syncthreads();
  for (int st = 128; st > 0; st >>= 1){
    if (threadIdx.x < st) red[threadIdx.x] += red[threadIdx.x + st];
    __syncthreads();
  }
  if (threadIdx.x == 0) biasp[o] = bias[o] - red[0];
}

__global__ void wsplit_k(const float* __restrict__ w,
                         unsigned short* __restrict__ wh, unsigned short* __restrict__ wl){
  int i = blockIdx.x * 256 + threadIdx.x;
  float v = w[i];
  unsigned short h = f2bf(v);
  wh[i] = h; wl[i] = f2bf(v - bf2f(h));
}

// ---------- 3-term conv GEMM, pipelined ----------
template<int MODE>
__global__ __launch_bounds__(512) void conv3_k(
    const float* __restrict__ X,
    const unsigned short* __restrict__ Wh, const unsigned short* __restrict__ Wl,
    const float* __restrict__ biasp,
    unsigned short* __restrict__ oh, unsigned short* __restrict__ ol,
    unsigned short* __restrict__ o2h, unsigned short* __restrict__ o2l)
{
  int ob = blockIdx.y, lb = blockIdx.x;
  __shared__ __align__(16) char csm[36864];
  typedef unsigned short (*XT)[64][72];
  XT Xh = (XT)csm;                 // [2][64][72]
  XT Xl = (XT)(csm + 18432);       // [2][64][72]

  int tid = threadIdx.x, w = tid >> 6, lane = tid & 63, lr = lane & 15, lg = lane >> 4;
  const unsigned short* WhB = Wh + (long)(ob*128 + w*16) * 512;
  const unsigned short* WlB = Wl + (long)(ob*128 + w*16) * 512;
  int sl = tid & 63, scg = tid >> 6;
  const float* Xg = X + (long)(scg*8)*4096 + lb*64 + sl;

  f32x4 acc[4] = {};
  float fA[8], fB[8];
  short8 wA0, wA1, wA2, wA3, wB0, wB1, wB2, wB3;

#define CV_XLOAD(F, CB) { _Pragma("unroll") for (int j=0;j<8;++j) F[j] = Xg[(long)((CB)*64 + j)*4096]; }
#define CV_XWRITE(BUF, F) { short8 hv, lv; _Pragma("unroll") for (int j=0;j<8;++j){ \
    unsigned short h_ = f2bf(F[j]); hv[j] = (short)h_; lv[j] = (short)f2bf(F[j] - bf2f(h_)); } \
    *(short8*)&Xh[BUF][sl][scg*8] = hv; *(short8*)&Xl[BUF][sl][scg*8] = lv; }
#define CV_WLOAD(W0,W1,W2,W3, CB) { \
    W0 = *(const short8*)(WhB + (long)lr*512 + (CB)*64 + lg*8); \
    W1 = *(const short8*)(WhB + (long)lr*512 + (CB)*64 + 32 + lg*8); \
    W2 = *(const short8*)(WlB + (long)lr*512 + (CB)*64 + lg*8); \
    W3 = *(const short8*)(WlB + (long)lr*512 + (CB)*64 + 32 + lg*8); }
#define CV_COMPUTE(BUF, W0,W1,W2,W3) { \
    _Pragma("unroll") for (int ct=0;ct<4;++ct){ \
      short8 bh = *(const short8*)&Xh[BUF][ct*16+lr][lg*8]; \
      short8 bl = *(const short8*)&Xl[BUF][ct*16+lr][lg*8]; \
      acc[ct] = MFMA(W0, bh, acc[ct], 0,0,0); \
      acc[ct] = MFMA(W2, bh, acc[ct], 0,0,0); \
      acc[ct] = MFMA(W0, bl, acc[ct], 0,0,0); } \
    _Pragma("unroll") for (int ct=0;ct<4;++ct){ \
      short8 bh = *(const short8*)&Xh[BUF][ct*16+lr][32+lg*8]; \
      short8 bl = *(const short8*)&Xl[BUF][ct*16+lr][32+lg*8]; \
      acc[ct] = MFMA(W1, bh, acc[ct], 0,0,0); \
      acc[ct] = MFMA(W3, bh, acc[ct], 0,0,0); \
      acc[ct] = MFMA(W1, bl, acc[ct], 0,0,0); } }

  CV_XLOAD(fA, 0); CV_XWRITE(0, fA);
  CV_XLOAD(fA, 1);
  CV_WLOAD(wA0,wA1,wA2,wA3, 0);
  __syncthreads();
  for (int cb = 0; cb < 8; cb += 2){
    if (cb+2 < 8) CV_XLOAD(fB, cb+2);
    CV_WLOAD(wB0,wB1,wB2,wB3, cb+1);
    CV_COMPUTE(0, wA0,wA1,wA2,wA3);
    CV_XWRITE(1, fA);
    __syncthreads();
    if (cb+3 < 8) CV_XLOAD(fA, cb+3);
    if (cb+2 < 8) CV_WLOAD(wA0,wA1,wA2,wA3, cb+2);
    CV_COMPUTE(1, wB0,wB1,wB2,wB3);
    if (cb+2 < 8) CV_XWRITE(0, fB);
    __syncthreads();
  }

  int o4 = ob*128 + w*16 + lg*4;
  float bv[4];
  #pragma unroll
  for (int r = 0; r < 4; ++r) bv[r] = biasp[o4 + r];
  if (MODE == 0){
    #pragma unroll
    for (int ct = 0; ct < 4; ++ct){
      u16x4 ph, pl;
      #pragma unroll
      for (int r = 0; r < 4; ++r){
        float y = acc[ct][r] + bv[r];
        unsigned short h = f2bf(y);
        ph[r] = h; pl[r] = f2bf(y - bf2f(h));
      }
      long base = ((long)(lb*64 + ct*16 + lr)) * 512 + o4;
      *(u16x4*)(oh + base) = ph;
      *(u16x4*)(ol + base) = pl;
    }
  } else {
    // V path: vh = bf16(y); v2 = vh*vh exactly (16-bit product), split EXACTLY
    // into v2h+v2l. Consistency: M = P@vh, M2 = P@vh^2 -> Var >= 0 structurally.
    unsigned short sh_[16], s2h_[16], s2l_[16];
    #pragma unroll
    for (int ct = 0; ct < 4; ++ct)
      #pragma unroll
      for (int r = 0; r < 4; ++r){
        float y = acc[ct][r] + bv[r];
        unsigned short h = f2bf(y);
        float vhf = bf2f(h);
        float v2 = vhf * vhf;
        unsigned short h2 = f2bf(v2);
        unsigned short l2 = f2bf(v2 - bf2f(h2));   // exact residual
        sh_[ct*4+r] = h; s2h_[ct*4+r] = h2; s2l_[ct*4+r] = l2;
      }
    unsigned short* T = (unsigned short*)csm;   // [128][72]
#define CV_STORE(ARR, DST) { \
    __syncthreads(); \
    _Pragma("unroll") for (int ct=0;ct<4;++ct) \
      _Pragma("unroll") for (int r=0;r<4;++r) \
        T[(w*16+lg*4+r)*72 + ct*16+lr] = ARR[ct*4+r]; \
    __syncthreads(); \
    _Pragma("unroll") for (int s_=0;s_<2;++s_){ \
      int slot = tid + s_*512; int row = slot>>3, ch=(slot&7)*8; \
      *(short8*)(DST + (long)(ob*128+row)*4096 + lb*64 + ch) = *(const short8*)&T[row*72+ch]; } }
    CV_STORE(sh_,  oh);
    CV_STORE(s2h_, o2h);
    CV_STORE(s2l_, o2l);
#undef CV_STORE
  }
#undef CV_XLOAD
#undef CV_XWRITE
#undef CV_WLOAD
#undef CV_COMPUTE
}

// ---------- 3-term S GEMM: 128q x 256k tile, wave = 64x64 (as=4 x bs=4) ----------
// pitch 64 + XOR 16B-unit swizzle (u ^= row&7): conflict-free, LDS 96 KB.
__global__ __launch_bounds__(512) void sgemm3_k(
    const unsigned short* __restrict__ Qh, const unsigned short* __restrict__ Ql,
    const unsigned short* __restrict__ Kh, const unsigned short* __restrict__ Kl,
    float* __restrict__ S, int qbase)
{
  int bx = blockIdx.x, by = blockIdx.y;
  int q0g = qbase + bx*128, k0 = by*256;
  __shared__ unsigned short Qhs[128][64], Qls[128][64];
  __shared__ unsigned short Khs[256][64], Kls[256][64];
  int tid = threadIdx.x, w = tid >> 6, lane = tid & 63, lr = lane & 15, lg = lane >> 4;
  int wr = w & 1, wc = w >> 1;
  int srow = tid >> 3, sch = (tid & 7)*8;
  int swu = ((tid & 7) ^ (srow & 7)) * 8;       // swizzled LDS write offset (shorts)
  int lr7 = lr & 7;
  short8 qr[4], kr[8];
  f32x4 acc[4][4] = {};

#define SG_LOAD(CB) { long c0_ = (long)(CB)*64 + sch; \
    _Pragma("unroll") for (int i = 0; i < 4; ++i){ \
      const unsigned short* src = (i < 2 ? Qh : Ql); \
      qr[i] = *(const short8*)(src + (long)(q0g + srow + (i&1)*64)*512 + c0_); } \
    _Pragma("unroll") for (int i = 0; i < 8; ++i){ \
      const unsigned short* src = (i < 4 ? Kh : Kl); \
      kr[i] = *(const short8*)(src + (long)(k0 + srow + (i&3)*64)*512 + c0_); } }
#define SG_WRITE { \
    _Pragma("unroll") for (int i = 0; i < 4; ++i){ \
      if (i < 2) *(short8*)&Qhs[srow + (i&1)*64][swu] = qr[i]; \
      else       *(short8*)&Qls[srow + (i&1)*64][swu] = qr[i]; } \
    _Pragma("unroll") for (int i = 0; i < 8; ++i){ \
      if (i < 4) *(short8*)&Khs[srow + (i&3)*64][swu] = kr[i]; \
      else       *(short8*)&Kls[srow + (i&3)*64][swu] = kr[i]; } }

  SG_LOAD(0); SG_WRITE;
  __syncthreads();
  for (int cb = 0; cb < 8; ++cb){
    if (cb < 7) SG_LOAD(cb+1);
    #pragma unroll
    for (int kk = 0; kk < 2; ++kk){
      int un = ((kk*4 + lg) ^ lr7) * 8;         // swizzled read offset
      short8 bh[4], bl[4];
      #pragma unroll
      for (int bs = 0; bs < 4; ++bs){
        int krow = wc*64 + bs*16 + lr;
        bh[bs] = *(const short8*)(&Khs[krow][un]);
        bl[bs] = *(const short8*)(&Kls[krow][un]);
      }
      #pragma unroll
      for (int as = 0; as < 4; ++as){
        int qrow = wr*64 + as*16 + lr;
        short8 ah = *(const short8*)(&Qhs[qrow][un]);
        short8 al = *(const short8*)(&Qls[qrow][un]);
        #pragma unroll
        for (int bs = 0; bs < 4; ++bs){
          acc[as][bs] = MFMA(ah, bh[bs], acc[as][bs], 0,0,0);
          acc[as][bs] = MFMA(al, bh[bs], acc[as][bs], 0,0,0);
          acc[as][bs] = MFMA(ah, bl[bs], acc[as][bs], 0,0,0);
        }
      }
    }
    __syncthreads();
    if (cb < 7){ SG_WRITE; __syncthreads(); }
  }
#undef SG_LOAD
#undef SG_WRITE
  #pragma unroll
  for (int as = 0; as < 4; ++as){
    #pragma unroll
    for (int bs = 0; bs < 4; ++bs){
      int q = bx*128 + wr*64 + as*16 + lg*4;
      int k = k0 + wc*64 + bs*16 + lr;
      float* Sp = S + (long)q*4096 + k;
      #pragma unroll
      for (int r = 0; r < 4; ++r) Sp[(long)r*4096] = acc[as][bs][r];
    }
  }
}

// ---------- row softmax ----------
__global__ __launch_bounds__(256) void softmax_k(const float* __restrict__ S,
                                                 unsigned short* __restrict__ Pb, long pitch,
                                                 int row0, float* __restrict__ inv2){
  int row = blockIdx.x;
  const float* Sr = S + (long)row * 4096;
  int t = threadIdx.x;
  f32x4 v[4];
  #pragma unroll
  for (int i = 0; i < 4; ++i) v[i] = *(const f32x4*)(Sr + t*4 + i*1024);
  float mx = v[0][0];
  #pragma unroll
  for (int i = 0; i < 4; ++i)
    #pragma unroll
    for (int j = 0; j < 4; ++j) mx = fmaxf(mx, v[i][j]);
  #pragma unroll
  for (int o = 32; o > 0; o >>= 1) mx = fmaxf(mx, __shfl_xor(mx, o));
  __shared__ float red[4];
  int wid = t >> 6;
  if ((t & 63) == 0) red[wid] = mx;
  __syncthreads();
  mx = fmaxf(fmaxf(red[0], red[1]), fmaxf(red[2], red[3]));
  __syncthreads();
  float p[16]; float d = 0.f;
  #pragma unroll
  for (int i = 0; i < 4; ++i)
    #pragma unroll
    for (int j = 0; j < 4; ++j){ float e = expf(v[i][j] - mx); p[i*4+j] = e; d += e; }
  #pragma unroll
  for (int o = 32; o > 0; o >>= 1) d += __shfl_xor(d, o);
  if ((t & 63) == 0) red[wid] = d;
  __syncthreads();
  d = red[0] + red[1] + red[2] + red[3];
  __syncthreads();
  float invd = 1.f / d;
  unsigned short pb[16]; float d2 = 0.f;
  #pragma unroll
  for (int i = 0; i < 16; ++i){ pb[i] = f2bf(p[i] * invd); d2 += bf2f(pb[i]); }
  #pragma unroll
  for (int o = 32; o > 0; o >>= 1) d2 += __shfl_xor(d2, o);
  if ((t & 63) == 0) red[wid] = d2;
  __syncthreads();
  if (t == 0) inv2[row0 + row] = 1.f / (red[0]+red[1]+red[2]+red[3]);
  unsigned short* Pr = Pb + (long)(row0 + row) * pitch;
  #pragma unroll
  for (int i = 0; i < 4; ++i){
    u16x4 pk;
    #pragma unroll
    for (int j = 0; j < 4; ++j) pk[j] = pb[i*4+j];
    *(u16x4*)(Pr + t*4 + i*1024) = pk;
  }
}

// ---------- PV GEMM + epilogue ----------
// 3 MFMA chains: M = P@vh, M2 = P@v2h + P@v2l (v2 = vh^2 exact-split).
// gload_lds staging, LDS 80 KB -> 2 blocks/CU.
__global__ __launch_bounds__(512, 4) void pv2_k(
    const unsigned short* __restrict__ P, long ppitch,
    const unsigned short* __restrict__ vh,
    const unsigned short* __restrict__ v2h, const unsigned short* __restrict__ v2l,
    const float* __restrict__ inv2,
    const float* __restrict__ cx, const float* __restrict__ mcx, const float* __restrict__ rcx,
    float* __restrict__ outb, int qP_base, int qG_base)
{
  __shared__ __align__(16) char smem[81920];            // 80 KB
  typedef unsigned short (*PlT)[128][64];               // Pl[2][128][64] : 32768 B
  typedef unsigned short (*VlT)[3][64][64];             // Vl[2][3][64][64] : 49152 B
  PlT Pl = (PlT)smem;
  VlT Vl = (VlT)(smem + 32768);
  float* R = (float*)smem;                              // epilogue scratch (<= 67.5 KB used)

  int tid = threadIdx.x;
  int l = tid & 63, w = tid >> 6;
  int s = w & 1, wv = (w >> 1) & 1, wq = w >> 2;
  int lr = l & 15, lg = l >> 4;
  int qP0 = qP_base + blockIdx.x*128, qG0 = qG_base + blockIdx.x*128;
  int vc0 = blockIdx.y*64;

  int rowA = tid >> 3, c8 = (tid & 7)*8;
  int srcc = c8 ^ ((rowA & 7) * 8);                     // pre-swizzled source column
  int wb = w * 8;                                       // wave-uniform first staged row
  int un = ((s*4 + lg) ^ (lr & 7)) * 8;                 // swizzled LDS read offset
  const unsigned short* pgA = P + (long)(qP0 + rowA)*ppitch + srcc;
  const unsigned short* pgB = pgA + (long)64*ppitch;
  long vgo = (long)(vc0 + rowA)*4096 + srcc;
  const unsigned short* vg0 = vh  + vgo;
  const unsigned short* vg1 = v2h + vgo;
  const unsigned short* vg2 = v2l + vgo;

  f32x4 accM[4][2] = {}, acc2[4][2] = {};

#define PV_STAGE(BUF, TT) { long ko_ = (long)(TT)*64; \
    gload16(pgA + ko_, &Pl[BUF][wb][0]); \
    gload16(pgB + ko_, &Pl[BUF][64 + wb][0]); \
    gload16(vg0 + ko_, &Vl[BUF][0][wb][0]); \
    gload16(vg1 + ko_, &Vl[BUF][1][wb][0]); \
    gload16(vg2 + ko_, &Vl[BUF][2][wb][0]); }
#define PV_COMPUTE(BUF) { \
    short8 fh[2], f2h[2], f2l[2]; \
    _Pragma("unroll") for (int bs = 0; bs < 2; ++bs){ \
      int vrow = wv*32 + bs*16 + lr; \
      fh[bs]  = *(const short8*)(&Vl[BUF][0][vrow][un]); \
      f2h[bs] = *(const short8*)(&Vl[BUF][1][vrow][un]); \
      f2l[bs] = *(const short8*)(&Vl[BUF][2][vrow][un]); } \
    _Pragma("unroll") for (int aq = 0; aq < 4; ++aq){ \
      short8 pa = *(const short8*)(&Pl[BUF][wq*64 + aq*16 + lr][un]); \
      _Pragma("unroll") for (int bs = 0; bs < 2; ++bs){ \
        accM[aq][bs] = MFMA(pa, fh[bs],  accM[aq][bs], 0,0,0); \
        acc2[aq][bs] = MFMA(pa, f2h[bs], acc2[aq][bs], 0,0,0); \
        acc2[aq][bs] = MFMA(pa, f2l[bs], acc2[aq][bs], 0,0,0); } } }

  PV_STAGE(0, 0);
  __syncthreads();
  int cur = 0;
  for (int t = 0; t < 64; ++t){
    if (t < 63) PV_STAGE(cur ^ 1, t+1);
    PV_COMPUTE(cur);
    __syncthreads();
    cur ^= 1;
  }
#undef PV_STAGE
#undef PV_COMPUTE

  // ---- k-substep reduce: s=1 waves dump, s=0 partners add ----
  if (s == 1){
    float* Rb = R + (w>>1)*4096 + l*64;
    #pragma unroll
    for (int aq = 0; aq < 4; ++aq)
      #pragma unroll
      for (int bs = 0; bs < 2; ++bs)
        #pragma unroll
        for (int r = 0; r < 4; ++r){
          Rb[(aq*2+bs)*4 + r]      = accM[aq][bs][r];
          Rb[32 + (aq*2+bs)*4 + r] = acc2[aq][bs][r];
        }
  }
  __syncthreads();
  if (s == 0){
    const float* Rb = R + (w>>1)*4096 + l*64;
    #pragma unroll
    for (int aq = 0; aq < 4; ++aq)
      #pragma unroll
      for (int bs = 0; bs < 2; ++bs)
        #pragma unroll
        for (int r = 0; r < 4; ++r){
          accM[aq][bs][r] += Rb[(aq*2+bs)*4 + r];
          acc2[aq][bs][r] += Rb[32 + (aq*2+bs)*4 + r];
        }
  }
  __syncthreads();
  float* Tm = R;
  float* T2 = R + 64*132;
  if (s == 0){
    #pragma unroll
    for (int aq = 0; aq < 4; ++aq)
      #pragma unroll
      for (int bs = 0; bs < 2; ++bs){
        int vcl = wv*32 + bs*16 + lr;
        int ql = wq*64 + aq*16 + lg*4;
        #pragma unroll
        for (int r = 0; r < 4; ++r){
          Tm[vcl*132 + ql + r] = accM[aq][bs][r];
          T2[vcl*132 + ql + r] = acc2[aq][bs][r];
        }
      }
  }
  __syncthreads();
  #pragma unroll
  for (int p = 0; p < 4; ++p){
    int chunk = tid + p*512;
    int row = chunk >> 5, c4 = (chunk & 31)*4;
    float mu = mcx[vc0 + row], rs = rcx[vc0 + row];
    f32x4 tm = *(const f32x4*)&Tm[row*132 + c4];
    f32x4 t2 = *(const f32x4*)&T2[row*132 + c4];
    f32x4 iv = *(const f32x4*)&inv2[qP0 + c4];
    f32x4 cv = *(const f32x4*)&cx[(long)(vc0+row)*4096 + qG0 + c4];
    f32x4 ov;
    #pragma unroll
    for (int j = 0; j < 4; ++j){
      float M = tm[j]*iv[j], M2 = t2[j]*iv[j];
      float var = M2 - M*M;
      float sd = sqrtf(fmaxf(var, 0.f));
      ov[j] = sd*(cv[j]-mu)*rs + M;
    }
    *(f32x4*)&outb[(long)(vc0+row)*4096 + qG0 + c4] = ov;
  }
}

// ---------- launch ----------
extern "C" void kernel_launch(void* const* d_in, const int* in_sizes, int n_in,
                              void* d_out, int out_size, void* d_ws, size_t ws_size,
                              hipStream_t stream){
  const float* c_x  = (const float*)d_in[0];
  const float* s_x  = (const float*)d_in[1];
  const float* c_1x = (const float*)d_in[2];
  const float* s_1x = (const float*)d_in[3];
  const float* f_w  = (const float*)d_in[4];
  const float* f_b  = (const float*)d_in[5];
  const float* g_w  = (const float*)d_in[6];
  const float* g_b  = (const float*)d_in[7];
  const float* h_w  = (const float*)d_in[8];
  const float* h_b  = (const float*)d_in[9];
  float* out = (float*)d_out;

  char* ws = (char*)d_ws;
  size_t off = 0;
  auto alloc = [&](size_t bytes)->void*{
    void* p = ws + off; off += (bytes + 255) & ~(size_t)255; return p;
  };
  float* meanQ = (float*)alloc(2048*4); float* rstdQ = (float*)alloc(2048*4);
  float* meanK = (float*)alloc(2048*4); float* rstdK = (float*)alloc(2048*4);
  float* meanC = (float*)alloc(2048*4); float* rstdC = (float*)alloc(2048*4);
  float* biasF = (float*)alloc(512*4);  float* biasG = (float*)alloc(512*4);
  unsigned short* Wfh = (unsigned short*)alloc((size_t)512*512*2);
  unsigned short* Wfl = (unsigned short*)alloc((size_t)512*512*2);
  unsigned short* Wgh = (unsigned short*)alloc((size_t)512*512*2);
  unsigned short* Wgl = (unsigned short*)alloc((size_t)512*512*2);
  unsigned short* Whh = (unsigned short*)alloc((size_t)512*512*2);
  unsigned short* Whl = (unsigned short*)alloc((size_t)512*512*2);
  unsigned short* Qh = (unsigned short*)alloc((size_t)4096*512*2);
  unsigned short* Ql = (unsigned short*)alloc((size_t)4096*512*2);
  unsigned short* Kh = (unsigned short*)alloc((size_t)4096*512*2);
  unsigned short* Kl = (unsigned short*)alloc((size_t)4096*512*2);
  unsigned short* vh  = (unsigned short*)alloc((size_t)512*4096*2);
  unsigned short* v2h = (unsigned short*)alloc((size_t)512*4096*2);
  unsigned short* v2l = (unsigned short*)alloc((size_t)512*4096*2);
  float* S    = (float*)alloc((size_t)2048*4096*4);   // fp32 S chunk
  float* inv2 = (float*)alloc(4096*4);

  size_t pbytes = (size_t)4096*4096*2;
  bool bigP = (off + pbytes + 256 <= ws_size);
  unsigned short* Pb; long ppitch;
  if (bigP){ Pb = (unsigned short*)alloc(pbytes); ppitch = 4096; }
  else     { Pb = (unsigned short*)S;             ppitch = 8192; }

  rowstats_k<<<2048, 256, 0, stream>>>(c_1x, meanQ, rstdQ);
  rowstats_k<<<2048, 256, 0, stream>>>(s_1x, meanK, rstdK);
  rowstats_k<<<2048, 256, 0, stream>>>(c_x,  meanC, rstdC);
  wsplit_k<<<1024, 256, 0, stream>>>(h_w, Whh, Whl);

  for (int b = 0; b < 4; ++b){
    long xoff = (long)b * 512 * 4096;
    foldw_k<<<512, 256, 0, stream>>>(f_w, f_b, meanQ + b*512, rstdQ + b*512, Wfh, Wfl, biasF);
    foldw_k<<<512, 256, 0, stream>>>(g_w, g_b, meanK + b*512, rstdK + b*512, Wgh, Wgl, biasG);
    conv3_k<0><<<dim3(64,4), 512, 0, stream>>>(c_1x + xoff, Wfh, Wfl, biasF, Qh, Ql, nullptr, nullptr);
    conv3_k<0><<<dim3(64,4), 512, 0, stream>>>(s_1x + xoff, Wgh, Wgl, biasG, Kh, Kl, nullptr, nullptr);
    conv3_k<1><<<dim3(64,4), 512, 0, stream>>>(s_x + xoff, Whh, Whl, h_b, vh, nullptr, v2h, v2l);
    if (bigP){
      for (int ch = 0; ch < 2; ++ch){
        int qbase = ch * 2048;
        sgemm3_k<<<dim3(16,16), 512, 0, stream>>>(Qh, Ql, Kh, Kl, S, qbase);
        softmax_k<<<2048, 256, 0, stream>>>(S, Pb, 4096, qbase, inv2);
      }
      pv2_k<<<dim3(32,8), 512, 0, stream>>>(Pb, 4096, vh, v2h, v2l, inv2,
                                            c_x + xoff, meanC + b*512, rstdC + b*512,
                                            out + xoff, 0, 0);
    } else {
      for (int ch = 0; ch < 2; ++ch){
        int qbase = ch * 2048;
        sgemm3_k<<<dim3(16,16), 512, 0, stream>>>(Qh, Ql, Kh, Kl, S, qbase);
        softmax_k<<<2048, 256, 0, stream>>>(S, Pb, 8192, 0, inv2);
        pv2_k<<<dim3(16,8), 512, 0, stream>>>(Pb, 8192, vh, v2h, v2l, inv2,
                                              c_x + xoff, meanC + b*512, rstdC + b*512,
                                              out + xoff, 0, qbase);
      }
    }
  }
}

// Round 11
// 746.041 us; speedup vs baseline: 1.2375x; 1.0697x over previous
//
#include <hip/hip_runtime.h>
#include <math.h>

typedef __attribute__((ext_vector_type(8))) short short8;    // 8 x bf16
typedef __attribute__((ext_vector_type(4))) float f32x4;
typedef __attribute__((ext_vector_type(4))) unsigned short u16x4;

#define DEVINL static __device__ __forceinline__
#define MFMA __builtin_amdgcn_mfma_f32_16x16x32_bf16

DEVINL unsigned short f2bf(float f){
  union { float f; unsigned u; } v; v.f = f;
  unsigned r = v.u + 0x7FFFu + ((v.u >> 16) & 1u);   // RNE
  return (unsigned short)(r >> 16);
}
DEVINL float bf2f(unsigned short h){
  union { unsigned u; float f; } v; v.u = ((unsigned)h) << 16;
  return v.f;
}
DEVINL void gload16(const void* g, void* l){
  __builtin_amdgcn_global_load_lds(
      (const __attribute__((address_space(1))) void*)g,
      (__attribute__((address_space(3))) void*)l, 16, 0, 0);
}

// B=4, C=QK=V=512, L=4096
__global__ void rowstats_k(const float* __restrict__ x,
                           float* __restrict__ mean, float* __restrict__ rstd){
  int row = blockIdx.x;
  const float4* p = (const float4*)(x + (long)row * 4096);
  float s = 0.f, ss = 0.f;
  for (int i = threadIdx.x; i < 1024; i += 256){
    float4 v = p[i];
    s  += v.x + v.y + v.z + v.w;
    ss += v.x*v.x + v.y*v.y + v.z*v.z + v.w*v.w;
  }
  for (int o = 32; o > 0; o >>= 1){ s += __shfl_down(s, o); ss += __shfl_down(ss, o); }
  __shared__ float ls[4], lss[4];
  int wv = threadIdx.x >> 6;
  if ((threadIdx.x & 63) == 0){ ls[wv] = s; lss[wv] = ss; }
  __syncthreads();
  if (threadIdx.x == 0){
    s = ls[0]+ls[1]+ls[2]+ls[3]; ss = lss[0]+lss[1]+lss[2]+lss[3];
    float m = s * (1.f/4096.f);
    float var = (ss - s*m) * (1.f/4095.f);
    mean[row] = m;
    rstd[row] = 1.f / sqrtf(var + 1e-5f);
  }
}

__global__ void foldw_k(const float* __restrict__ w, const float* __restrict__ bias,
                        const float* __restrict__ mean, const float* __restrict__ rstd,
                        unsigned short* __restrict__ wh, unsigned short* __restrict__ wl,
                        float* __restrict__ biasp){
  int o = blockIdx.x;
  const float* wr = w + (long)o * 512;
  float part = 0.f;
  for (int c = threadIdx.x; c < 512; c += 256){
    float wv = wr[c] * rstd[c];
    unsigned short h = f2bf(wv);
    wh[(o<<9)+c] = h;
    wl[(o<<9)+c] = f2bf(wv - bf2f(h));
    part += wv * mean[c];
  }
  __shared__ float red[256];
  red[threadIdx.x] = part; __syncthreads();
  for (int st = 128; st > 0; st >>= 1){
    if (threadIdx.x < st) red[threadIdx.x] += red[threadIdx.x + st];
    __syncthreads();
  }
  if (threadIdx.x == 0) biasp[o] = bias[o] - red[0];
}

__global__ void wsplit_k(const float* __restrict__ w,
                         unsigned short* __restrict__ wh, unsigned short* __restrict__ wl){
  int i = blockIdx.x * 256 + threadIdx.x;
  float v = w[i];
  unsigned short h = f2bf(v);
  wh[i] = h; wl[i] = f2bf(v - bf2f(h));
}

// ---------- 3-term conv GEMM, pipelined ----------
template<int MODE>
__global__ __launch_bounds__(512) void conv3_k(
    const float* __restrict__ X,
    const unsigned short* __restrict__ Wh, const unsigned short* __restrict__ Wl,
    const float* __restrict__ biasp,
    unsigned short* __restrict__ oh, unsigned short* __restrict__ ol,
    unsigned short* __restrict__ o2h, unsigned short* __restrict__ o2l)
{
  int ob = blockIdx.y, lb = blockIdx.x;
  __shared__ __align__(16) char csm[36864];
  typedef unsigned short (*XT)[64][72];
  XT Xh = (XT)csm;                 // [2][64][72]
  XT Xl = (XT)(csm + 18432);       // [2][64][72]

  int tid = threadIdx.x, w = tid >> 6, lane = tid & 63, lr = lane & 15, lg = lane >> 4;
  const unsigned short* WhB = Wh + (long)(ob*128 + w*16) * 512;
  const unsigned short* WlB = Wl + (long)(ob*128 + w*16) * 512;
  int sl = tid & 63, scg = tid >> 6;
  const float* Xg = X + (long)(scg*8)*4096 + lb*64 + sl;

  f32x4 acc[4] = {};
  float fA[8], fB[8];
  short8 wA0, wA1, wA2, wA3, wB0, wB1, wB2, wB3;

#define CV_XLOAD(F, CB) { _Pragma("unroll") for (int j=0;j<8;++j) F[j] = Xg[(long)((CB)*64 + j)*4096]; }
#define CV_XWRITE(BUF, F) { short8 hv, lv; _Pragma("unroll") for (int j=0;j<8;++j){ \
    unsigned short h_ = f2bf(F[j]); hv[j] = (short)h_; lv[j] = (short)f2bf(F[j] - bf2f(h_)); } \
    *(short8*)&Xh[BUF][sl][scg*8] = hv; *(short8*)&Xl[BUF][sl][scg*8] = lv; }
#define CV_WLOAD(W0,W1,W2,W3, CB) { \
    W0 = *(const short8*)(WhB + (long)lr*512 + (CB)*64 + lg*8); \
    W1 = *(const short8*)(WhB + (long)lr*512 + (CB)*64 + 32 + lg*8); \
    W2 = *(const short8*)(WlB + (long)lr*512 + (CB)*64 + lg*8); \
    W3 = *(const short8*)(WlB + (long)lr*512 + (CB)*64 + 32 + lg*8); }
#define CV_COMPUTE(BUF, W0,W1,W2,W3) { \
    _Pragma("unroll") for (int ct=0;ct<4;++ct){ \
      short8 bh = *(const short8*)&Xh[BUF][ct*16+lr][lg*8]; \
      short8 bl = *(const short8*)&Xl[BUF][ct*16+lr][lg*8]; \
      acc[ct] = MFMA(W0, bh, acc[ct], 0,0,0); \
      acc[ct] = MFMA(W2, bh, acc[ct], 0,0,0); \
      acc[ct] = MFMA(W0, bl, acc[ct], 0,0,0); } \
    _Pragma("unroll") for (int ct=0;ct<4;++ct){ \
      short8 bh = *(const short8*)&Xh[BUF][ct*16+lr][32+lg*8]; \
      short8 bl = *(const short8*)&Xl[BUF][ct*16+lr][32+lg*8]; \
      acc[ct] = MFMA(W1, bh, acc[ct], 0,0,0); \
      acc[ct] = MFMA(W3, bh, acc[ct], 0,0,0); \
      acc[ct] = MFMA(W1, bl, acc[ct], 0,0,0); } }

  CV_XLOAD(fA, 0); CV_XWRITE(0, fA);
  CV_XLOAD(fA, 1);
  CV_WLOAD(wA0,wA1,wA2,wA3, 0);
  __syncthreads();
  for (int cb = 0; cb < 8; cb += 2){
    if (cb+2 < 8) CV_XLOAD(fB, cb+2);
    CV_WLOAD(wB0,wB1,wB2,wB3, cb+1);
    CV_COMPUTE(0, wA0,wA1,wA2,wA3);
    CV_XWRITE(1, fA);
    __syncthreads();
    if (cb+3 < 8) CV_XLOAD(fA, cb+3);
    if (cb+2 < 8) CV_WLOAD(wA0,wA1,wA2,wA3, cb+2);
    CV_COMPUTE(1, wB0,wB1,wB2,wB3);
    if (cb+2 < 8) CV_XWRITE(0, fB);
    __syncthreads();
  }

  int o4 = ob*128 + w*16 + lg*4;
  float bv[4];
  #pragma unroll
  for (int r = 0; r < 4; ++r) bv[r] = biasp[o4 + r];
  if (MODE == 0){
    #pragma unroll
    for (int ct = 0; ct < 4; ++ct){
      u16x4 ph, pl;
      #pragma unroll
      for (int r = 0; r < 4; ++r){
        float y = acc[ct][r] + bv[r];
        unsigned short h = f2bf(y);
        ph[r] = h; pl[r] = f2bf(y - bf2f(h));
      }
      long base = ((long)(lb*64 + ct*16 + lr)) * 512 + o4;
      *(u16x4*)(oh + base) = ph;
      *(u16x4*)(ol + base) = pl;
    }
  } else {
    // V path: vh = bf16(y); v2 = vh*vh exact product, exact split v2h+v2l.
    unsigned short sh_[16], s2h_[16], s2l_[16];
    #pragma unroll
    for (int ct = 0; ct < 4; ++ct)
      #pragma unroll
      for (int r = 0; r < 4; ++r){
        float y = acc[ct][r] + bv[r];
        unsigned short h = f2bf(y);
        float vhf = bf2f(h);
        float v2 = vhf * vhf;
        unsigned short h2 = f2bf(v2);
        unsigned short l2 = f2bf(v2 - bf2f(h2));
        sh_[ct*4+r] = h; s2h_[ct*4+r] = h2; s2l_[ct*4+r] = l2;
      }
    unsigned short* T = (unsigned short*)csm;   // [128][72]
#define CV_STORE(ARR, DST) { \
    __syncthreads(); \
    _Pragma("unroll") for (int ct=0;ct<4;++ct) \
      _Pragma("unroll") for (int r=0;r<4;++r) \
        T[(w*16+lg*4+r)*72 + ct*16+lr] = ARR[ct*4+r]; \
    __syncthreads(); \
    _Pragma("unroll") for (int s_=0;s_<2;++s_){ \
      int slot = tid + s_*512; int row = slot>>3, ch=(slot&7)*8; \
      *(short8*)(DST + (long)(ob*128+row)*4096 + lb*64 + ch) = *(const short8*)&T[row*72+ch]; } }
    CV_STORE(sh_,  oh);
    CV_STORE(s2h_, o2h);
    CV_STORE(s2l_, o2l);
#undef CV_STORE
  }
#undef CV_XLOAD
#undef CV_XWRITE
#undef CV_WLOAD
#undef CV_COMPUTE
}

// ---------- 3-term S GEMM: 128q x 256k tile, wave = 64x64 (as=4 x bs=4) ----------
__global__ __launch_bounds__(512) void sgemm3_k(
    const unsigned short* __restrict__ Qh, const unsigned short* __restrict__ Ql,
    const unsigned short* __restrict__ Kh, const unsigned short* __restrict__ Kl,
    float* __restrict__ S, int qbase)
{
  int bx = blockIdx.x, by = blockIdx.y;
  int q0g = qbase + bx*128, k0 = by*256;
  __shared__ unsigned short Qhs[128][64], Qls[128][64];
  __shared__ unsigned short Khs[256][64], Kls[256][64];
  int tid = threadIdx.x, w = tid >> 6, lane = tid & 63, lr = lane & 15, lg = lane >> 4;
  int wr = w & 1, wc = w >> 1;
  int srow = tid >> 3, sch = (tid & 7)*8;
  int swu = ((tid & 7) ^ (srow & 7)) * 8;
  int lr7 = lr & 7;
  short8 qr[4], kr[8];
  f32x4 acc[4][4] = {};

#define SG_LOAD(CB) { long c0_ = (long)(CB)*64 + sch; \
    _Pragma("unroll") for (int i = 0; i < 4; ++i){ \
      const unsigned short* src = (i < 2 ? Qh : Ql); \
      qr[i] = *(const short8*)(src + (long)(q0g + srow + (i&1)*64)*512 + c0_); } \
    _Pragma("unroll") for (int i = 0; i < 8; ++i){ \
      const unsigned short* src = (i < 4 ? Kh : Kl); \
      kr[i] = *(const short8*)(src + (long)(k0 + srow + (i&3)*64)*512 + c0_); } }
#define SG_WRITE { \
    _Pragma("unroll") for (int i = 0; i < 4; ++i){ \
      if (i < 2) *(short8*)&Qhs[srow + (i&1)*64][swu] = qr[i]; \
      else       *(short8*)&Qls[srow + (i&1)*64][swu] = qr[i]; } \
    _Pragma("unroll") for (int i = 0; i < 8; ++i){ \
      if (i < 4) *(short8*)&Khs[srow + (i&3)*64][swu] = kr[i]; \
      else       *(short8*)&Kls[srow + (i&3)*64][swu] = kr[i]; } }

  SG_LOAD(0); SG_WRITE;
  __syncthreads();
  for (int cb = 0; cb < 8; ++cb){
    if (cb < 7) SG_LOAD(cb+1);
    #pragma unroll
    for (int kk = 0; kk < 2; ++kk){
      int un = ((kk*4 + lg) ^ lr7) * 8;
      short8 bh[4], bl[4];
      #pragma unroll
      for (int bs = 0; bs < 4; ++bs){
        int krow = wc*64 + bs*16 + lr;
        bh[bs] = *(const short8*)(&Khs[krow][un]);
        bl[bs] = *(const short8*)(&Kls[krow][un]);
      }
      #pragma unroll
      for (int as = 0; as < 4; ++as){
        int qrow = wr*64 + as*16 + lr;
        short8 ah = *(const short8*)(&Qhs[qrow][un]);
        short8 al = *(const short8*)(&Qls[qrow][un]);
        #pragma unroll
        for (int bs = 0; bs < 4; ++bs){
          acc[as][bs] = MFMA(ah, bh[bs], acc[as][bs], 0,0,0);
          acc[as][bs] = MFMA(al, bh[bs], acc[as][bs], 0,0,0);
          acc[as][bs] = MFMA(ah, bl[bs], acc[as][bs], 0,0,0);
        }
      }
    }
    __syncthreads();
    if (cb < 7){ SG_WRITE; __syncthreads(); }
  }
#undef SG_LOAD
#undef SG_WRITE
  #pragma unroll
  for (int as = 0; as < 4; ++as){
    #pragma unroll
    for (int bs = 0; bs < 4; ++bs){
      int q = bx*128 + wr*64 + as*16 + lg*4;
      int k = k0 + wc*64 + bs*16 + lr;
      float* Sp = S + (long)q*4096 + k;
      #pragma unroll
      for (int r = 0; r < 4; ++r) Sp[(long)r*4096] = acc[as][bs][r];
    }
  }
}

// ---------- row softmax ----------
__global__ __launch_bounds__(256) void softmax_k(const float* __restrict__ S,
                                                 unsigned short* __restrict__ Pb, long pitch,
                                                 int row0, float* __restrict__ inv2){
  int row = blockIdx.x;
  const float* Sr = S + (long)row * 4096;
  int t = threadIdx.x;
  f32x4 v[4];
  #pragma unroll
  for (int i = 0; i < 4; ++i) v[i] = *(const f32x4*)(Sr + t*4 + i*1024);
  float mx = v[0][0];
  #pragma unroll
  for (int i = 0; i < 4; ++i)
    #pragma unroll
    for (int j = 0; j < 4; ++j) mx = fmaxf(mx, v[i][j]);
  #pragma unroll
  for (int o = 32; o > 0; o >>= 1) mx = fmaxf(mx, __shfl_xor(mx, o));
  __shared__ float red[4];
  int wid = t >> 6;
  if ((t & 63) == 0) red[wid] = mx;
  __syncthreads();
  mx = fmaxf(fmaxf(red[0], red[1]), fmaxf(red[2], red[3]));
  __syncthreads();
  float p[16]; float d = 0.f;
  #pragma unroll
  for (int i = 0; i < 4; ++i)
    #pragma unroll
    for (int j = 0; j < 4; ++j){ float e = expf(v[i][j] - mx); p[i*4+j] = e; d += e; }
  #pragma unroll
  for (int o = 32; o > 0; o >>= 1) d += __shfl_xor(d, o);
  if ((t & 63) == 0) red[wid] = d;
  __syncthreads();
  d = red[0] + red[1] + red[2] + red[3];
  __syncthreads();
  float invd = 1.f / d;
  unsigned short pb[16]; float d2 = 0.f;
  #pragma unroll
  for (int i = 0; i < 16; ++i){ pb[i] = f2bf(p[i] * invd); d2 += bf2f(pb[i]); }
  #pragma unroll
  for (int o = 32; o > 0; o >>= 1) d2 += __shfl_xor(d2, o);
  if ((t & 63) == 0) red[wid] = d2;
  __syncthreads();
  if (t == 0) inv2[row0 + row] = 1.f / (red[0]+red[1]+red[2]+red[3]);
  unsigned short* Pr = Pb + (long)(row0 + row) * pitch;
  #pragma unroll
  for (int i = 0; i < 4; ++i){
    u16x4 pk;
    #pragma unroll
    for (int j = 0; j < 4; ++j) pk[j] = pb[i*4+j];
    *(u16x4*)(Pr + t*4 + i*1024) = pk;
  }
}

// ---------- PV GEMM + epilogue ----------
// 256-thread blocks, 64q x 64vc tile, grid (64,8) = 512 blocks -> 2 blocks/CU
// (LDS 64 KB). Wave w stages array w (P, vh, v2h, v2l) via gload16; waves
// compute 32q x 32vc quadrants over full k. Same swizzle math as r9/r10.
__global__ __launch_bounds__(256, 2) void pv2_k(
    const unsigned short* __restrict__ P, long ppitch,
    const unsigned short* __restrict__ vh,
    const unsigned short* __restrict__ v2h, const unsigned short* __restrict__ v2l,
    const float* __restrict__ inv2,
    const float* __restrict__ cx, const float* __restrict__ mcx, const float* __restrict__ rcx,
    float* __restrict__ outb, int qP_base, int qG_base)
{
  __shared__ __align__(16) char smem[65536];            // 64 KB
  typedef unsigned short (*PlT)[64][64];                // Pl[2][64][64] : 16384 B
  typedef unsigned short (*VlT)[3][64][64];             // Vl[2][3][64][64] : 49152 B
  PlT Pl = (PlT)smem;
  VlT Vl = (VlT)(smem + 16384);
  float* R = (float*)smem;                              // epilogue scratch (17.4 KB used)

  int tid = threadIdx.x;
  int l = tid & 63, w = tid >> 6;                       // 4 waves
  int wq = w >> 1, wv = w & 1;
  int lr = l & 15, lg = l >> 4;
  int qP0 = qP_base + blockIdx.x*64, qG0 = qG_base + blockIdx.x*64;
  int vc0 = blockIdx.y*64;

  // staging: wave w stages its array; lane covers row (l>>3), cols (l&7)*8,
  // source column pre-swizzled so LDS[row][u] == G[row][u ^ (row&7)*8].
  int r8_ = l >> 3, c8 = (l & 7)*8;
  int srcc = c8 ^ (r8_*8);
  const unsigned short* gsrc;
  long rs8;
  unsigned short *l0, *l1;
  if (w == 0){
    gsrc = P + (long)(qP0 + r8_)*ppitch + srcc;
    rs8 = (long)8*ppitch;
    l0 = &Pl[0][0][0]; l1 = &Pl[1][0][0];
  } else {
    const unsigned short* va = (w==1 ? vh : w==2 ? v2h : v2l);
    gsrc = va + (long)(vc0 + r8_)*4096 + srcc;
    rs8 = (long)8*4096;
    l0 = &Vl[0][w-1][0][0]; l1 = &Vl[1][w-1][0][0];
  }

  f32x4 accM[2][2] = {}, acc2[2][2] = {};

#define PV_STAGE(LB, TT) { long ko_ = (long)(TT)*64; \
    _Pragma("unroll") for (int j = 0; j < 8; ++j) \
      gload16(gsrc + j*rs8 + ko_, LB + j*512); }
#define PV_COMPUTE(BUF) { \
    _Pragma("unroll") for (int kk = 0; kk < 2; ++kk){ \
      int un = ((kk*4 + lg) ^ (lr & 7)) * 8; \
      short8 fh[2], f2h[2], f2l[2]; \
      _Pragma("unroll") for (int bs = 0; bs < 2; ++bs){ \
        int vrow = wv*32 + bs*16 + lr; \
        fh[bs]  = *(const short8*)(&Vl[BUF][0][vrow][un]); \
        f2h[bs] = *(const short8*)(&Vl[BUF][1][vrow][un]); \
        f2l[bs] = *(const short8*)(&Vl[BUF][2][vrow][un]); } \
      _Pragma("unroll") for (int aq = 0; aq < 2; ++aq){ \
        short8 pa = *(const short8*)(&Pl[BUF][wq*32 + aq*16 + lr][un]); \
        _Pragma("unroll") for (int bs = 0; bs < 2; ++bs){ \
          accM[aq][bs] = MFMA(pa, fh[bs],  accM[aq][bs], 0,0,0); \
          acc2[aq][bs] = MFMA(pa, f2h[bs], acc2[aq][bs], 0,0,0); \
          acc2[aq][bs] = MFMA(pa, f2l[bs], acc2[aq][bs], 0,0,0); } } } }

  PV_STAGE(l0, 0);
  __syncthreads();
  for (int t = 0; t < 64; ++t){
    unsigned short* nb = (t & 1) ? l0 : l1;   // tile t+1 goes to buf (t+1)&1
    if (t < 63) PV_STAGE(nb, t+1);
    int buf = t & 1;
    PV_COMPUTE(buf);
    __syncthreads();
  }
#undef PV_STAGE
#undef PV_COMPUTE

  // ---- epilogue: two-pass transpose [64 vc][68] then blend ----
  float* Tm = R;
  #pragma unroll
  for (int aq = 0; aq < 2; ++aq)
    #pragma unroll
    for (int bs = 0; bs < 2; ++bs){
      int vcl = wv*32 + bs*16 + lr;
      int ql  = wq*32 + aq*16 + lg*4;
      #pragma unroll
      for (int r = 0; r < 4; ++r) Tm[vcl*68 + ql + r] = accM[aq][bs][r];
    }
  __syncthreads();
  f32x4 Mv[4];
  #pragma unroll
  for (int p = 0; p < 4; ++p){
    int chunk = tid + p*256;
    int row = chunk >> 4, c4 = (chunk & 15)*4;
    Mv[p] = *(const f32x4*)&Tm[row*68 + c4];
  }
  __syncthreads();
  #pragma unroll
  for (int aq = 0; aq < 2; ++aq)
    #pragma unroll
    for (int bs = 0; bs < 2; ++bs){
      int vcl = wv*32 + bs*16 + lr;
      int ql  = wq*32 + aq*16 + lg*4;
      #pragma unroll
      for (int r = 0; r < 4; ++r) Tm[vcl*68 + ql + r] = acc2[aq][bs][r];
    }
  __syncthreads();
  #pragma unroll
  for (int p = 0; p < 4; ++p){
    int chunk = tid + p*256;
    int row = chunk >> 4, c4 = (chunk & 15)*4;
    float mu = mcx[vc0 + row], rs = rcx[vc0 + row];
    f32x4 t2 = *(const f32x4*)&Tm[row*68 + c4];
    f32x4 iv = *(const f32x4*)&inv2[qP0 + c4];
    f32x4 cv = *(const f32x4*)&cx[(long)(vc0+row)*4096 + qG0 + c4];
    f32x4 ov;
    #pragma unroll
    for (int j = 0; j < 4; ++j){
      float M = Mv[p][j]*iv[j], M2 = t2[j]*iv[j];
      float var = M2 - M*M;
      float sd = sqrtf(fmaxf(var, 0.f));
      ov[j] = sd*(cv[j]-mu)*rs + M;
    }
    *(f32x4*)&outb[(long)(vc0+row)*4096 + qG0 + c4] = ov;
  }
}

// ---------- launch ----------
extern "C" void kernel_launch(void* const* d_in, const int* in_sizes, int n_in,
                              void* d_out, int out_size, void* d_ws, size_t ws_size,
                              hipStream_t stream){
  const float* c_x  = (const float*)d_in[0];
  const float* s_x  = (const float*)d_in[1];
  const float* c_1x = (const float*)d_in[2];
  const float* s_1x = (const float*)d_in[3];
  const float* f_w  = (const float*)d_in[4];
  const float* f_b  = (const float*)d_in[5];
  const float* g_w  = (const float*)d_in[6];
  const float* g_b  = (const float*)d_in[7];
  const float* h_w  = (const float*)d_in[8];
  const float* h_b  = (const float*)d_in[9];
  float* out = (float*)d_out;

  char* ws = (char*)d_ws;
  size_t off = 0;
  auto alloc = [&](size_t bytes)->void*{
    void* p = ws + off; off += (bytes + 255) & ~(size_t)255; return p;
  };
  float* meanQ = (float*)alloc(2048*4); float* rstdQ = (float*)alloc(2048*4);
  float* meanK = (float*)alloc(2048*4); float* rstdK = (float*)alloc(2048*4);
  float* meanC = (float*)alloc(2048*4); float* rstdC = (float*)alloc(2048*4);
  float* biasF = (float*)alloc(512*4);  float* biasG = (float*)alloc(512*4);
  unsigned short* Wfh = (unsigned short*)alloc((size_t)512*512*2);
  unsigned short* Wfl = (unsigned short*)alloc((size_t)512*512*2);
  unsigned short* Wgh = (unsigned short*)alloc((size_t)512*512*2);
  unsigned short* Wgl = (unsigned short*)alloc((size_t)512*512*2);
  unsigned short* Whh = (unsigned short*)alloc((size_t)512*512*2);
  unsigned short* Whl = (unsigned short*)alloc((size_t)512*512*2);
  unsigned short* Qh = (unsigned short*)alloc((size_t)4096*512*2);
  unsigned short* Ql = (unsigned short*)alloc((size_t)4096*512*2);
  unsigned short* Kh = (unsigned short*)alloc((size_t)4096*512*2);
  unsigned short* Kl = (unsigned short*)alloc((size_t)4096*512*2);
  unsigned short* vh  = (unsigned short*)alloc((size_t)512*4096*2);
  unsigned short* v2h = (unsigned short*)alloc((size_t)512*4096*2);
  unsigned short* v2l = (unsigned short*)alloc((size_t)512*4096*2);
  float* S    = (float*)alloc((size_t)2048*4096*4);   // fp32 S chunk
  float* inv2 = (float*)alloc(4096*4);

  size_t pbytes = (size_t)4096*4096*2;
  bool bigP = (off + pbytes + 256 <= ws_size);
  unsigned short* Pb; long ppitch;
  if (bigP){ Pb = (unsigned short*)alloc(pbytes); ppitch = 4096; }
  else     { Pb = (unsigned short*)S;             ppitch = 8192; }

  rowstats_k<<<2048, 256, 0, stream>>>(c_1x, meanQ, rstdQ);
  rowstats_k<<<2048, 256, 0, stream>>>(s_1x, meanK, rstdK);
  rowstats_k<<<2048, 256, 0, stream>>>(c_x,  meanC, rstdC);
  wsplit_k<<<1024, 256, 0, stream>>>(h_w, Whh, Whl);

  for (int b = 0; b < 4; ++b){
    long xoff = (long)b * 512 * 4096;
    foldw_k<<<512, 256, 0, stream>>>(f_w, f_b, meanQ + b*512, rstdQ + b*512, Wfh, Wfl, biasF);
    foldw_k<<<512, 256, 0, stream>>>(g_w, g_b, meanK + b*512, rstdK + b*512, Wgh, Wgl, biasG);
    conv3_k<0><<<dim3(64,4), 512, 0, stream>>>(c_1x + xoff, Wfh, Wfl, biasF, Qh, Ql, nullptr, nullptr);
    conv3_k<0><<<dim3(64,4), 512, 0, stream>>>(s_1x + xoff, Wgh, Wgl, biasG, Kh, Kl, nullptr, nullptr);
    conv3_k<1><<<dim3(64,4), 512, 0, stream>>>(s_x + xoff, Whh, Whl, h_b, vh, nullptr, v2h, v2l);
    if (bigP){
      for (int ch = 0; ch < 2; ++ch){
        int qbase = ch * 2048;
        sgemm3_k<<<dim3(16,16), 512, 0, stream>>>(Qh, Ql, Kh, Kl, S, qbase);
        softmax_k<<<2048, 256, 0, stream>>>(S, Pb, 4096, qbase, inv2);
      }
      pv2_k<<<dim3(64,8), 256, 0, stream>>>(Pb, 4096, vh, v2h, v2l, inv2,
                                            c_x + xoff, meanC + b*512, rstdC + b*512,
                                            out + xoff, 0, 0);
    } else {
      for (int ch = 0; ch < 2; ++ch){
        int qbase = ch * 2048;
        sgemm3_k<<<dim3(16,16), 512, 0, stream>>>(Qh, Ql, Kh, Kl, S, qbase);
        softmax_k<<<2048, 256, 0, stream>>>(S, Pb, 8192, 0, inv2);
        pv2_k<<<dim3(32,8), 256, 0, stream>>>(Pb, 8192, vh, v2h, v2l, inv2,
                                              c_x + xoff, meanC + b*512, rstdC + b*512,
                                              out + xoff, 0, qbase);
      }
    }
  }
}

// Round 12
// 719.742 us; speedup vs baseline: 1.2827x; 1.0365x over previous
//
#include <hip/hip_runtime.h>
#include <math.h>

typedef __attribute__((ext_vector_type(8))) short short8;    // 8 x bf16
typedef __attribute__((ext_vector_type(4))) float f32x4;
typedef __attribute__((ext_vector_type(4))) unsigned short u16x4;

#define DEVINL static __device__ __forceinline__
#define MFMA __builtin_amdgcn_mfma_f32_16x16x32_bf16

DEVINL unsigned short f2bf(float f){
  union { float f; unsigned u; } v; v.f = f;
  unsigned r = v.u + 0x7FFFu + ((v.u >> 16) & 1u);   // RNE
  return (unsigned short)(r >> 16);
}
DEVINL float bf2f(unsigned short h){
  union { unsigned u; float f; } v; v.u = ((unsigned)h) << 16;
  return v.f;
}
DEVINL void gload16(const void* g, void* l){
  __builtin_amdgcn_global_load_lds(
      (const __attribute__((address_space(1))) void*)g,
      (__attribute__((address_space(3))) void*)l, 16, 0, 0);
}

// B=4, C=QK=V=512, L=4096
__global__ void rowstats_k(const float* __restrict__ x,
                           float* __restrict__ mean, float* __restrict__ rstd){
  int row = blockIdx.x;
  const float4* p = (const float4*)(x + (long)row * 4096);
  float s = 0.f, ss = 0.f;
  for (int i = threadIdx.x; i < 1024; i += 256){
    float4 v = p[i];
    s  += v.x + v.y + v.z + v.w;
    ss += v.x*v.x + v.y*v.y + v.z*v.z + v.w*v.w;
  }
  for (int o = 32; o > 0; o >>= 1){ s += __shfl_down(s, o); ss += __shfl_down(ss, o); }
  __shared__ float ls[4], lss[4];
  int wv = threadIdx.x >> 6;
  if ((threadIdx.x & 63) == 0){ ls[wv] = s; lss[wv] = ss; }
  __syncthreads();
  if (threadIdx.x == 0){
    s = ls[0]+ls[1]+ls[2]+ls[3]; ss = lss[0]+lss[1]+lss[2]+lss[3];
    float m = s * (1.f/4096.f);
    float var = (ss - s*m) * (1.f/4095.f);
    mean[row] = m;
    rstd[row] = 1.f / sqrtf(var + 1e-5f);
  }
}

// merged fold for f (y=0) and g (y=1)
__global__ void foldw2_k(const float* __restrict__ fw, const float* __restrict__ fb,
                         const float* __restrict__ mQ, const float* __restrict__ rQ,
                         unsigned short* __restrict__ Wfh, unsigned short* __restrict__ Wfl,
                         float* __restrict__ bF,
                         const float* __restrict__ gw, const float* __restrict__ gb,
                         const float* __restrict__ mK, const float* __restrict__ rK,
                         unsigned short* __restrict__ Wgh, unsigned short* __restrict__ Wgl,
                         float* __restrict__ bG){
  int o = blockIdx.x;
  int g = blockIdx.y;
  const float* w    = g ? gw : fw;
  const float* bias = g ? gb : fb;
  const float* mean = g ? mK : mQ;
  const float* rstd = g ? rK : rQ;
  unsigned short* wh = g ? Wgh : Wfh;
  unsigned short* wl = g ? Wgl : Wfl;
  float* biasp = g ? bG : bF;
  const float* wr = w + (long)o * 512;
  float part = 0.f;
  for (int c = threadIdx.x; c < 512; c += 256){
    float wv = wr[c] * rstd[c];
    unsigned short h = f2bf(wv);
    wh[(o<<9)+c] = h;
    wl[(o<<9)+c] = f2bf(wv - bf2f(h));
    part += wv * mean[c];
  }
  __shared__ float red[256];
  red[threadIdx.x] = part; __syncthreads();
  for (int st = 128; st > 0; st >>= 1){
    if (threadIdx.x < st) red[threadIdx.x] += red[threadIdx.x + st];
    __syncthreads();
  }
  if (threadIdx.x == 0) biasp[o] = bias[o] - red[0];
}

__global__ void wsplit_k(const float* __restrict__ w,
                         unsigned short* __restrict__ wh, unsigned short* __restrict__ wl){
  int i = blockIdx.x * 256 + threadIdx.x;
  float v = w[i];
  unsigned short h = f2bf(v);
  wh[i] = h; wl[i] = f2bf(v - bf2f(h));
}

// ---------- 3-term conv GEMM for Q and K, merged over blockIdx.z ----------
__global__ __launch_bounds__(512) void conv3qk_k(
    const float* __restrict__ X0, const float* __restrict__ X1,
    const unsigned short* __restrict__ Wh0, const unsigned short* __restrict__ Wl0,
    const unsigned short* __restrict__ Wh1, const unsigned short* __restrict__ Wl1,
    const float* __restrict__ b0, const float* __restrict__ b1,
    unsigned short* __restrict__ oh0, unsigned short* __restrict__ ol0,
    unsigned short* __restrict__ oh1, unsigned short* __restrict__ ol1)
{
  int ob = blockIdx.y, lb = blockIdx.x, z = blockIdx.z;
  const float* X = z ? X1 : X0;
  const unsigned short* Wh = z ? Wh1 : Wh0;
  const unsigned short* Wl = z ? Wl1 : Wl0;
  const float* biasp = z ? b1 : b0;
  unsigned short* oh = z ? oh1 : oh0;
  unsigned short* ol = z ? ol1 : ol0;

  __shared__ __align__(16) char csm[36864];
  typedef unsigned short (*XT)[64][72];
  XT Xh = (XT)csm;                 // [2][64][72]
  XT Xl = (XT)(csm + 18432);       // [2][64][72]

  int tid = threadIdx.x, w = tid >> 6, lane = tid & 63, lr = lane & 15, lg = lane >> 4;
  const unsigned short* WhB = Wh + (long)(ob*128 + w*16) * 512;
  const unsigned short* WlB = Wl + (long)(ob*128 + w*16) * 512;
  int sl = tid & 63, scg = tid >> 6;
  const float* Xg = X + (long)(scg*8)*4096 + lb*64 + sl;

  f32x4 acc[4] = {};
  float fA[8], fB[8];
  short8 wA0, wA1, wA2, wA3, wB0, wB1, wB2, wB3;

#define CV_XLOAD(F, CB) { _Pragma("unroll") for (int j=0;j<8;++j) F[j] = Xg[(long)((CB)*64 + j)*4096]; }
#define CV_XWRITE(BUF, F) { short8 hv, lv; _Pragma("unroll") for (int j=0;j<8;++j){ \
    unsigned short h_ = f2bf(F[j]); hv[j] = (short)h_; lv[j] = (short)f2bf(F[j] - bf2f(h_)); } \
    *(short8*)&Xh[BUF][sl][scg*8] = hv; *(short8*)&Xl[BUF][sl][scg*8] = lv; }
#define CV_WLOAD(W0,W1,W2,W3, CB) { \
    W0 = *(const short8*)(WhB + (long)lr*512 + (CB)*64 + lg*8); \
    W1 = *(const short8*)(WhB + (long)lr*512 + (CB)*64 + 32 + lg*8); \
    W2 = *(const short8*)(WlB + (long)lr*512 + (CB)*64 + lg*8); \
    W3 = *(const short8*)(WlB + (long)lr*512 + (CB)*64 + 32 + lg*8); }
#define CV_COMPUTE(BUF, W0,W1,W2,W3) { \
    _Pragma("unroll") for (int ct=0;ct<4;++ct){ \
      short8 bh = *(const short8*)&Xh[BUF][ct*16+lr][lg*8]; \
      short8 bl = *(const short8*)&Xl[BUF][ct*16+lr][lg*8]; \
      acc[ct] = MFMA(W0, bh, acc[ct], 0,0,0); \
      acc[ct] = MFMA(W2, bh, acc[ct], 0,0,0); \
      acc[ct] = MFMA(W0, bl, acc[ct], 0,0,0); } \
    _Pragma("unroll") for (int ct=0;ct<4;++ct){ \
      short8 bh = *(const short8*)&Xh[BUF][ct*16+lr][32+lg*8]; \
      short8 bl = *(const short8*)&Xl[BUF][ct*16+lr][32+lg*8]; \
      acc[ct] = MFMA(W1, bh, acc[ct], 0,0,0); \
      acc[ct] = MFMA(W3, bh, acc[ct], 0,0,0); \
      acc[ct] = MFMA(W1, bl, acc[ct], 0,0,0); } }

  CV_XLOAD(fA, 0); CV_XWRITE(0, fA);
  CV_XLOAD(fA, 1);
  CV_WLOAD(wA0,wA1,wA2,wA3, 0);
  __syncthreads();
  for (int cb = 0; cb < 8; cb += 2){
    if (cb+2 < 8) CV_XLOAD(fB, cb+2);
    CV_WLOAD(wB0,wB1,wB2,wB3, cb+1);
    CV_COMPUTE(0, wA0,wA1,wA2,wA3);
    CV_XWRITE(1, fA);
    __syncthreads();
    if (cb+3 < 8) CV_XLOAD(fA, cb+3);
    if (cb+2 < 8) CV_WLOAD(wA0,wA1,wA2,wA3, cb+2);
    CV_COMPUTE(1, wB0,wB1,wB2,wB3);
    if (cb+2 < 8) CV_XWRITE(0, fB);
    __syncthreads();
  }

  int o4 = ob*128 + w*16 + lg*4;
  float bv[4];
  #pragma unroll
  for (int r = 0; r < 4; ++r) bv[r] = biasp[o4 + r];
  #pragma unroll
  for (int ct = 0; ct < 4; ++ct){
    u16x4 ph, pl;
    #pragma unroll
    for (int r = 0; r < 4; ++r){
      float y = acc[ct][r] + bv[r];
      unsigned short h = f2bf(y);
      ph[r] = h; pl[r] = f2bf(y - bf2f(h));
    }
    long base = ((long)(lb*64 + ct*16 + lr)) * 512 + o4;
    *(u16x4*)(oh + base) = ph;
    *(u16x4*)(ol + base) = pl;
  }
}

// ---------- 3-term conv GEMM, V path ----------
__global__ __launch_bounds__(512) void conv3v_k(
    const float* __restrict__ X,
    const unsigned short* __restrict__ Wh, const unsigned short* __restrict__ Wl,
    const float* __restrict__ biasp,
    unsigned short* __restrict__ oh,
    unsigned short* __restrict__ o2h, unsigned short* __restrict__ o2l)
{
  int ob = blockIdx.y, lb = blockIdx.x;
  __shared__ __align__(16) char csm[36864];
  typedef unsigned short (*XT)[64][72];
  XT Xh = (XT)csm;
  XT Xl = (XT)(csm + 18432);

  int tid = threadIdx.x, w = tid >> 6, lane = tid & 63, lr = lane & 15, lg = lane >> 4;
  const unsigned short* WhB = Wh + (long)(ob*128 + w*16) * 512;
  const unsigned short* WlB = Wl + (long)(ob*128 + w*16) * 512;
  int sl = tid & 63, scg = tid >> 6;
  const float* Xg = X + (long)(scg*8)*4096 + lb*64 + sl;

  f32x4 acc[4] = {};
  float fA[8], fB[8];
  short8 wA0, wA1, wA2, wA3, wB0, wB1, wB2, wB3;

  CV_XLOAD(fA, 0); CV_XWRITE(0, fA);
  CV_XLOAD(fA, 1);
  CV_WLOAD(wA0,wA1,wA2,wA3, 0);
  __syncthreads();
  for (int cb = 0; cb < 8; cb += 2){
    if (cb+2 < 8) CV_XLOAD(fB, cb+2);
    CV_WLOAD(wB0,wB1,wB2,wB3, cb+1);
    CV_COMPUTE(0, wA0,wA1,wA2,wA3);
    CV_XWRITE(1, fA);
    __syncthreads();
    if (cb+3 < 8) CV_XLOAD(fA, cb+3);
    if (cb+2 < 8) CV_WLOAD(wA0,wA1,wA2,wA3, cb+2);
    CV_COMPUTE(1, wB0,wB1,wB2,wB3);
    if (cb+2 < 8) CV_XWRITE(0, fB);
    __syncthreads();
  }

  int o4 = ob*128 + w*16 + lg*4;
  float bv[4];
  #pragma unroll
  for (int r = 0; r < 4; ++r) bv[r] = biasp[o4 + r];
  // vh = bf16(y); v2 = vh*vh exact product, exact split v2h+v2l.
  unsigned short sh_[16], s2h_[16], s2l_[16];
  #pragma unroll
  for (int ct = 0; ct < 4; ++ct)
    #pragma unroll
    for (int r = 0; r < 4; ++r){
      float y = acc[ct][r] + bv[r];
      unsigned short h = f2bf(y);
      float vhf = bf2f(h);
      float v2 = vhf * vhf;
      unsigned short h2 = f2bf(v2);
      unsigned short l2 = f2bf(v2 - bf2f(h2));
      sh_[ct*4+r] = h; s2h_[ct*4+r] = h2; s2l_[ct*4+r] = l2;
    }
  unsigned short* T = (unsigned short*)csm;   // [128][72]
#define CV_STORE(ARR, DST) { \
    __syncthreads(); \
    _Pragma("unroll") for (int ct=0;ct<4;++ct) \
      _Pragma("unroll") for (int r=0;r<4;++r) \
        T[(w*16+lg*4+r)*72 + ct*16+lr] = ARR[ct*4+r]; \
    __syncthreads(); \
    _Pragma("unroll") for (int s_=0;s_<2;++s_){ \
      int slot = tid + s_*512; int row = slot>>3, ch=(slot&7)*8; \
      *(short8*)(DST + (long)(ob*128+row)*4096 + lb*64 + ch) = *(const short8*)&T[row*72+ch]; } }
  CV_STORE(sh_,  oh);
  CV_STORE(s2h_, o2h);
  CV_STORE(s2l_, o2l);
#undef CV_STORE
#undef CV_XLOAD
#undef CV_XWRITE
#undef CV_WLOAD
#undef CV_COMPUTE
}

// ---------- 3-term S GEMM: 128q x 128k tile, LDS 64 KB -> 2 blocks/CU ----------
// wave = 64q x 32k (as=4 x bs=2); same swizzle; bit-identical accumulation order.
__global__ __launch_bounds__(512, 4) void sgemm3_k(
    const unsigned short* __restrict__ Qh, const unsigned short* __restrict__ Ql,
    const unsigned short* __restrict__ Kh, const unsigned short* __restrict__ Kl,
    float* __restrict__ S, int qbase)
{
  int bx = blockIdx.x, by = blockIdx.y;
  int q0g = qbase + bx*128, k0 = by*128;
  __shared__ unsigned short Qhs[128][64], Qls[128][64];
  __shared__ unsigned short Khs[128][64], Kls[128][64];
  int tid = threadIdx.x, w = tid >> 6, lane = tid & 63, lr = lane & 15, lg = lane >> 4;
  int wr = w & 1, wc = w >> 1;
  int srow = tid >> 3, sch = (tid & 7)*8;
  int swu = ((tid & 7) ^ (srow & 7)) * 8;
  int lr7 = lr & 7;
  short8 qr[4], kr[4];
  f32x4 acc[4][2] = {};

#define SG_LOAD(CB) { long c0_ = (long)(CB)*64 + sch; \
    qr[0] = *(const short8*)(Qh + (long)(q0g + srow)*512 + c0_); \
    qr[1] = *(const short8*)(Qh + (long)(q0g + srow + 64)*512 + c0_); \
    qr[2] = *(const short8*)(Ql + (long)(q0g + srow)*512 + c0_); \
    qr[3] = *(const short8*)(Ql + (long)(q0g + srow + 64)*512 + c0_); \
    kr[0] = *(const short8*)(Kh + (long)(k0 + srow)*512 + c0_); \
    kr[1] = *(const short8*)(Kh + (long)(k0 + srow + 64)*512 + c0_); \
    kr[2] = *(const short8*)(Kl + (long)(k0 + srow)*512 + c0_); \
    kr[3] = *(const short8*)(Kl + (long)(k0 + srow + 64)*512 + c0_); }
#define SG_WRITE { \
    *(short8*)&Qhs[srow][swu] = qr[0];      *(short8*)&Qhs[srow + 64][swu] = qr[1]; \
    *(short8*)&Qls[srow][swu] = qr[2];      *(short8*)&Qls[srow + 64][swu] = qr[3]; \
    *(short8*)&Khs[srow][swu] = kr[0];      *(short8*)&Khs[srow + 64][swu] = kr[1]; \
    *(short8*)&Kls[srow][swu] = kr[2];      *(short8*)&Kls[srow + 64][swu] = kr[3]; }

  SG_LOAD(0); SG_WRITE;
  __syncthreads();
  for (int cb = 0; cb < 8; ++cb){
    if (cb < 7) SG_LOAD(cb+1);
    #pragma unroll
    for (int kk = 0; kk < 2; ++kk){
      int un = ((kk*4 + lg) ^ lr7) * 8;
      short8 bh[2], bl[2];
      #pragma unroll
      for (int bs = 0; bs < 2; ++bs){
        int krow = wc*32 + bs*16 + lr;
        bh[bs] = *(const short8*)(&Khs[krow][un]);
        bl[bs] = *(const short8*)(&Kls[krow][un]);
      }
      #pragma unroll
      for (int as = 0; as < 4; ++as){
        int qrow = wr*64 + as*16 + lr;
        short8 ah = *(const short8*)(&Qhs[qrow][un]);
        short8 al = *(const short8*)(&Qls[qrow][un]);
        #pragma unroll
        for (int bs = 0; bs < 2; ++bs){
          acc[as][bs] = MFMA(ah, bh[bs], acc[as][bs], 0,0,0);
          acc[as][bs] = MFMA(al, bh[bs], acc[as][bs], 0,0,0);
          acc[as][bs] = MFMA(ah, bl[bs], acc[as][bs], 0,0,0);
        }
      }
    }
    __syncthreads();
    if (cb < 7){ SG_WRITE; __syncthreads(); }
  }
#undef SG_LOAD
#undef SG_WRITE
  #pragma unroll
  for (int as = 0; as < 4; ++as){
    #pragma unroll
    for (int bs = 0; bs < 2; ++bs){
      int q = bx*128 + wr*64 + as*16 + lg*4;
      int k = k0 + wc*32 + bs*16 + lr;
      float* Sp = S + (long)q*4096 + k;
      #pragma unroll
      for (int r = 0; r < 4; ++r) Sp[(long)r*4096] = acc[as][bs][r];
    }
  }
}

// ---------- row softmax ----------
__global__ __launch_bounds__(256) void softmax_k(const float* __restrict__ S,
                                                 unsigned short* __restrict__ Pb, long pitch,
                                                 int row0, float* __restrict__ inv2){
  int row = blockIdx.x;
  const float* Sr = S + (long)row * 4096;
  int t = threadIdx.x;
  f32x4 v[4];
  #pragma unroll
  for (int i = 0; i < 4; ++i) v[i] = *(const f32x4*)(Sr + t*4 + i*1024);
  float mx = v[0][0];
  #pragma unroll
  for (int i = 0; i < 4; ++i)
    #pragma unroll
    for (int j = 0; j < 4; ++j) mx = fmaxf(mx, v[i][j]);
  #pragma unroll
  for (int o = 32; o > 0; o >>= 1) mx = fmaxf(mx, __shfl_xor(mx, o));
  __shared__ float red[4];
  int wid = t >> 6;
  if ((t & 63) == 0) red[wid] = mx;
  __syncthreads();
  mx = fmaxf(fmaxf(red[0], red[1]), fmaxf(red[2], red[3]));
  __syncthreads();
  float p[16]; float d = 0.f;
  #pragma unroll
  for (int i = 0; i < 4; ++i)
    #pragma unroll
    for (int j = 0; j < 4; ++j){ float e = expf(v[i][j] - mx); p[i*4+j] = e; d += e; }
  #pragma unroll
  for (int o = 32; o > 0; o >>= 1) d += __shfl_xor(d, o);
  if ((t & 63) == 0) red[wid] = d;
  __syncthreads();
  d = red[0] + red[1] + red[2] + red[3];
  __syncthreads();
  float invd = 1.f / d;
  unsigned short pb[16]; float d2 = 0.f;
  #pragma unroll
  for (int i = 0; i < 16; ++i){ pb[i] = f2bf(p[i] * invd); d2 += bf2f(pb[i]); }
  #pragma unroll
  for (int o = 32; o > 0; o >>= 1) d2 += __shfl_xor(d2, o);
  if ((t & 63) == 0) red[wid] = d2;
  __syncthreads();
  if (t == 0) inv2[row0 + row] = 1.f / (red[0]+red[1]+red[2]+red[3]);
  unsigned short* Pr = Pb + (long)(row0 + row) * pitch;
  #pragma unroll
  for (int i = 0; i < 4; ++i){
    u16x4 pk;
    #pragma unroll
    for (int j = 0; j < 4; ++j) pk[j] = pb[i*4+j];
    *(u16x4*)(Pr + t*4 + i*1024) = pk;
  }
}

// ---------- PV GEMM + epilogue (r11 proven: 256 thr, 2 blocks/CU, gload16) ----------
__global__ __launch_bounds__(256, 2) void pv2_k(
    const unsigned short* __restrict__ P, long ppitch,
    const unsigned short* __restrict__ vh,
    const unsigned short* __restrict__ v2h, const unsigned short* __restrict__ v2l,
    const float* __restrict__ inv2,
    const float* __restrict__ cx, const float* __restrict__ mcx, const float* __restrict__ rcx,
    float* __restrict__ outb, int qP_base, int qG_base)
{
  __shared__ __align__(16) char smem[65536];            // 64 KB
  typedef unsigned short (*PlT)[64][64];
  typedef unsigned short (*VlT)[3][64][64];
  PlT Pl = (PlT)smem;
  VlT Vl = (VlT)(smem + 16384);
  float* R = (float*)smem;

  int tid = threadIdx.x;
  int l = tid & 63, w = tid >> 6;
  int wq = w >> 1, wv = w & 1;
  int lr = l & 15, lg = l >> 4;
  int qP0 = qP_base + blockIdx.x*64, qG0 = qG_base + blockIdx.x*64;
  int vc0 = blockIdx.y*64;

  int r8_ = l >> 3, c8 = (l & 7)*8;
  int srcc = c8 ^ (r8_*8);
  const unsigned short* gsrc;
  long rs8;
  unsigned short *l0, *l1;
  if (w == 0){
    gsrc = P + (long)(qP0 + r8_)*ppitch + srcc;
    rs8 = (long)8*ppitch;
    l0 = &Pl[0][0][0]; l1 = &Pl[1][0][0];
  } else {
    const unsigned short* va = (w==1 ? vh : w==2 ? v2h : v2l);
    gsrc = va + (long)(vc0 + r8_)*4096 + srcc;
    rs8 = (long)8*4096;
    l0 = &Vl[0][w-1][0][0]; l1 = &Vl[1][w-1][0][0];
  }

  f32x4 accM[2][2] = {}, acc2[2][2] = {};

#define PV_STAGE(LB, TT) { long ko_ = (long)(TT)*64; \
    _Pragma("unroll") for (int j = 0; j < 8; ++j) \
      gload16(gsrc + j*rs8 + ko_, LB + j*512); }
#define PV_COMPUTE(BUF) { \
    _Pragma("unroll") for (int kk = 0; kk < 2; ++kk){ \
      int un = ((kk*4 + lg) ^ (lr & 7)) * 8; \
      short8 fh[2], f2h[2], f2l[2]; \
      _Pragma("unroll") for (int bs = 0; bs < 2; ++bs){ \
        int vrow = wv*32 + bs*16 + lr; \
        fh[bs]  = *(const short8*)(&Vl[BUF][0][vrow][un]); \
        f2h[bs] = *(const short8*)(&Vl[BUF][1][vrow][un]); \
        f2l[bs] = *(const short8*)(&Vl[BUF][2][vrow][un]); } \
      _Pragma("unroll") for (int aq = 0; aq < 2; ++aq){ \
        short8 pa = *(const short8*)(&Pl[BUF][wq*32 + aq*16 + lr][un]); \
        _Pragma("unroll") for (int bs = 0; bs < 2; ++bs){ \
          accM[aq][bs] = MFMA(pa, fh[bs],  accM[aq][bs], 0,0,0); \
          acc2[aq][bs] = MFMA(pa, f2h[bs], acc2[aq][bs], 0,0,0); \
          acc2[aq][bs] = MFMA(pa, f2l[bs], acc2[aq][bs], 0,0,0); } } } }

  PV_STAGE(l0, 0);
  __syncthreads();
  for (int t = 0; t < 64; ++t){
    unsigned short* nb = (t & 1) ? l0 : l1;
    if (t < 63) PV_STAGE(nb, t+1);
    int buf = t & 1;
    PV_COMPUTE(buf);
    __syncthreads();
  }
#undef PV_STAGE
#undef PV_COMPUTE

  float* Tm = R;
  #pragma unroll
  for (int aq = 0; aq < 2; ++aq)
    #pragma unroll
    for (int bs = 0; bs < 2; ++bs){
      int vcl = wv*32 + bs*16 + lr;
      int ql  = wq*32 + aq*16 + lg*4;
      #pragma unroll
      for (int r = 0; r < 4; ++r) Tm[vcl*68 + ql + r] = accM[aq][bs][r];
    }
  __syncthreads();
  f32x4 Mv[4];
  #pragma unroll
  for (int p = 0; p < 4; ++p){
    int chunk = tid + p*256;
    int row = chunk >> 4, c4 = (chunk & 15)*4;
    Mv[p] = *(const f32x4*)&Tm[row*68 + c4];
  }
  __syncthreads();
  #pragma unroll
  for (int aq = 0; aq < 2; ++aq)
    #pragma unroll
    for (int bs = 0; bs < 2; ++bs){
      int vcl = wv*32 + bs*16 + lr;
      int ql  = wq*32 + aq*16 + lg*4;
      #pragma unroll
      for (int r = 0; r < 4; ++r) Tm[vcl*68 + ql + r] = acc2[aq][bs][r];
    }
  __syncthreads();
  #pragma unroll
  for (int p = 0; p < 4; ++p){
    int chunk = tid + p*256;
    int row = chunk >> 4, c4 = (chunk & 15)*4;
    float mu = mcx[vc0 + row], rs = rcx[vc0 + row];
    f32x4 t2 = *(const f32x4*)&Tm[row*68 + c4];
    f32x4 iv = *(const f32x4*)&inv2[qP0 + c4];
    f32x4 cv = *(const f32x4*)&cx[(long)(vc0+row)*4096 + qG0 + c4];
    f32x4 ov;
    #pragma unroll
    for (int j = 0; j < 4; ++j){
      float M = Mv[p][j]*iv[j], M2 = t2[j]*iv[j];
      float var = M2 - M*M;
      float sd = sqrtf(fmaxf(var, 0.f));
      ov[j] = sd*(cv[j]-mu)*rs + M;
    }
    *(f32x4*)&outb[(long)(vc0+row)*4096 + qG0 + c4] = ov;
  }
}

// ---------- launch ----------
extern "C" void kernel_launch(void* const* d_in, const int* in_sizes, int n_in,
                              void* d_out, int out_size, void* d_ws, size_t ws_size,
                              hipStream_t stream){
  const float* c_x  = (const float*)d_in[0];
  const float* s_x  = (const float*)d_in[1];
  const float* c_1x = (const float*)d_in[2];
  const float* s_1x = (const float*)d_in[3];
  const float* f_w  = (const float*)d_in[4];
  const float* f_b  = (const float*)d_in[5];
  const float* g_w  = (const float*)d_in[6];
  const float* g_b  = (const float*)d_in[7];
  const float* h_w  = (const float*)d_in[8];
  const float* h_b  = (const float*)d_in[9];
  float* out = (float*)d_out;

  char* ws = (char*)d_ws;
  size_t off = 0;
  auto alloc = [&](size_t bytes)->void*{
    void* p = ws + off; off += (bytes + 255) & ~(size_t)255; return p;
  };
  float* meanQ = (float*)alloc(2048*4); float* rstdQ = (float*)alloc(2048*4);
  float* meanK = (float*)alloc(2048*4); float* rstdK = (float*)alloc(2048*4);
  float* meanC = (float*)alloc(2048*4); float* rstdC = (float*)alloc(2048*4);
  float* biasF = (float*)alloc(512*4);  float* biasG = (float*)alloc(512*4);
  unsigned short* Wfh = (unsigned short*)alloc((size_t)512*512*2);
  unsigned short* Wfl = (unsigned short*)alloc((size_t)512*512*2);
  unsigned short* Wgh = (unsigned short*)alloc((size_t)512*512*2);
  unsigned short* Wgl = (unsigned short*)alloc((size_t)512*512*2);
  unsigned short* Whh = (unsigned short*)alloc((size_t)512*512*2);
  unsigned short* Whl = (unsigned short*)alloc((size_t)512*512*2);
  unsigned short* Qh = (unsigned short*)alloc((size_t)4096*512*2);
  unsigned short* Ql = (unsigned short*)alloc((size_t)4096*512*2);
  unsigned short* Kh = (unsigned short*)alloc((size_t)4096*512*2);
  unsigned short* Kl = (unsigned short*)alloc((size_t)4096*512*2);
  unsigned short* vh  = (unsigned short*)alloc((size_t)512*4096*2);
  unsigned short* v2h = (unsigned short*)alloc((size_t)512*4096*2);
  unsigned short* v2l = (unsigned short*)alloc((size_t)512*4096*2);
  float* S    = (float*)alloc((size_t)2048*4096*4);   // fp32 S chunk
  float* inv2 = (float*)alloc(4096*4);

  size_t pbytes = (size_t)4096*4096*2;
  bool bigP = (off + pbytes + 256 <= ws_size);
  unsigned short* Pb; long ppitch;
  if (bigP){ Pb = (unsigned short*)alloc(pbytes); ppitch = 4096; }
  else     { Pb = (unsigned short*)S;             ppitch = 8192; }

  rowstats_k<<<2048, 256, 0, stream>>>(c_1x, meanQ, rstdQ);
  rowstats_k<<<2048, 256, 0, stream>>>(s_1x, meanK, rstdK);
  rowstats_k<<<2048, 256, 0, stream>>>(c_x,  meanC, rstdC);
  wsplit_k<<<1024, 256, 0, stream>>>(h_w, Whh, Whl);

  for (int b = 0; b < 4; ++b){
    long xoff = (long)b * 512 * 4096;
    foldw2_k<<<dim3(512,2), 256, 0, stream>>>(f_w, f_b, meanQ + b*512, rstdQ + b*512, Wfh, Wfl, biasF,
                                              g_w, g_b, meanK + b*512, rstdK + b*512, Wgh, Wgl, biasG);
    conv3qk_k<<<dim3(64,4,2), 512, 0, stream>>>(c_1x + xoff, s_1x + xoff,
                                                Wfh, Wfl, Wgh, Wgl, biasF, biasG,
                                                Qh, Ql, Kh, Kl);
    conv3v_k<<<dim3(64,4), 512, 0, stream>>>(s_x + xoff, Whh, Whl, h_b, vh, v2h, v2l);
    if (bigP){
      for (int ch = 0; ch < 2; ++ch){
        int qbase = ch * 2048;
        sgemm3_k<<<dim3(16,32), 512, 0, stream>>>(Qh, Ql, Kh, Kl, S, qbase);
        softmax_k<<<2048, 256, 0, stream>>>(S, Pb, 4096, qbase, inv2);
      }
      pv2_k<<<dim3(64,8), 256, 0, stream>>>(Pb, 4096, vh, v2h, v2l, inv2,
                                            c_x + xoff, meanC + b*512, rstdC + b*512,
                                            out + xoff, 0, 0);
    } else {
      for (int ch = 0; ch < 2; ++ch){
        int qbase = ch * 2048;
        sgemm3_k<<<dim3(16,32), 512, 0, stream>>>(Qh, Ql, Kh, Kl, S, qbase);
        softmax_k<<<2048, 256, 0, stream>>>(S, Pb, 8192, 0, inv2);
        pv2_k<<<dim3(32,8), 256, 0, stream>>>(Pb, 8192, vh, v2h, v2l, inv2,
                                              c_x + xoff, meanC + b*512, rstdC + b*512,
                                              out + xoff, 0, qbase);
      }
    }
  }
}

// Round 13
// 635.066 us; speedup vs baseline: 1.4537x; 1.1333x over previous
//
#include <hip/hip_runtime.h>
#include <math.h>

typedef __attribute__((ext_vector_type(8))) short short8;    // 8 x bf16/fp16
typedef __attribute__((ext_vector_type(4))) float f32x4;
typedef __attribute__((ext_vector_type(4))) unsigned short u16x4;

#define DEVINL static __device__ __forceinline__
#define MFMA  __builtin_amdgcn_mfma_f32_16x16x32_bf16
#define MFMAH __builtin_amdgcn_mfma_f32_16x16x32_f16

DEVINL unsigned short f2bf(float f){
  union { float f; unsigned u; } v; v.f = f;
  unsigned r = v.u + 0x7FFFu + ((v.u >> 16) & 1u);   // RNE
  return (unsigned short)(r >> 16);
}
DEVINL float bf2f(unsigned short h){
  union { unsigned u; float f; } v; v.u = ((unsigned)h) << 16;
  return v.f;
}
DEVINL unsigned short f2h(float f){
  union { _Float16 h; unsigned short u; } c; c.h = (_Float16)f;  // RNE
  return c.u;
}
DEVINL void gload16(const void* g, void* l){
  __builtin_amdgcn_global_load_lds(
      (const __attribute__((address_space(1))) void*)g,
      (__attribute__((address_space(3))) void*)l, 16, 0, 0);
}

// B=4, C=QK=V=512, L=4096
__global__ void rowstats_k(const float* __restrict__ x,
                           float* __restrict__ mean, float* __restrict__ rstd){
  int row = blockIdx.x;
  const float4* p = (const float4*)(x + (long)row * 4096);
  float s = 0.f, ss = 0.f;
  for (int i = threadIdx.x; i < 1024; i += 256){
    float4 v = p[i];
    s  += v.x + v.y + v.z + v.w;
    ss += v.x*v.x + v.y*v.y + v.z*v.z + v.w*v.w;
  }
  for (int o = 32; o > 0; o >>= 1){ s += __shfl_down(s, o); ss += __shfl_down(ss, o); }
  __shared__ float ls[4], lss[4];
  int wv = threadIdx.x >> 6;
  if ((threadIdx.x & 63) == 0){ ls[wv] = s; lss[wv] = ss; }
  __syncthreads();
  if (threadIdx.x == 0){
    s = ls[0]+ls[1]+ls[2]+ls[3]; ss = lss[0]+lss[1]+lss[2]+lss[3];
    float m = s * (1.f/4096.f);
    float var = (ss - s*m) * (1.f/4095.f);
    mean[row] = m;
    rstd[row] = 1.f / sqrtf(var + 1e-5f);
  }
}

// merged fold for f (y=0) and g (y=1)
__global__ void foldw2_k(const float* __restrict__ fw, const float* __restrict__ fb,
                         const float* __restrict__ mQ, const float* __restrict__ rQ,
                         unsigned short* __restrict__ Wfh, unsigned short* __restrict__ Wfl,
                         float* __restrict__ bF,
                         const float* __restrict__ gw, const float* __restrict__ gb,
                         const float* __restrict__ mK, const float* __restrict__ rK,
                         unsigned short* __restrict__ Wgh, unsigned short* __restrict__ Wgl,
                         float* __restrict__ bG){
  int o = blockIdx.x;
  int g = blockIdx.y;
  const float* w    = g ? gw : fw;
  const float* bias = g ? gb : fb;
  const float* mean = g ? mK : mQ;
  const float* rstd = g ? rK : rQ;
  unsigned short* wh = g ? Wgh : Wfh;
  unsigned short* wl = g ? Wgl : Wfl;
  float* biasp = g ? bG : bF;
  const float* wr = w + (long)o * 512;
  float part = 0.f;
  for (int c = threadIdx.x; c < 512; c += 256){
    float wv = wr[c] * rstd[c];
    unsigned short h = f2bf(wv);
    wh[(o<<9)+c] = h;
    wl[(o<<9)+c] = f2bf(wv - bf2f(h));
    part += wv * mean[c];
  }
  __shared__ float red[256];
  red[threadIdx.x] = part; __syncthreads();
  for (int st = 128; st > 0; st >>= 1){
    if (threadIdx.x < st) red[threadIdx.x] += red[threadIdx.x + st];
    __syncthreads();
  }
  if (threadIdx.x == 0) biasp[o] = bias[o] - red[0];
}

__global__ void wsplit_k(const float* __restrict__ w,
                         unsigned short* __restrict__ wh, unsigned short* __restrict__ wl){
  int i = blockIdx.x * 256 + threadIdx.x;
  float v = w[i];
  unsigned short h = f2bf(v);
  wh[i] = h; wl[i] = f2bf(v - bf2f(h));
}

// ---------- 3-term conv GEMM for Q and K, merged; OUTPUT = single fp16 ----------
__global__ __launch_bounds__(512) void conv3qk_k(
    const float* __restrict__ X0, const float* __restrict__ X1,
    const unsigned short* __restrict__ Wh0, const unsigned short* __restrict__ Wl0,
    const unsigned short* __restrict__ Wh1, const unsigned short* __restrict__ Wl1,
    const float* __restrict__ b0, const float* __restrict__ b1,
    unsigned short* __restrict__ of0, unsigned short* __restrict__ of1)
{
  int ob = blockIdx.y, lb = blockIdx.x, z = blockIdx.z;
  const float* X = z ? X1 : X0;
  const unsigned short* Wh = z ? Wh1 : Wh0;
  const unsigned short* Wl = z ? Wl1 : Wl0;
  const float* biasp = z ? b1 : b0;
  unsigned short* of = z ? of1 : of0;

  __shared__ __align__(16) char csm[36864];
  typedef unsigned short (*XT)[64][72];
  XT Xh = (XT)csm;                 // [2][64][72]
  XT Xl = (XT)(csm + 18432);       // [2][64][72]

  int tid = threadIdx.x, w = tid >> 6, lane = tid & 63, lr = lane & 15, lg = lane >> 4;
  const unsigned short* WhB = Wh + (long)(ob*128 + w*16) * 512;
  const unsigned short* WlB = Wl + (long)(ob*128 + w*16) * 512;
  int sl = tid & 63, scg = tid >> 6;
  const float* Xg = X + (long)(scg*8)*4096 + lb*64 + sl;

  f32x4 acc[4] = {};
  float fA[8], fB[8];
  short8 wA0, wA1, wA2, wA3, wB0, wB1, wB2, wB3;

#define CV_XLOAD(F, CB) { _Pragma("unroll") for (int j=0;j<8;++j) F[j] = Xg[(long)((CB)*64 + j)*4096]; }
#define CV_XWRITE(BUF, F) { short8 hv, lv; _Pragma("unroll") for (int j=0;j<8;++j){ \
    unsigned short h_ = f2bf(F[j]); hv[j] = (short)h_; lv[j] = (short)f2bf(F[j] - bf2f(h_)); } \
    *(short8*)&Xh[BUF][sl][scg*8] = hv; *(short8*)&Xl[BUF][sl][scg*8] = lv; }
#define CV_WLOAD(W0,W1,W2,W3, CB) { \
    W0 = *(const short8*)(WhB + (long)lr*512 + (CB)*64 + lg*8); \
    W1 = *(const short8*)(WhB + (long)lr*512 + (CB)*64 + 32 + lg*8); \
    W2 = *(const short8*)(WlB + (long)lr*512 + (CB)*64 + lg*8); \
    W3 = *(const short8*)(WlB + (long)lr*512 + (CB)*64 + 32 + lg*8); }
#define CV_COMPUTE(BUF, W0,W1,W2,W3) { \
    _Pragma("unroll") for (int ct=0;ct<4;++ct){ \
      short8 bh = *(const short8*)&Xh[BUF][ct*16+lr][lg*8]; \
      short8 bl = *(const short8*)&Xl[BUF][ct*16+lr][lg*8]; \
      acc[ct] = MFMA(W0, bh, acc[ct], 0,0,0); \
      acc[ct] = MFMA(W2, bh, acc[ct], 0,0,0); \
      acc[ct] = MFMA(W0, bl, acc[ct], 0,0,0); } \
    _Pragma("unroll") for (int ct=0;ct<4;++ct){ \
      short8 bh = *(const short8*)&Xh[BUF][ct*16+lr][32+lg*8]; \
      short8 bl = *(const short8*)&Xl[BUF][ct*16+lr][32+lg*8]; \
      acc[ct] = MFMA(W1, bh, acc[ct], 0,0,0); \
      acc[ct] = MFMA(W3, bh, acc[ct], 0,0,0); \
      acc[ct] = MFMA(W1, bl, acc[ct], 0,0,0); } }

  CV_XLOAD(fA, 0); CV_XWRITE(0, fA);
  CV_XLOAD(fA, 1);
  CV_WLOAD(wA0,wA1,wA2,wA3, 0);
  __syncthreads();
  for (int cb = 0; cb < 8; cb += 2){
    if (cb+2 < 8) CV_XLOAD(fB, cb+2);
    CV_WLOAD(wB0,wB1,wB2,wB3, cb+1);
    CV_COMPUTE(0, wA0,wA1,wA2,wA3);
    CV_XWRITE(1, fA);
    __syncthreads();
    if (cb+3 < 8) CV_XLOAD(fA, cb+3);
    if (cb+2 < 8) CV_WLOAD(wA0,wA1,wA2,wA3, cb+2);
    CV_COMPUTE(1, wB0,wB1,wB2,wB3);
    if (cb+2 < 8) CV_XWRITE(0, fB);
    __syncthreads();
  }

  int o4 = ob*128 + w*16 + lg*4;
  float bv[4];
  #pragma unroll
  for (int r = 0; r < 4; ++r) bv[r] = biasp[o4 + r];
  #pragma unroll
  for (int ct = 0; ct < 4; ++ct){
    u16x4 ph;
    #pragma unroll
    for (int r = 0; r < 4; ++r) ph[r] = f2h(acc[ct][r] + bv[r]);
    long base = ((long)(lb*64 + ct*16 + lr)) * 512 + o4;
    *(u16x4*)(of + base) = ph;
  }
}

// ---------- 3-term conv GEMM, V path (unchanged numerics) ----------
__global__ __launch_bounds__(512) void conv3v_k(
    const float* __restrict__ X,
    const unsigned short* __restrict__ Wh, const unsigned short* __restrict__ Wl,
    const float* __restrict__ biasp,
    unsigned short* __restrict__ oh,
    unsigned short* __restrict__ o2h, unsigned short* __restrict__ o2l)
{
  int ob = blockIdx.y, lb = blockIdx.x;
  __shared__ __align__(16) char csm[36864];
  typedef unsigned short (*XT)[64][72];
  XT Xh = (XT)csm;
  XT Xl = (XT)(csm + 18432);

  int tid = threadIdx.x, w = tid >> 6, lane = tid & 63, lr = lane & 15, lg = lane >> 4;
  const unsigned short* WhB = Wh + (long)(ob*128 + w*16) * 512;
  const unsigned short* WlB = Wl + (long)(ob*128 + w*16) * 512;
  int sl = tid & 63, scg = tid >> 6;
  const float* Xg = X + (long)(scg*8)*4096 + lb*64 + sl;

  f32x4 acc[4] = {};
  float fA[8], fB[8];
  short8 wA0, wA1, wA2, wA3, wB0, wB1, wB2, wB3;

  CV_XLOAD(fA, 0); CV_XWRITE(0, fA);
  CV_XLOAD(fA, 1);
  CV_WLOAD(wA0,wA1,wA2,wA3, 0);
  __syncthreads();
  for (int cb = 0; cb < 8; cb += 2){
    if (cb+2 < 8) CV_XLOAD(fB, cb+2);
    CV_WLOAD(wB0,wB1,wB2,wB3, cb+1);
    CV_COMPUTE(0, wA0,wA1,wA2,wA3);
    CV_XWRITE(1, fA);
    __syncthreads();
    if (cb+3 < 8) CV_XLOAD(fA, cb+3);
    if (cb+2 < 8) CV_WLOAD(wA0,wA1,wA2,wA3, cb+2);
    CV_COMPUTE(1, wB0,wB1,wB2,wB3);
    if (cb+2 < 8) CV_XWRITE(0, fB);
    __syncthreads();
  }

  int o4 = ob*128 + w*16 + lg*4;
  float bv[4];
  #pragma unroll
  for (int r = 0; r < 4; ++r) bv[r] = biasp[o4 + r];
  unsigned short sh_[16], s2h_[16], s2l_[16];
  #pragma unroll
  for (int ct = 0; ct < 4; ++ct)
    #pragma unroll
    for (int r = 0; r < 4; ++r){
      float y = acc[ct][r] + bv[r];
      unsigned short h = f2bf(y);
      float vhf = bf2f(h);
      float v2 = vhf * vhf;
      unsigned short h2 = f2bf(v2);
      unsigned short l2 = f2bf(v2 - bf2f(h2));
      sh_[ct*4+r] = h; s2h_[ct*4+r] = h2; s2l_[ct*4+r] = l2;
    }
  unsigned short* T = (unsigned short*)csm;   // [128][72]
#define CV_STORE(ARR, DST) { \
    __syncthreads(); \
    _Pragma("unroll") for (int ct=0;ct<4;++ct) \
      _Pragma("unroll") for (int r=0;r<4;++r) \
        T[(w*16+lg*4+r)*72 + ct*16+lr] = ARR[ct*4+r]; \
    __syncthreads(); \
    _Pragma("unroll") for (int s_=0;s_<2;++s_){ \
      int slot = tid + s_*512; int row = slot>>3, ch=(slot&7)*8; \
      *(short8*)(DST + (long)(ob*128+row)*4096 + lb*64 + ch) = *(const short8*)&T[row*72+ch]; } }
  CV_STORE(sh_,  oh);
  CV_STORE(s2h_, o2h);
  CV_STORE(s2l_, o2l);
#undef CV_STORE
#undef CV_XLOAD
#undef CV_XWRITE
#undef CV_WLOAD
#undef CV_COMPUTE
}

// ---------- 1-term fp16 S GEMM: 128q x 128k tile, LDS 32 KB, 2 blocks/CU ----------
// S = Qf16 . Kf16 (single MFMA chain). Same swizzle skeleton as the proven sgemm3.
__global__ __launch_bounds__(512, 4) void sgemm1h_k(
    const unsigned short* __restrict__ Qf, const unsigned short* __restrict__ Kf,
    float* __restrict__ S, int qbase)
{
  int bx = blockIdx.x, by = blockIdx.y;
  int q0g = qbase + bx*128, k0 = by*128;
  __shared__ unsigned short Qs[128][64], Ks[128][64];
  int tid = threadIdx.x, w = tid >> 6, lane = tid & 63, lr = lane & 15, lg = lane >> 4;
  int wr = w & 1, wc = w >> 1;
  int srow = tid >> 3, sch = (tid & 7)*8;
  int swu = ((tid & 7) ^ (srow & 7)) * 8;
  int lr7 = lr & 7;
  short8 qr0, qr1, kr0, kr1;
  f32x4 acc[4][2] = {};

#define SG_LOAD(CB) { long c0_ = (long)(CB)*64 + sch; \
    qr0 = *(const short8*)(Qf + (long)(q0g + srow)*512 + c0_); \
    qr1 = *(const short8*)(Qf + (long)(q0g + srow + 64)*512 + c0_); \
    kr0 = *(const short8*)(Kf + (long)(k0 + srow)*512 + c0_); \
    kr1 = *(const short8*)(Kf + (long)(k0 + srow + 64)*512 + c0_); }
#define SG_WRITE { \
    *(short8*)&Qs[srow][swu] = qr0; *(short8*)&Qs[srow + 64][swu] = qr1; \
    *(short8*)&Ks[srow][swu] = kr0; *(short8*)&Ks[srow + 64][swu] = kr1; }

  SG_LOAD(0); SG_WRITE;
  __syncthreads();
  for (int cb = 0; cb < 8; ++cb){
    if (cb < 7) SG_LOAD(cb+1);
    #pragma unroll
    for (int kk = 0; kk < 2; ++kk){
      int un = ((kk*4 + lg) ^ lr7) * 8;
      short8 bh[2];
      #pragma unroll
      for (int bs = 0; bs < 2; ++bs)
        bh[bs] = *(const short8*)(&Ks[wc*32 + bs*16 + lr][un]);
      #pragma unroll
      for (int as = 0; as < 4; ++as){
        short8 ah = *(const short8*)(&Qs[wr*64 + as*16 + lr][un]);
        #pragma unroll
        for (int bs = 0; bs < 2; ++bs)
          acc[as][bs] = MFMAH(ah, bh[bs], acc[as][bs], 0,0,0);
      }
    }
    __syncthreads();
    if (cb < 7){ SG_WRITE; __syncthreads(); }
  }
#undef SG_LOAD
#undef SG_WRITE
  #pragma unroll
  for (int as = 0; as < 4; ++as){
    #pragma unroll
    for (int bs = 0; bs < 2; ++bs){
      int q = bx*128 + wr*64 + as*16 + lg*4;
      int k = k0 + wc*32 + bs*16 + lr;
      float* Sp = S + (long)q*4096 + k;
      #pragma unroll
      for (int r = 0; r < 4; ++r) Sp[(long)r*4096] = acc[as][bs][r];
    }
  }
}

// ---------- row softmax ----------
__global__ __launch_bounds__(256) void softmax_k(const float* __restrict__ S,
                                                 unsigned short* __restrict__ Pb, long pitch,
                                                 int row0, float* __restrict__ inv2){
  int row = blockIdx.x;
  const float* Sr = S + (long)row * 4096;
  int t = threadIdx.x;
  f32x4 v[4];
  #pragma unroll
  for (int i = 0; i < 4; ++i) v[i] = *(const f32x4*)(Sr + t*4 + i*1024);
  float mx = v[0][0];
  #pragma unroll
  for (int i = 0; i < 4; ++i)
    #pragma unroll
    for (int j = 0; j < 4; ++j) mx = fmaxf(mx, v[i][j]);
  #pragma unroll
  for (int o = 32; o > 0; o >>= 1) mx = fmaxf(mx, __shfl_xor(mx, o));
  __shared__ float red[4];
  int wid = t >> 6;
  if ((t & 63) == 0) red[wid] = mx;
  __syncthreads();
  mx = fmaxf(fmaxf(red[0], red[1]), fmaxf(red[2], red[3]));
  __syncthreads();
  float p[16]; float d = 0.f;
  #pragma unroll
  for (int i = 0; i < 4; ++i)
    #pragma unroll
    for (int j = 0; j < 4; ++j){ float e = expf(v[i][j] - mx); p[i*4+j] = e; d += e; }
  #pragma unroll
  for (int o = 32; o > 0; o >>= 1) d += __shfl_xor(d, o);
  if ((t & 63) == 0) red[wid] = d;
  __syncthreads();
  d = red[0] + red[1] + red[2] + red[3];
  __syncthreads();
  float invd = 1.f / d;
  unsigned short pb[16]; float d2 = 0.f;
  #pragma unroll
  for (int i = 0; i < 16; ++i){ pb[i] = f2bf(p[i] * invd); d2 += bf2f(pb[i]); }
  #pragma unroll
  for (int o = 32; o > 0; o >>= 1) d2 += __shfl_xor(d2, o);
  if ((t & 63) == 0) red[wid] = d2;
  __syncthreads();
  if (t == 0) inv2[row0 + row] = 1.f / (red[0]+red[1]+red[2]+red[3]);
  unsigned short* Pr = Pb + (long)(row0 + row) * pitch;
  #pragma unroll
  for (int i = 0; i < 4; ++i){
    u16x4 pk;
    #pragma unroll
    for (int j = 0; j < 4; ++j) pk[j] = pb[i*4+j];
    *(u16x4*)(Pr + t*4 + i*1024) = pk;
  }
}

// ---------- PV GEMM + epilogue (r11 proven: 256 thr, 2 blocks/CU, gload16) ----------
__global__ __launch_bounds__(256, 2) void pv2_k(
    const unsigned short* __restrict__ P, long ppitch,
    const unsigned short* __restrict__ vh,
    const unsigned short* __restrict__ v2h, const unsigned short* __restrict__ v2l,
    const float* __restrict__ inv2,
    const float* __restrict__ cx, const float* __restrict__ mcx, const float* __restrict__ rcx,
    float* __restrict__ outb, int qP_base, int qG_base)
{
  __shared__ __align__(16) char smem[65536];            // 64 KB
  typedef unsigned short (*PlT)[64][64];
  typedef unsigned short (*VlT)[3][64][64];
  PlT Pl = (PlT)smem;
  VlT Vl = (VlT)(smem + 16384);
  float* R = (float*)smem;

  int tid = threadIdx.x;
  int l = tid & 63, w = tid >> 6;
  int wq = w >> 1, wv = w & 1;
  int lr = l & 15, lg = l >> 4;
  int qP0 = qP_base + blockIdx.x*64, qG0 = qG_base + blockIdx.x*64;
  int vc0 = blockIdx.y*64;

  int r8_ = l >> 3, c8 = (l & 7)*8;
  int srcc = c8 ^ (r8_*8);
  const unsigned short* gsrc;
  long rs8;
  unsigned short *l0, *l1;
  if (w == 0){
    gsrc = P + (long)(qP0 + r8_)*ppitch + srcc;
    rs8 = (long)8*ppitch;
    l0 = &Pl[0][0][0]; l1 = &Pl[1][0][0];
  } else {
    const unsigned short* va = (w==1 ? vh : w==2 ? v2h : v2l);
    gsrc = va + (long)(vc0 + r8_)*4096 + srcc;
    rs8 = (long)8*4096;
    l0 = &Vl[0][w-1][0][0]; l1 = &Vl[1][w-1][0][0];
  }

  f32x4 accM[2][2] = {}, acc2[2][2] = {};

#define PV_STAGE(LB, TT) { long ko_ = (long)(TT)*64; \
    _Pragma("unroll") for (int j = 0; j < 8; ++j) \
      gload16(gsrc + j*rs8 + ko_, LB + j*512); }
#define PV_COMPUTE(BUF) { \
    _Pragma("unroll") for (int kk = 0; kk < 2; ++kk){ \
      int un = ((kk*4 + lg) ^ (lr & 7)) * 8; \
      short8 fh[2], f2h[2], f2l[2]; \
      _Pragma("unroll") for (int bs = 0; bs < 2; ++bs){ \
        int vrow = wv*32 + bs*16 + lr; \
        fh[bs]  = *(const short8*)(&Vl[BUF][0][vrow][un]); \
        f2h[bs] = *(const short8*)(&Vl[BUF][1][vrow][un]); \
        f2l[bs] = *(const short8*)(&Vl[BUF][2][vrow][un]); } \
      _Pragma("unroll") for (int aq = 0; aq < 2; ++aq){ \
        short8 pa = *(const short8*)(&Pl[BUF][wq*32 + aq*16 + lr][un]); \
        _Pragma("unroll") for (int bs = 0; bs < 2; ++bs){ \
          accM[aq][bs] = MFMA(pa, fh[bs],  accM[aq][bs], 0,0,0); \
          acc2[aq][bs] = MFMA(pa, f2h[bs], acc2[aq][bs], 0,0,0); \
          acc2[aq][bs] = MFMA(pa, f2l[bs], acc2[aq][bs], 0,0,0); } } } }

  PV_STAGE(l0, 0);
  __syncthreads();
  for (int t = 0; t < 64; ++t){
    unsigned short* nb = (t & 1) ? l0 : l1;
    if (t < 63) PV_STAGE(nb, t+1);
    int buf = t & 1;
    PV_COMPUTE(buf);
    __syncthreads();
  }
#undef PV_STAGE
#undef PV_COMPUTE

  float* Tm = R;
  #pragma unroll
  for (int aq = 0; aq < 2; ++aq)
    #pragma unroll
    for (int bs = 0; bs < 2; ++bs){
      int vcl = wv*32 + bs*16 + lr;
      int ql  = wq*32 + aq*16 + lg*4;
      #pragma unroll
      for (int r = 0; r < 4; ++r) Tm[vcl*68 + ql + r] = accM[aq][bs][r];
    }
  __syncthreads();
  f32x4 Mv[4];
  #pragma unroll
  for (int p = 0; p < 4; ++p){
    int chunk = tid + p*256;
    int row = chunk >> 4, c4 = (chunk & 15)*4;
    Mv[p] = *(const f32x4*)&Tm[row*68 + c4];
  }
  __syncthreads();
  #pragma unroll
  for (int aq = 0; aq < 2; ++aq)
    #pragma unroll
    for (int bs = 0; bs < 2; ++bs){
      int vcl = wv*32 + bs*16 + lr;
      int ql  = wq*32 + aq*16 + lg*4;
      #pragma unroll
      for (int r = 0; r < 4; ++r) Tm[vcl*68 + ql + r] = acc2[aq][bs][r];
    }
  __syncthreads();
  #pragma unroll
  for (int p = 0; p < 4; ++p){
    int chunk = tid + p*256;
    int row = chunk >> 4, c4 = (chunk & 15)*4;
    float mu = mcx[vc0 + row], rs = rcx[vc0 + row];
    f32x4 t2 = *(const f32x4*)&Tm[row*68 + c4];
    f32x4 iv = *(const f32x4*)&inv2[qP0 + c4];
    f32x4 cv = *(const f32x4*)&cx[(long)(vc0+row)*4096 + qG0 + c4];
    f32x4 ov;
    #pragma unroll
    for (int j = 0; j < 4; ++j){
      float M = Mv[p][j]*iv[j], M2 = t2[j]*iv[j];
      float var = M2 - M*M;
      float sd = sqrtf(fmaxf(var, 0.f));
      ov[j] = sd*(cv[j]-mu)*rs + M;
    }
    *(f32x4*)&outb[(long)(vc0+row)*4096 + qG0 + c4] = ov;
  }
}

// ---------- launch ----------
extern "C" void kernel_launch(void* const* d_in, const int* in_sizes, int n_in,
                              void* d_out, int out_size, void* d_ws, size_t ws_size,
                              hipStream_t stream){
  const float* c_x  = (const float*)d_in[0];
  const float* s_x  = (const float*)d_in[1];
  const float* c_1x = (const float*)d_in[2];
  const float* s_1x = (const float*)d_in[3];
  const float* f_w  = (const float*)d_in[4];
  const float* f_b  = (const float*)d_in[5];
  const float* g_w  = (const float*)d_in[6];
  const float* g_b  = (const float*)d_in[7];
  const float* h_w  = (const float*)d_in[8];
  const float* h_b  = (const float*)d_in[9];
  float* out = (float*)d_out;

  char* ws = (char*)d_ws;
  size_t off = 0;
  auto alloc = [&](size_t bytes)->void*{
    void* p = ws + off; off += (bytes + 255) & ~(size_t)255; return p;
  };
  float* meanQ = (float*)alloc(2048*4); float* rstdQ = (float*)alloc(2048*4);
  float* meanK = (float*)alloc(2048*4); float* rstdK = (float*)alloc(2048*4);
  float* meanC = (float*)alloc(2048*4); float* rstdC = (float*)alloc(2048*4);
  float* biasF = (float*)alloc(512*4);  float* biasG = (float*)alloc(512*4);
  unsigned short* Wfh = (unsigned short*)alloc((size_t)512*512*2);
  unsigned short* Wfl = (unsigned short*)alloc((size_t)512*512*2);
  unsigned short* Wgh = (unsigned short*)alloc((size_t)512*512*2);
  unsigned short* Wgl = (unsigned short*)alloc((size_t)512*512*2);
  unsigned short* Whh = (unsigned short*)alloc((size_t)512*512*2);
  unsigned short* Whl = (unsigned short*)alloc((size_t)512*512*2);
  unsigned short* Qf = (unsigned short*)alloc((size_t)4096*512*2);   // fp16
  unsigned short* Kf = (unsigned short*)alloc((size_t)4096*512*2);   // fp16
  unsigned short* vh  = (unsigned short*)alloc((size_t)512*4096*2);
  unsigned short* v2h = (unsigned short*)alloc((size_t)512*4096*2);
  unsigned short* v2l = (unsigned short*)alloc((size_t)512*4096*2);
  float* S    = (float*)alloc((size_t)2048*4096*4);   // fp32 S chunk
  float* inv2 = (float*)alloc(4096*4);

  size_t pbytes = (size_t)4096*4096*2;
  bool bigP = (off + pbytes + 256 <= ws_size);
  unsigned short* Pb; long ppitch;
  if (bigP){ Pb = (unsigned short*)alloc(pbytes); ppitch = 4096; }
  else     { Pb = (unsigned short*)S;             ppitch = 8192; }

  rowstats_k<<<2048, 256, 0, stream>>>(c_1x, meanQ, rstdQ);
  rowstats_k<<<2048, 256, 0, stream>>>(s_1x, meanK, rstdK);
  rowstats_k<<<2048, 256, 0, stream>>>(c_x,  meanC, rstdC);
  wsplit_k<<<1024, 256, 0, stream>>>(h_w, Whh, Whl);

  for (int b = 0; b < 4; ++b){
    long xoff = (long)b * 512 * 4096;
    foldw2_k<<<dim3(512,2), 256, 0, stream>>>(f_w, f_b, meanQ + b*512, rstdQ + b*512, Wfh, Wfl, biasF,
                                              g_w, g_b, meanK + b*512, rstdK + b*512, Wgh, Wgl, biasG);
    conv3qk_k<<<dim3(64,4,2), 512, 0, stream>>>(c_1x + xoff, s_1x + xoff,
                                                Wfh, Wfl, Wgh, Wgl, biasF, biasG,
                                                Qf, Kf);
    conv3v_k<<<dim3(64,4), 512, 0, stream>>>(s_x + xoff, Whh, Whl, h_b, vh, v2h, v2l);
    if (bigP){
      for (int ch = 0; ch < 2; ++ch){
        int qbase = ch * 2048;
        sgemm1h_k<<<dim3(16,32), 512, 0, stream>>>(Qf, Kf, S, qbase);
        softmax_k<<<2048, 256, 0, stream>>>(S, Pb, 4096, qbase, inv2);
      }
      pv2_k<<<dim3(64,8), 256, 0, stream>>>(Pb, 4096, vh, v2h, v2l, inv2,
                                            c_x + xoff, meanC + b*512, rstdC + b*512,
                                            out + xoff, 0, 0);
    } else {
      for (int ch = 0; ch < 2; ++ch){
        int qbase = ch * 2048;
        sgemm1h_k<<<dim3(16,32), 512, 0, stream>>>(Qf, Kf, S, qbase);
        softmax_k<<<2048, 256, 0, stream>>>(S, Pb, 8192, 0, inv2);
        pv2_k<<<dim3(32,8), 256, 0, stream>>>(Pb, 8192, vh, v2h, v2l, inv2,
                                              c_x + xoff, meanC + b*512, rstdC + b*512,
                                              out + xoff, 0, qbase);
      }
    }
  }
}

// Round 14
// 575.448 us; speedup vs baseline: 1.6043x; 1.1036x over previous
//
#include <hip/hip_runtime.h>
#include <math.h>

typedef __attribute__((ext_vector_type(8))) short short8;    // 8 x bf16/fp16
typedef __attribute__((ext_vector_type(4))) float f32x4;
typedef __attribute__((ext_vector_type(4))) unsigned short u16x4;

#define DEVINL static __device__ __forceinline__
#define MFMA  __builtin_amdgcn_mfma_f32_16x16x32_bf16
#define MFMAH __builtin_amdgcn_mfma_f32_16x16x32_f16

DEVINL unsigned short f2bf(float f){
  union { float f; unsigned u; } v; v.f = f;
  unsigned r = v.u + 0x7FFFu + ((v.u >> 16) & 1u);   // RNE
  return (unsigned short)(r >> 16);
}
DEVINL float bf2f(unsigned short h){
  union { unsigned u; float f; } v; v.u = ((unsigned)h) << 16;
  return v.f;
}
DEVINL unsigned short f2h(float f){
  union { _Float16 h; unsigned short u; } c; c.h = (_Float16)f;  // RNE
  return c.u;
}
DEVINL float h2f(unsigned short u){
  union { unsigned short u; _Float16 h; } c; c.u = u;
  return (float)c.h;
}
DEVINL void gload16(const void* g, void* l){
  __builtin_amdgcn_global_load_lds(
      (const __attribute__((address_space(1))) void*)g,
      (__attribute__((address_space(3))) void*)l, 16, 0, 0);
}

// B=4, C=QK=V=512, L=4096
__global__ void rowstats_k(const float* __restrict__ x,
                           float* __restrict__ mean, float* __restrict__ rstd){
  int row = blockIdx.x;
  const float4* p = (const float4*)(x + (long)row * 4096);
  float s = 0.f, ss = 0.f;
  for (int i = threadIdx.x; i < 1024; i += 256){
    float4 v = p[i];
    s  += v.x + v.y + v.z + v.w;
    ss += v.x*v.x + v.y*v.y + v.z*v.z + v.w*v.w;
  }
  for (int o = 32; o > 0; o >>= 1){ s += __shfl_down(s, o); ss += __shfl_down(ss, o); }
  __shared__ float ls[4], lss[4];
  int wv = threadIdx.x >> 6;
  if ((threadIdx.x & 63) == 0){ ls[wv] = s; lss[wv] = ss; }
  __syncthreads();
  if (threadIdx.x == 0){
    s = ls[0]+ls[1]+ls[2]+ls[3]; ss = lss[0]+lss[1]+lss[2]+lss[3];
    float m = s * (1.f/4096.f);
    float var = (ss - s*m) * (1.f/4095.f);
    mean[row] = m;
    rstd[row] = 1.f / sqrtf(var + 1e-5f);
  }
}

// merged fold for f (y=0) and g (y=1)
__global__ void foldw2_k(const float* __restrict__ fw, const float* __restrict__ fb,
                         const float* __restrict__ mQ, const float* __restrict__ rQ,
                         unsigned short* __restrict__ Wfh, unsigned short* __restrict__ Wfl,
                         float* __restrict__ bF,
                         const float* __restrict__ gw, const float* __restrict__ gb,
                         const float* __restrict__ mK, const float* __restrict__ rK,
                         unsigned short* __restrict__ Wgh, unsigned short* __restrict__ Wgl,
                         float* __restrict__ bG){
  int o = blockIdx.x;
  int g = blockIdx.y;
  const float* w    = g ? gw : fw;
  const float* bias = g ? gb : fb;
  const float* mean = g ? mK : mQ;
  const float* rstd = g ? rK : rQ;
  unsigned short* wh = g ? Wgh : Wfh;
  unsigned short* wl = g ? Wgl : Wfl;
  float* biasp = g ? bG : bF;
  const float* wr = w + (long)o * 512;
  float part = 0.f;
  for (int c = threadIdx.x; c < 512; c += 256){
    float wv = wr[c] * rstd[c];
    unsigned short h = f2bf(wv);
    wh[(o<<9)+c] = h;
    wl[(o<<9)+c] = f2bf(wv - bf2f(h));
    part += wv * mean[c];
  }
  __shared__ float red[256];
  red[threadIdx.x] = part; __syncthreads();
  for (int st = 128; st > 0; st >>= 1){
    if (threadIdx.x < st) red[threadIdx.x] += red[threadIdx.x + st];
    __syncthreads();
  }
  if (threadIdx.x == 0) biasp[o] = bias[o] - red[0];
}

__global__ void wsplit_k(const float* __restrict__ w,
                         unsigned short* __restrict__ wh, unsigned short* __restrict__ wl){
  int i = blockIdx.x * 256 + threadIdx.x;
  float v = w[i];
  unsigned short h = f2bf(v);
  wh[i] = h; wl[i] = f2bf(v - bf2f(h));
}

// ---------- 3-term conv GEMM for Q and K, merged; OUTPUT = single fp16 ----------
__global__ __launch_bounds__(512) void conv3qk_k(
    const float* __restrict__ X0, const float* __restrict__ X1,
    const unsigned short* __restrict__ Wh0, const unsigned short* __restrict__ Wl0,
    const unsigned short* __restrict__ Wh1, const unsigned short* __restrict__ Wl1,
    const float* __restrict__ b0, const float* __restrict__ b1,
    unsigned short* __restrict__ of0, unsigned short* __restrict__ of1)
{
  int ob = blockIdx.y, lb = blockIdx.x, z = blockIdx.z;
  const float* X = z ? X1 : X0;
  const unsigned short* Wh = z ? Wh1 : Wh0;
  const unsigned short* Wl = z ? Wl1 : Wl0;
  const float* biasp = z ? b1 : b0;
  unsigned short* of = z ? of1 : of0;

  __shared__ __align__(16) char csm[36864];
  typedef unsigned short (*XT)[64][72];
  XT Xh = (XT)csm;                 // [2][64][72]
  XT Xl = (XT)(csm + 18432);       // [2][64][72]

  int tid = threadIdx.x, w = tid >> 6, lane = tid & 63, lr = lane & 15, lg = lane >> 4;
  const unsigned short* WhB = Wh + (long)(ob*128 + w*16) * 512;
  const unsigned short* WlB = Wl + (long)(ob*128 + w*16) * 512;
  int sl = tid & 63, scg = tid >> 6;
  const float* Xg = X + (long)(scg*8)*4096 + lb*64 + sl;

  f32x4 acc[4] = {};
  float fA[8], fB[8];
  short8 wA0, wA1, wA2, wA3, wB0, wB1, wB2, wB3;

#define CV_XLOAD(F, CB) { _Pragma("unroll") for (int j=0;j<8;++j) F[j] = Xg[(long)((CB)*64 + j)*4096]; }
#define CV_XWRITE(BUF, F) { short8 hv, lv; _Pragma("unroll") for (int j=0;j<8;++j){ \
    unsigned short h_ = f2bf(F[j]); hv[j] = (short)h_; lv[j] = (short)f2bf(F[j] - bf2f(h_)); } \
    *(short8*)&Xh[BUF][sl][scg*8] = hv; *(short8*)&Xl[BUF][sl][scg*8] = lv; }
#define CV_WLOAD(W0,W1,W2,W3, CB) { \
    W0 = *(const short8*)(WhB + (long)lr*512 + (CB)*64 + lg*8); \
    W1 = *(const short8*)(WhB + (long)lr*512 + (CB)*64 + 32 + lg*8); \
    W2 = *(const short8*)(WlB + (long)lr*512 + (CB)*64 + lg*8); \
    W3 = *(const short8*)(WlB + (long)lr*512 + (CB)*64 + 32 + lg*8); }
#define CV_COMPUTE(BUF, W0,W1,W2,W3) { \
    _Pragma("unroll") for (int ct=0;ct<4;++ct){ \
      short8 bh = *(const short8*)&Xh[BUF][ct*16+lr][lg*8]; \
      short8 bl = *(const short8*)&Xl[BUF][ct*16+lr][lg*8]; \
      acc[ct] = MFMA(W0, bh, acc[ct], 0,0,0); \
      acc[ct] = MFMA(W2, bh, acc[ct], 0,0,0); \
      acc[ct] = MFMA(W0, bl, acc[ct], 0,0,0); } \
    _Pragma("unroll") for (int ct=0;ct<4;++ct){ \
      short8 bh = *(const short8*)&Xh[BUF][ct*16+lr][32+lg*8]; \
      short8 bl = *(const short8*)&Xl[BUF][ct*16+lr][32+lg*8]; \
      acc[ct] = MFMA(W1, bh, acc[ct], 0,0,0); \
      acc[ct] = MFMA(W3, bh, acc[ct], 0,0,0); \
      acc[ct] = MFMA(W1, bl, acc[ct], 0,0,0); } }

  CV_XLOAD(fA, 0); CV_XWRITE(0, fA);
  CV_XLOAD(fA, 1);
  CV_WLOAD(wA0,wA1,wA2,wA3, 0);
  __syncthreads();
  for (int cb = 0; cb < 8; cb += 2){
    if (cb+2 < 8) CV_XLOAD(fB, cb+2);
    CV_WLOAD(wB0,wB1,wB2,wB3, cb+1);
    CV_COMPUTE(0, wA0,wA1,wA2,wA3);
    CV_XWRITE(1, fA);
    __syncthreads();
    if (cb+3 < 8) CV_XLOAD(fA, cb+3);
    if (cb+2 < 8) CV_WLOAD(wA0,wA1,wA2,wA3, cb+2);
    CV_COMPUTE(1, wB0,wB1,wB2,wB3);
    if (cb+2 < 8) CV_XWRITE(0, fB);
    __syncthreads();
  }

  int o4 = ob*128 + w*16 + lg*4;
  float bv[4];
  #pragma unroll
  for (int r = 0; r < 4; ++r) bv[r] = biasp[o4 + r];
  #pragma unroll
  for (int ct = 0; ct < 4; ++ct){
    u16x4 ph;
    #pragma unroll
    for (int r = 0; r < 4; ++r) ph[r] = f2h(acc[ct][r] + bv[r]);
    long base = ((long)(lb*64 + ct*16 + lr)) * 512 + o4;
    *(u16x4*)(of + base) = ph;
  }
}

// ---------- 3-term conv GEMM, V path (unchanged numerics) ----------
__global__ __launch_bounds__(512) void conv3v_k(
    const float* __restrict__ X,
    const unsigned short* __restrict__ Wh, const unsigned short* __restrict__ Wl,
    const float* __restrict__ biasp,
    unsigned short* __restrict__ oh,
    unsigned short* __restrict__ o2h, unsigned short* __restrict__ o2l)
{
  int ob = blockIdx.y, lb = blockIdx.x;
  __shared__ __align__(16) char csm[36864];
  typedef unsigned short (*XT)[64][72];
  XT Xh = (XT)csm;
  XT Xl = (XT)(csm + 18432);

  int tid = threadIdx.x, w = tid >> 6, lane = tid & 63, lr = lane & 15, lg = lane >> 4;
  const unsigned short* WhB = Wh + (long)(ob*128 + w*16) * 512;
  const unsigned short* WlB = Wl + (long)(ob*128 + w*16) * 512;
  int sl = tid & 63, scg = tid >> 6;
  const float* Xg = X + (long)(scg*8)*4096 + lb*64 + sl;

  f32x4 acc[4] = {};
  float fA[8], fB[8];
  short8 wA0, wA1, wA2, wA3, wB0, wB1, wB2, wB3;

  CV_XLOAD(fA, 0); CV_XWRITE(0, fA);
  CV_XLOAD(fA, 1);
  CV_WLOAD(wA0,wA1,wA2,wA3, 0);
  __syncthreads();
  for (int cb = 0; cb < 8; cb += 2){
    if (cb+2 < 8) CV_XLOAD(fB, cb+2);
    CV_WLOAD(wB0,wB1,wB2,wB3, cb+1);
    CV_COMPUTE(0, wA0,wA1,wA2,wA3);
    CV_XWRITE(1, fA);
    __syncthreads();
    if (cb+3 < 8) CV_XLOAD(fA, cb+3);
    if (cb+2 < 8) CV_WLOAD(wA0,wA1,wA2,wA3, cb+2);
    CV_COMPUTE(1, wB0,wB1,wB2,wB3);
    if (cb+2 < 8) CV_XWRITE(0, fB);
    __syncthreads();
  }

  int o4 = ob*128 + w*16 + lg*4;
  float bv[4];
  #pragma unroll
  for (int r = 0; r < 4; ++r) bv[r] = biasp[o4 + r];
  unsigned short sh_[16], s2h_[16], s2l_[16];
  #pragma unroll
  for (int ct = 0; ct < 4; ++ct)
    #pragma unroll
    for (int r = 0; r < 4; ++r){
      float y = acc[ct][r] + bv[r];
      unsigned short h = f2bf(y);
      float vhf = bf2f(h);
      float v2 = vhf * vhf;
      unsigned short h2 = f2bf(v2);
      unsigned short l2 = f2bf(v2 - bf2f(h2));
      sh_[ct*4+r] = h; s2h_[ct*4+r] = h2; s2l_[ct*4+r] = l2;
    }
  unsigned short* T = (unsigned short*)csm;   // [128][72]
#define CV_STORE(ARR, DST) { \
    __syncthreads(); \
    _Pragma("unroll") for (int ct=0;ct<4;++ct) \
      _Pragma("unroll") for (int r=0;r<4;++r) \
        T[(w*16+lg*4+r)*72 + ct*16+lr] = ARR[ct*4+r]; \
    __syncthreads(); \
    _Pragma("unroll") for (int s_=0;s_<2;++s_){ \
      int slot = tid + s_*512; int row = slot>>3, ch=(slot&7)*8; \
      *(short8*)(DST + (long)(ob*128+row)*4096 + lb*64 + ch) = *(const short8*)&T[row*72+ch]; } }
  CV_STORE(sh_,  oh);
  CV_STORE(s2h_, o2h);
  CV_STORE(s2l_, o2l);
#undef CV_STORE
#undef CV_XLOAD
#undef CV_XWRITE
#undef CV_WLOAD
#undef CV_COMPUTE
}

// ---------- 1-term fp16 S GEMM: 128q x 128k tile, S stored as fp16 ----------
__global__ __launch_bounds__(512, 4) void sgemm1h_k(
    const unsigned short* __restrict__ Qf, const unsigned short* __restrict__ Kf,
    unsigned short* __restrict__ S)
{
  int bx = blockIdx.x, by = blockIdx.y;
  int q0g = bx*128, k0 = by*128;
  __shared__ unsigned short Qs[128][64], Ks[128][64];
  int tid = threadIdx.x, w = tid >> 6, lane = tid & 63, lr = lane & 15, lg = lane >> 4;
  int wr = w & 1, wc = w >> 1;
  int srow = tid >> 3, sch = (tid & 7)*8;
  int swu = ((tid & 7) ^ (srow & 7)) * 8;
  int lr7 = lr & 7;
  short8 qr0, qr1, kr0, kr1;
  f32x4 acc[4][2] = {};

#define SG_LOAD(CB) { long c0_ = (long)(CB)*64 + sch; \
    qr0 = *(const short8*)(Qf + (long)(q0g + srow)*512 + c0_); \
    qr1 = *(const short8*)(Qf + (long)(q0g + srow + 64)*512 + c0_); \
    kr0 = *(const short8*)(Kf + (long)(k0 + srow)*512 + c0_); \
    kr1 = *(const short8*)(Kf + (long)(k0 + srow + 64)*512 + c0_); }
#define SG_WRITE { \
    *(short8*)&Qs[srow][swu] = qr0; *(short8*)&Qs[srow + 64][swu] = qr1; \
    *(short8*)&Ks[srow][swu] = kr0; *(short8*)&Ks[srow + 64][swu] = kr1; }

  SG_LOAD(0); SG_WRITE;
  __syncthreads();
  for (int cb = 0; cb < 8; ++cb){
    if (cb < 7) SG_LOAD(cb+1);
    #pragma unroll
    for (int kk = 0; kk < 2; ++kk){
      int un = ((kk*4 + lg) ^ lr7) * 8;
      short8 bh[2];
      #pragma unroll
      for (int bs = 0; bs < 2; ++bs)
        bh[bs] = *(const short8*)(&Ks[wc*32 + bs*16 + lr][un]);
      #pragma unroll
      for (int as = 0; as < 4; ++as){
        short8 ah = *(const short8*)(&Qs[wr*64 + as*16 + lr][un]);
        #pragma unroll
        for (int bs = 0; bs < 2; ++bs)
          acc[as][bs] = MFMAH(ah, bh[bs], acc[as][bs], 0,0,0);
      }
    }
    __syncthreads();
    if (cb < 7){ SG_WRITE; __syncthreads(); }
  }
#undef SG_LOAD
#undef SG_WRITE
  #pragma unroll
  for (int as = 0; as < 4; ++as){
    #pragma unroll
    for (int bs = 0; bs < 2; ++bs){
      int q = q0g + wr*64 + as*16 + lg*4;
      int k = k0 + wc*32 + bs*16 + lr;
      unsigned short* Sp = S + (long)q*4096 + k;
      #pragma unroll
      for (int r = 0; r < 4; ++r) Sp[(long)r*4096] = f2h(acc[as][bs][r]);
    }
  }
}

// ---------- row softmax: read fp16 S, write bf16 P IN PLACE; exact renorm ----------
__global__ __launch_bounds__(256) void softmax_k(unsigned short* __restrict__ SP,
                                                 float* __restrict__ inv2){
  int row = blockIdx.x;
  unsigned short* Sr = SP + (long)row * 4096;
  int t = threadIdx.x;
  short8 a = *(const short8*)(Sr + t*8);
  short8 b = *(const short8*)(Sr + 2048 + t*8);
  float v[16];
  #pragma unroll
  for (int j = 0; j < 8; ++j){ v[j] = h2f((unsigned short)a[j]); v[8+j] = h2f((unsigned short)b[j]); }
  float mx = v[0];
  #pragma unroll
  for (int i = 1; i < 16; ++i) mx = fmaxf(mx, v[i]);
  #pragma unroll
  for (int o = 32; o > 0; o >>= 1) mx = fmaxf(mx, __shfl_xor(mx, o));
  __shared__ float red[4];
  int wid = t >> 6;
  if ((t & 63) == 0) red[wid] = mx;
  __syncthreads();
  mx = fmaxf(fmaxf(red[0], red[1]), fmaxf(red[2], red[3]));
  __syncthreads();
  float p[16]; float d = 0.f;
  #pragma unroll
  for (int i = 0; i < 16; ++i){ float e = expf(v[i] - mx); p[i] = e; d += e; }
  #pragma unroll
  for (int o = 32; o > 0; o >>= 1) d += __shfl_xor(d, o);
  if ((t & 63) == 0) red[wid] = d;
  __syncthreads();
  d = red[0] + red[1] + red[2] + red[3];
  __syncthreads();
  float invd = 1.f / d;
  unsigned short pb[16]; float d2 = 0.f;
  #pragma unroll
  for (int i = 0; i < 16; ++i){ pb[i] = f2bf(p[i] * invd); d2 += bf2f(pb[i]); }
  #pragma unroll
  for (int o = 32; o > 0; o >>= 1) d2 += __shfl_xor(d2, o);
  if ((t & 63) == 0) red[wid] = d2;
  __syncthreads();
  if (t == 0) inv2[row] = 1.f / (red[0]+red[1]+red[2]+red[3]);
  short8 pa, pbv;
  #pragma unroll
  for (int j = 0; j < 8; ++j){ pa[j] = (short)pb[j]; pbv[j] = (short)pb[8+j]; }
  *(short8*)(Sr + t*8) = pa;
  *(short8*)(Sr + 2048 + t*8) = pbv;
}

// ---------- PV GEMM + epilogue (r11 proven: 256 thr, 2 blocks/CU, gload16) ----------
__global__ __launch_bounds__(256, 2) void pv2_k(
    const unsigned short* __restrict__ P, long ppitch,
    const unsigned short* __restrict__ vh,
    const unsigned short* __restrict__ v2h, const unsigned short* __restrict__ v2l,
    const float* __restrict__ inv2,
    const float* __restrict__ cx, const float* __restrict__ mcx, const float* __restrict__ rcx,
    float* __restrict__ outb)
{
  __shared__ __align__(16) char smem[65536];            // 64 KB
  typedef unsigned short (*PlT)[64][64];
  typedef unsigned short (*VlT)[3][64][64];
  PlT Pl = (PlT)smem;
  VlT Vl = (VlT)(smem + 16384);
  float* R = (float*)smem;

  int tid = threadIdx.x;
  int l = tid & 63, w = tid >> 6;
  int wq = w >> 1, wv = w & 1;
  int lr = l & 15, lg = l >> 4;
  int qP0 = blockIdx.x*64, qG0 = blockIdx.x*64;
  int vc0 = blockIdx.y*64;

  int r8_ = l >> 3, c8 = (l & 7)*8;
  int srcc = c8 ^ (r8_*8);
  const unsigned short* gsrc;
  long rs8;
  unsigned short *l0, *l1;
  if (w == 0){
    gsrc = P + (long)(qP0 + r8_)*ppitch + srcc;
    rs8 = (long)8*ppitch;
    l0 = &Pl[0][0][0]; l1 = &Pl[1][0][0];
  } else {
    const unsigned short* va = (w==1 ? vh : w==2 ? v2h : v2l);
    gsrc = va + (long)(vc0 + r8_)*4096 + srcc;
    rs8 = (long)8*4096;
    l0 = &Vl[0][w-1][0][0]; l1 = &Vl[1][w-1][0][0];
  }

  f32x4 accM[2][2] = {}, acc2[2][2] = {};

#define PV_STAGE(LB, TT) { long ko_ = (long)(TT)*64; \
    _Pragma("unroll") for (int j = 0; j < 8; ++j) \
      gload16(gsrc + j*rs8 + ko_, LB + j*512); }
#define PV_COMPUTE(BUF) { \
    _Pragma("unroll") for (int kk = 0; kk < 2; ++kk){ \
      int un = ((kk*4 + lg) ^ (lr & 7)) * 8; \
      short8 fh[2], f2h_[2], f2l_[2]; \
      _Pragma("unroll") for (int bs = 0; bs < 2; ++bs){ \
        int vrow = wv*32 + bs*16 + lr; \
        fh[bs]   = *(const short8*)(&Vl[BUF][0][vrow][un]); \
        f2h_[bs] = *(const short8*)(&Vl[BUF][1][vrow][un]); \
        f2l_[bs] = *(const short8*)(&Vl[BUF][2][vrow][un]); } \
      _Pragma("unroll") for (int aq = 0; aq < 2; ++aq){ \
        short8 pa = *(const short8*)(&Pl[BUF][wq*32 + aq*16 + lr][un]); \
        _Pragma("unroll") for (int bs = 0; bs < 2; ++bs){ \
          accM[aq][bs] = MFMA(pa, fh[bs],   accM[aq][bs], 0,0,0); \
          acc2[aq][bs] = MFMA(pa, f2h_[bs], acc2[aq][bs], 0,0,0); \
          acc2[aq][bs] = MFMA(pa, f2l_[bs], acc2[aq][bs], 0,0,0); } } } }

  PV_STAGE(l0, 0);
  __syncthreads();
  for (int t = 0; t < 64; ++t){
    unsigned short* nb = (t & 1) ? l0 : l1;
    if (t < 63) PV_STAGE(nb, t+1);
    int buf = t & 1;
    PV_COMPUTE(buf);
    __syncthreads();
  }
#undef PV_STAGE
#undef PV_COMPUTE

  float* Tm = R;
  #pragma unroll
  for (int aq = 0; aq < 2; ++aq)
    #pragma unroll
    for (int bs = 0; bs < 2; ++bs){
      int vcl = wv*32 + bs*16 + lr;
      int ql  = wq*32 + aq*16 + lg*4;
      #pragma unroll
      for (int r = 0; r < 4; ++r) Tm[vcl*68 + ql + r] = accM[aq][bs][r];
    }
  __syncthreads();
  f32x4 Mv[4];
  #pragma unroll
  for (int p = 0; p < 4; ++p){
    int chunk = tid + p*256;
    int row = chunk >> 4, c4 = (chunk & 15)*4;
    Mv[p] = *(const f32x4*)&Tm[row*68 + c4];
  }
  __syncthreads();
  #pragma unroll
  for (int aq = 0; aq < 2; ++aq)
    #pragma unroll
    for (int bs = 0; bs < 2; ++bs){
      int vcl = wv*32 + bs*16 + lr;
      int ql  = wq*32 + aq*16 + lg*4;
      #pragma unroll
      for (int r = 0; r < 4; ++r) Tm[vcl*68 + ql + r] = acc2[aq][bs][r];
    }
  __syncthreads();
  #pragma unroll
  for (int p = 0; p < 4; ++p){
    int chunk = tid + p*256;
    int row = chunk >> 4, c4 = (chunk & 15)*4;
    float mu = mcx[vc0 + row], rs = rcx[vc0 + row];
    f32x4 t2 = *(const f32x4*)&Tm[row*68 + c4];
    f32x4 iv = *(const f32x4*)&inv2[qP0 + c4];
    f32x4 cv = *(const f32x4*)&cx[(long)(vc0+row)*4096 + qG0 + c4];
    f32x4 ov;
    #pragma unroll
    for (int j = 0; j < 4; ++j){
      float M = Mv[p][j]*iv[j], M2 = t2[j]*iv[j];
      float var = M2 - M*M;
      float sd = sqrtf(fmaxf(var, 0.f));
      ov[j] = sd*(cv[j]-mu)*rs + M;
    }
    *(f32x4*)&outb[(long)(vc0+row)*4096 + qG0 + c4] = ov;
  }
}

// ---------- launch ----------
extern "C" void kernel_launch(void* const* d_in, const int* in_sizes, int n_in,
                              void* d_out, int out_size, void* d_ws, size_t ws_size,
                              hipStream_t stream){
  const float* c_x  = (const float*)d_in[0];
  const float* s_x  = (const float*)d_in[1];
  const float* c_1x = (const float*)d_in[2];
  const float* s_1x = (const float*)d_in[3];
  const float* f_w  = (const float*)d_in[4];
  const float* f_b  = (const float*)d_in[5];
  const float* g_w  = (const float*)d_in[6];
  const float* g_b  = (const float*)d_in[7];
  const float* h_w  = (const float*)d_in[8];
  const float* h_b  = (const float*)d_in[9];
  float* out = (float*)d_out;

  char* ws = (char*)d_ws;
  size_t off = 0;
  auto alloc = [&](size_t bytes)->void*{
    void* p = ws + off; off += (bytes + 255) & ~(size_t)255; return p;
  };
  float* meanQ = (float*)alloc(2048*4); float* rstdQ = (float*)alloc(2048*4);
  float* meanK = (float*)alloc(2048*4); float* rstdK = (float*)alloc(2048*4);
  float* meanC = (float*)alloc(2048*4); float* rstdC = (float*)alloc(2048*4);
  float* biasF = (float*)alloc(512*4);  float* biasG = (float*)alloc(512*4);
  unsigned short* Wfh = (unsigned short*)alloc((size_t)512*512*2);
  unsigned short* Wfl = (unsigned short*)alloc((size_t)512*512*2);
  unsigned short* Wgh = (unsigned short*)alloc((size_t)512*512*2);
  unsigned short* Wgl = (unsigned short*)alloc((size_t)512*512*2);
  unsigned short* Whh = (unsigned short*)alloc((size_t)512*512*2);
  unsigned short* Whl = (unsigned short*)alloc((size_t)512*512*2);
  unsigned short* Qf = (unsigned short*)alloc((size_t)4096*512*2);   // fp16
  unsigned short* Kf = (unsigned short*)alloc((size_t)4096*512*2);   // fp16
  unsigned short* vh  = (unsigned short*)alloc((size_t)512*4096*2);
  unsigned short* v2h = (unsigned short*)alloc((size_t)512*4096*2);
  unsigned short* v2l = (unsigned short*)alloc((size_t)512*4096*2);
  unsigned short* S   = (unsigned short*)alloc((size_t)4096*4096*2); // fp16 S; bf16 P in place
  float* inv2 = (float*)alloc(4096*4);
  // total ws ~58 MB

  rowstats_k<<<2048, 256, 0, stream>>>(c_1x, meanQ, rstdQ);
  rowstats_k<<<2048, 256, 0, stream>>>(s_1x, meanK, rstdK);
  rowstats_k<<<2048, 256, 0, stream>>>(c_x,  meanC, rstdC);
  wsplit_k<<<1024, 256, 0, stream>>>(h_w, Whh, Whl);

  for (int b = 0; b < 4; ++b){
    long xoff = (long)b * 512 * 4096;
    foldw2_k<<<dim3(512,2), 256, 0, stream>>>(f_w, f_b, meanQ + b*512, rstdQ + b*512, Wfh, Wfl, biasF,
                                              g_w, g_b, meanK + b*512, rstdK + b*512, Wgh, Wgl, biasG);
    conv3qk_k<<<dim3(64,4,2), 512, 0, stream>>>(c_1x + xoff, s_1x + xoff,
                                                Wfh, Wfl, Wgh, Wgl, biasF, biasG,
                                                Qf, Kf);
    conv3v_k<<<dim3(64,4), 512, 0, stream>>>(s_x + xoff, Whh, Whl, h_b, vh, v2h, v2l);
    sgemm1h_k<<<dim3(32,32), 512, 0, stream>>>(Qf, Kf, S);
    softmax_k<<<4096, 256, 0, stream>>>(S, inv2);
    pv2_k<<<dim3(64,8), 256, 0, stream>>>(S, 4096, vh, v2h, v2l, inv2,
                                          c_x + xoff, meanC + b*512, rstdC + b*512,
                                          out + xoff);
  }
}

// Round 15
// 556.574 us; speedup vs baseline: 1.6587x; 1.0339x over previous
//
#include <hip/hip_runtime.h>
#include <math.h>

typedef __attribute__((ext_vector_type(8))) short short8;    // 8 x bf16/fp16
typedef __attribute__((ext_vector_type(4))) float f32x4;
typedef __attribute__((ext_vector_type(4))) unsigned short u16x4;

#define DEVINL static __device__ __forceinline__
#define MFMA  __builtin_amdgcn_mfma_f32_16x16x32_bf16
#define MFMAH __builtin_amdgcn_mfma_f32_16x16x32_f16

DEVINL unsigned short f2bf(float f){
  union { float f; unsigned u; } v; v.f = f;
  unsigned r = v.u + 0x7FFFu + ((v.u >> 16) & 1u);   // RNE
  return (unsigned short)(r >> 16);
}
DEVINL float bf2f(unsigned short h){
  union { unsigned u; float f; } v; v.u = ((unsigned)h) << 16;
  return v.f;
}
DEVINL unsigned short f2h(float f){
  union { _Float16 h; unsigned short u; } c; c.h = (_Float16)f;  // RNE
  return c.u;
}
DEVINL float h2f(unsigned short u){
  union { unsigned short u; _Float16 h; } c; c.u = u;
  return (float)c.h;
}
DEVINL void gload16(const void* g, void* l){
  __builtin_amdgcn_global_load_lds(
      (const __attribute__((address_space(1))) void*)g,
      (__attribute__((address_space(3))) void*)l, 16, 0, 0);
}

// B=4, C=QK=V=512, L=4096
// ---------- merged per-(b,c) stats for all three inputs ----------
__global__ void rowstats3_k(const float* __restrict__ x0, float* __restrict__ m0, float* __restrict__ r0,
                            const float* __restrict__ x1, float* __restrict__ m1, float* __restrict__ r1,
                            const float* __restrict__ x2, float* __restrict__ m2, float* __restrict__ r2){
  int row = blockIdx.x, z = blockIdx.y;
  const float* x = (z==0 ? x0 : z==1 ? x1 : x2);
  float* mean = (z==0 ? m0 : z==1 ? m1 : m2);
  float* rstd = (z==0 ? r0 : z==1 ? r1 : r2);
  const float4* p = (const float4*)(x + (long)row * 4096);
  float s = 0.f, ss = 0.f;
  for (int i = threadIdx.x; i < 1024; i += 256){
    float4 v = p[i];
    s  += v.x + v.y + v.z + v.w;
    ss += v.x*v.x + v.y*v.y + v.z*v.z + v.w*v.w;
  }
  for (int o = 32; o > 0; o >>= 1){ s += __shfl_down(s, o); ss += __shfl_down(ss, o); }
  __shared__ float ls[4], lss[4];
  int wv = threadIdx.x >> 6;
  if ((threadIdx.x & 63) == 0){ ls[wv] = s; lss[wv] = ss; }
  __syncthreads();
  if (threadIdx.x == 0){
    s = ls[0]+ls[1]+ls[2]+ls[3]; ss = lss[0]+lss[1]+lss[2]+lss[3];
    float m = s * (1.f/4096.f);
    float var = (ss - s*m) * (1.f/4095.f);
    mean[row] = m;
    rstd[row] = 1.f / sqrtf(var + 1e-5f);
  }
}

// merged fold for f (y=0) and g (y=1)
__global__ void foldw2_k(const float* __restrict__ fw, const float* __restrict__ fb,
                         const float* __restrict__ mQ, const float* __restrict__ rQ,
                         unsigned short* __restrict__ Wfh, unsigned short* __restrict__ Wfl,
                         float* __restrict__ bF,
                         const float* __restrict__ gw, const float* __restrict__ gb,
                         const float* __restrict__ mK, const float* __restrict__ rK,
                         unsigned short* __restrict__ Wgh, unsigned short* __restrict__ Wgl,
                         float* __restrict__ bG){
  int o = blockIdx.x;
  int g = blockIdx.y;
  const float* w    = g ? gw : fw;
  const float* bias = g ? gb : fb;
  const float* mean = g ? mK : mQ;
  const float* rstd = g ? rK : rQ;
  unsigned short* wh = g ? Wgh : Wfh;
  unsigned short* wl = g ? Wgl : Wfl;
  float* biasp = g ? bG : bF;
  const float* wr = w + (long)o * 512;
  float part = 0.f;
  for (int c = threadIdx.x; c < 512; c += 256){
    float wv = wr[c] * rstd[c];
    unsigned short h = f2bf(wv);
    wh[(o<<9)+c] = h;
    wl[(o<<9)+c] = f2bf(wv - bf2f(h));
    part += wv * mean[c];
  }
  __shared__ float red[256];
  red[threadIdx.x] = part; __syncthreads();
  for (int st = 128; st > 0; st >>= 1){
    if (threadIdx.x < st) red[threadIdx.x] += red[threadIdx.x + st];
    __syncthreads();
  }
  if (threadIdx.x == 0) biasp[o] = bias[o] - red[0];
}

__global__ void wsplit_k(const float* __restrict__ w,
                         unsigned short* __restrict__ wh, unsigned short* __restrict__ wl){
  int i = blockIdx.x * 256 + threadIdx.x;
  float v = w[i];
  unsigned short h = f2bf(v);
  wh[i] = h; wl[i] = f2bf(v - bf2f(h));
}

// ---------- merged 3-term conv GEMM: z=0 Q(fp16), z=1 K(fp16), z=2 V(bf16 triple) ----------
__global__ __launch_bounds__(512) void conv3all_k(
    const float* __restrict__ Xq, const float* __restrict__ Xk, const float* __restrict__ Xv,
    const unsigned short* __restrict__ WhQ, const unsigned short* __restrict__ WlQ, const float* __restrict__ bQ,
    const unsigned short* __restrict__ WhK, const unsigned short* __restrict__ WlK, const float* __restrict__ bK,
    const unsigned short* __restrict__ WhV, const unsigned short* __restrict__ WlV, const float* __restrict__ bV,
    unsigned short* __restrict__ Qf, unsigned short* __restrict__ Kf,
    unsigned short* __restrict__ vh, unsigned short* __restrict__ v2h, unsigned short* __restrict__ v2l)
{
  int ob = blockIdx.y, lb = blockIdx.x, z = blockIdx.z;
  const float* X = (z==0 ? Xq : z==1 ? Xk : Xv);
  const unsigned short* Wh = (z==0 ? WhQ : z==1 ? WhK : WhV);
  const unsigned short* Wl = (z==0 ? WlQ : z==1 ? WlK : WlV);
  const float* biasp = (z==0 ? bQ : z==1 ? bK : bV);

  __shared__ __align__(16) char csm[36864];
  typedef unsigned short (*XT)[64][72];
  XT Xh = (XT)csm;                 // [2][64][72]
  XT Xl = (XT)(csm + 18432);       // [2][64][72]

  int tid = threadIdx.x, w = tid >> 6, lane = tid & 63, lr = lane & 15, lg = lane >> 4;
  const unsigned short* WhB = Wh + (long)(ob*128 + w*16) * 512;
  const unsigned short* WlB = Wl + (long)(ob*128 + w*16) * 512;
  int sl = tid & 63, scg = tid >> 6;
  const float* Xg = X + (long)(scg*8)*4096 + lb*64 + sl;

  f32x4 acc[4] = {};
  float fA[8], fB[8];
  short8 wA0, wA1, wA2, wA3, wB0, wB1, wB2, wB3;

#define CV_XLOAD(F, CB) { _Pragma("unroll") for (int j=0;j<8;++j) F[j] = Xg[(long)((CB)*64 + j)*4096]; }
#define CV_XWRITE(BUF, F) { short8 hv, lv; _Pragma("unroll") for (int j=0;j<8;++j){ \
    unsigned short h_ = f2bf(F[j]); hv[j] = (short)h_; lv[j] = (short)f2bf(F[j] - bf2f(h_)); } \
    *(short8*)&Xh[BUF][sl][scg*8] = hv; *(short8*)&Xl[BUF][sl][scg*8] = lv; }
#define CV_WLOAD(W0,W1,W2,W3, CB) { \
    W0 = *(const short8*)(WhB + (long)lr*512 + (CB)*64 + lg*8); \
    W1 = *(const short8*)(WhB + (long)lr*512 + (CB)*64 + 32 + lg*8); \
    W2 = *(const short8*)(WlB + (long)lr*512 + (CB)*64 + lg*8); \
    W3 = *(const short8*)(WlB + (long)lr*512 + (CB)*64 + 32 + lg*8); }
#define CV_COMPUTE(BUF, W0,W1,W2,W3) { \
    _Pragma("unroll") for (int ct=0;ct<4;++ct){ \
      short8 bh = *(const short8*)&Xh[BUF][ct*16+lr][lg*8]; \
      short8 bl = *(const short8*)&Xl[BUF][ct*16+lr][lg*8]; \
      acc[ct] = MFMA(W0, bh, acc[ct], 0,0,0); \
      acc[ct] = MFMA(W2, bh, acc[ct], 0,0,0); \
      acc[ct] = MFMA(W0, bl, acc[ct], 0,0,0); } \
    _Pragma("unroll") for (int ct=0;ct<4;++ct){ \
      short8 bh = *(const short8*)&Xh[BUF][ct*16+lr][32+lg*8]; \
      short8 bl = *(const short8*)&Xl[BUF][ct*16+lr][32+lg*8]; \
      acc[ct] = MFMA(W1, bh, acc[ct], 0,0,0); \
      acc[ct] = MFMA(W3, bh, acc[ct], 0,0,0); \
      acc[ct] = MFMA(W1, bl, acc[ct], 0,0,0); } }

  CV_XLOAD(fA, 0); CV_XWRITE(0, fA);
  CV_XLOAD(fA, 1);
  CV_WLOAD(wA0,wA1,wA2,wA3, 0);
  __syncthreads();
  for (int cb = 0; cb < 8; cb += 2){
    if (cb+2 < 8) CV_XLOAD(fB, cb+2);
    CV_WLOAD(wB0,wB1,wB2,wB3, cb+1);
    CV_COMPUTE(0, wA0,wA1,wA2,wA3);
    CV_XWRITE(1, fA);
    __syncthreads();
    if (cb+3 < 8) CV_XLOAD(fA, cb+3);
    if (cb+2 < 8) CV_WLOAD(wA0,wA1,wA2,wA3, cb+2);
    CV_COMPUTE(1, wB0,wB1,wB2,wB3);
    if (cb+2 < 8) CV_XWRITE(0, fB);
    __syncthreads();
  }

  int o4 = ob*128 + w*16 + lg*4;
  float bv[4];
  #pragma unroll
  for (int r = 0; r < 4; ++r) bv[r] = biasp[o4 + r];
  if (z < 2){
    unsigned short* of = (z==0 ? Qf : Kf);
    #pragma unroll
    for (int ct = 0; ct < 4; ++ct){
      u16x4 ph;
      #pragma unroll
      for (int r = 0; r < 4; ++r) ph[r] = f2h(acc[ct][r] + bv[r]);
      long base = ((long)(lb*64 + ct*16 + lr)) * 512 + o4;
      *(u16x4*)(of + base) = ph;
    }
  } else {
    unsigned short sh_[16], s2h_[16], s2l_[16];
    #pragma unroll
    for (int ct = 0; ct < 4; ++ct)
      #pragma unroll
      for (int r = 0; r < 4; ++r){
        float y = acc[ct][r] + bv[r];
        unsigned short h = f2bf(y);
        float vhf = bf2f(h);
        float v2 = vhf * vhf;
        unsigned short h2 = f2bf(v2);
        unsigned short l2 = f2bf(v2 - bf2f(h2));
        sh_[ct*4+r] = h; s2h_[ct*4+r] = h2; s2l_[ct*4+r] = l2;
      }
    unsigned short* T = (unsigned short*)csm;   // [128][72]
#define CV_STORE(ARR, DST) { \
    __syncthreads(); \
    _Pragma("unroll") for (int ct=0;ct<4;++ct) \
      _Pragma("unroll") for (int r=0;r<4;++r) \
        T[(w*16+lg*4+r)*72 + ct*16+lr] = ARR[ct*4+r]; \
    __syncthreads(); \
    _Pragma("unroll") for (int s_=0;s_<2;++s_){ \
      int slot = tid + s_*512; int row = slot>>3, ch=(slot&7)*8; \
      *(short8*)(DST + (long)(ob*128+row)*4096 + lb*64 + ch) = *(const short8*)&T[row*72+ch]; } }
    CV_STORE(sh_,  vh);
    CV_STORE(s2h_, v2h);
    CV_STORE(s2l_, v2l);
#undef CV_STORE
  }
#undef CV_XLOAD
#undef CV_XWRITE
#undef CV_WLOAD
#undef CV_COMPUTE
}

// ---------- 1-term fp16 S GEMM: 128q x 128k tile, S stored as fp16 ----------
__global__ __launch_bounds__(512, 4) void sgemm1h_k(
    const unsigned short* __restrict__ Qf, const unsigned short* __restrict__ Kf,
    unsigned short* __restrict__ S)
{
  int bx = blockIdx.x, by = blockIdx.y;
  int q0g = bx*128, k0 = by*128;
  __shared__ unsigned short Qs[128][64], Ks[128][64];
  int tid = threadIdx.x, w = tid >> 6, lane = tid & 63, lr = lane & 15, lg = lane >> 4;
  int wr = w & 1, wc = w >> 1;
  int srow = tid >> 3, sch = (tid & 7)*8;
  int swu = ((tid & 7) ^ (srow & 7)) * 8;
  int lr7 = lr & 7;
  short8 qr0, qr1, kr0, kr1;
  f32x4 acc[4][2] = {};

#define SG_LOAD(CB) { long c0_ = (long)(CB)*64 + sch; \
    qr0 = *(const short8*)(Qf + (long)(q0g + srow)*512 + c0_); \
    qr1 = *(const short8*)(Qf + (long)(q0g + srow + 64)*512 + c0_); \
    kr0 = *(const short8*)(Kf + (long)(k0 + srow)*512 + c0_); \
    kr1 = *(const short8*)(Kf + (long)(k0 + srow + 64)*512 + c0_); }
#define SG_WRITE { \
    *(short8*)&Qs[srow][swu] = qr0; *(short8*)&Qs[srow + 64][swu] = qr1; \
    *(short8*)&Ks[srow][swu] = kr0; *(short8*)&Ks[srow + 64][swu] = kr1; }

  SG_LOAD(0); SG_WRITE;
  __syncthreads();
  for (int cb = 0; cb < 8; ++cb){
    if (cb < 7) SG_LOAD(cb+1);
    #pragma unroll
    for (int kk = 0; kk < 2; ++kk){
      int un = ((kk*4 + lg) ^ lr7) * 8;
      short8 bh[2];
      #pragma unroll
      for (int bs = 0; bs < 2; ++bs)
        bh[bs] = *(const short8*)(&Ks[wc*32 + bs*16 + lr][un]);
      #pragma unroll
      for (int as = 0; as < 4; ++as){
        short8 ah = *(const short8*)(&Qs[wr*64 + as*16 + lr][un]);
        #pragma unroll
        for (int bs = 0; bs < 2; ++bs)
          acc[as][bs] = MFMAH(ah, bh[bs], acc[as][bs], 0,0,0);
      }
    }
    __syncthreads();
    if (cb < 7){ SG_WRITE; __syncthreads(); }
  }
#undef SG_LOAD
#undef SG_WRITE
  #pragma unroll
  for (int as = 0; as < 4; ++as){
    #pragma unroll
    for (int bs = 0; bs < 2; ++bs){
      int q = q0g + wr*64 + as*16 + lg*4;
      int k = k0 + wc*32 + bs*16 + lr;
      unsigned short* Sp = S + (long)q*4096 + k;
      #pragma unroll
      for (int r = 0; r < 4; ++r) Sp[(long)r*4096] = f2h(acc[as][bs][r]);
    }
  }
}

// ---------- row softmax: read fp16 S, write bf16 P IN PLACE; exact renorm ----------
__global__ __launch_bounds__(256) void softmax_k(unsigned short* __restrict__ SP,
                                                 float* __restrict__ inv2){
  int row = blockIdx.x;
  unsigned short* Sr = SP + (long)row * 4096;
  int t = threadIdx.x;
  short8 a = *(const short8*)(Sr + t*8);
  short8 b = *(const short8*)(Sr + 2048 + t*8);
  float v[16];
  #pragma unroll
  for (int j = 0; j < 8; ++j){ v[j] = h2f((unsigned short)a[j]); v[8+j] = h2f((unsigned short)b[j]); }
  float mx = v[0];
  #pragma unroll
  for (int i = 1; i < 16; ++i) mx = fmaxf(mx, v[i]);
  #pragma unroll
  for (int o = 32; o > 0; o >>= 1) mx = fmaxf(mx, __shfl_xor(mx, o));
  __shared__ float red[4];
  int wid = t >> 6;
  if ((t & 63) == 0) red[wid] = mx;
  __syncthreads();
  mx = fmaxf(fmaxf(red[0], red[1]), fmaxf(red[2], red[3]));
  __syncthreads();
  float p[16]; float d = 0.f;
  #pragma unroll
  for (int i = 0; i < 16; ++i){ float e = expf(v[i] - mx); p[i] = e; d += e; }
  #pragma unroll
  for (int o = 32; o > 0; o >>= 1) d += __shfl_xor(d, o);
  if ((t & 63) == 0) red[wid] = d;
  __syncthreads();
  d = red[0] + red[1] + red[2] + red[3];
  __syncthreads();
  float invd = 1.f / d;
  unsigned short pb[16]; float d2 = 0.f;
  #pragma unroll
  for (int i = 0; i < 16; ++i){ pb[i] = f2bf(p[i] * invd); d2 += bf2f(pb[i]); }
  #pragma unroll
  for (int o = 32; o > 0; o >>= 1) d2 += __shfl_xor(d2, o);
  if ((t & 63) == 0) red[wid] = d2;
  __syncthreads();
  if (t == 0) inv2[row] = 1.f / (red[0]+red[1]+red[2]+red[3]);
  short8 pa, pbv;
  #pragma unroll
  for (int j = 0; j < 8; ++j){ pa[j] = (short)pb[j]; pbv[j] = (short)pb[8+j]; }
  *(short8*)(Sr + t*8) = pa;
  *(short8*)(Sr + 2048 + t*8) = pbv;
}

// ---------- PV GEMM + epilogue: split-stage interleave (issue 4 loads, kk0, 4 loads, kk1) ----------
__global__ __launch_bounds__(256, 2) void pv2_k(
    const unsigned short* __restrict__ P, long ppitch,
    const unsigned short* __restrict__ vh,
    const unsigned short* __restrict__ v2h, const unsigned short* __restrict__ v2l,
    const float* __restrict__ inv2,
    const float* __restrict__ cx, const float* __restrict__ mcx, const float* __restrict__ rcx,
    float* __restrict__ outb)
{
  __shared__ __align__(16) char smem[65536];            // 64 KB
  typedef unsigned short (*PlT)[64][64];
  typedef unsigned short (*VlT)[3][64][64];
  PlT Pl = (PlT)smem;
  VlT Vl = (VlT)(smem + 16384);
  float* R = (float*)smem;

  int tid = threadIdx.x;
  int l = tid & 63, w = tid >> 6;
  int wq = w >> 1, wv = w & 1;
  int lr = l & 15, lg = l >> 4;
  int qP0 = blockIdx.x*64, qG0 = blockIdx.x*64;
  int vc0 = blockIdx.y*64;

  int r8_ = l >> 3, c8 = (l & 7)*8;
  int srcc = c8 ^ (r8_*8);
  const unsigned short* gsrc;
  long rs8;
  unsigned short *l0, *l1;
  if (w == 0){
    gsrc = P + (long)(qP0 + r8_)*ppitch + srcc;
    rs8 = (long)8*ppitch;
    l0 = &Pl[0][0][0]; l1 = &Pl[1][0][0];
  } else {
    const unsigned short* va = (w==1 ? vh : w==2 ? v2h : v2l);
    gsrc = va + (long)(vc0 + r8_)*4096 + srcc;
    rs8 = (long)8*4096;
    l0 = &Vl[0][w-1][0][0]; l1 = &Vl[1][w-1][0][0];
  }

  f32x4 accM[2][2] = {}, acc2[2][2] = {};

#define PV_STAGE_J(LB, TT, J0, J1) { long ko_ = (long)(TT)*64; \
    _Pragma("unroll") for (int j = J0; j < J1; ++j) \
      gload16(gsrc + j*rs8 + ko_, LB + j*512); }
#define PV_COMPUTE_KK(BUF, KK) { \
    int un = (((KK)*4 + lg) ^ (lr & 7)) * 8; \
    short8 fh[2], f2h_[2], f2l_[2]; \
    _Pragma("unroll") for (int bs = 0; bs < 2; ++bs){ \
      int vrow = wv*32 + bs*16 + lr; \
      fh[bs]   = *(const short8*)(&Vl[BUF][0][vrow][un]); \
      f2h_[bs] = *(const short8*)(&Vl[BUF][1][vrow][un]); \
      f2l_[bs] = *(const short8*)(&Vl[BUF][2][vrow][un]); } \
    _Pragma("unroll") for (int aq = 0; aq < 2; ++aq){ \
      short8 pa = *(const short8*)(&Pl[BUF][wq*32 + aq*16 + lr][un]); \
      _Pragma("unroll") for (int bs = 0; bs < 2; ++bs){ \
        accM[aq][bs] = MFMA(pa, fh[bs],   accM[aq][bs], 0,0,0); \
        acc2[aq][bs] = MFMA(pa, f2h_[bs], acc2[aq][bs], 0,0,0); \
        acc2[aq][bs] = MFMA(pa, f2l_[bs], acc2[aq][bs], 0,0,0); } } }

  PV_STAGE_J(l0, 0, 0, 8);
  __syncthreads();
  for (int t = 0; t < 64; ++t){
    unsigned short* nb = (t & 1) ? l0 : l1;
    int buf = t & 1;
    if (t < 63) PV_STAGE_J(nb, t+1, 0, 4);
    PV_COMPUTE_KK(buf, 0);
    if (t < 63) PV_STAGE_J(nb, t+1, 4, 8);
    PV_COMPUTE_KK(buf, 1);
    __syncthreads();
  }
#undef PV_STAGE_J
#undef PV_COMPUTE_KK

  float* Tm = R;
  #pragma unroll
  for (int aq = 0; aq < 2; ++aq)
    #pragma unroll
    for (int bs = 0; bs < 2; ++bs){
      int vcl = wv*32 + bs*16 + lr;
      int ql  = wq*32 + aq*16 + lg*4;
      #pragma unroll
      for (int r = 0; r < 4; ++r) Tm[vcl*68 + ql + r] = accM[aq][bs][r];
    }
  __syncthreads();
  f32x4 Mv[4];
  #pragma unroll
  for (int p = 0; p < 4; ++p){
    int chunk = tid + p*256;
    int row = chunk >> 4, c4 = (chunk & 15)*4;
    Mv[p] = *(const f32x4*)&Tm[row*68 + c4];
  }
  __syncthreads();
  #pragma unroll
  for (int aq = 0; aq < 2; ++aq)
    #pragma unroll
    for (int bs = 0; bs < 2; ++bs){
      int vcl = wv*32 + bs*16 + lr;
      int ql  = wq*32 + aq*16 + lg*4;
      #pragma unroll
      for (int r = 0; r < 4; ++r) Tm[vcl*68 + ql + r] = acc2[aq][bs][r];
    }
  __syncthreads();
  #pragma unroll
  for (int p = 0; p < 4; ++p){
    int chunk = tid + p*256;
    int row = chunk >> 4, c4 = (chunk & 15)*4;
    float mu = mcx[vc0 + row], rs = rcx[vc0 + row];
    f32x4 t2 = *(const f32x4*)&Tm[row*68 + c4];
    f32x4 iv = *(const f32x4*)&inv2[qP0 + c4];
    f32x4 cv = *(const f32x4*)&cx[(long)(vc0+row)*4096 + qG0 + c4];
    f32x4 ov;
    #pragma unroll
    for (int j = 0; j < 4; ++j){
      float M = Mv[p][j]*iv[j], M2 = t2[j]*iv[j];
      float var = M2 - M*M;
      float sd = sqrtf(fmaxf(var, 0.f));
      ov[j] = sd*(cv[j]-mu)*rs + M;
    }
    *(f32x4*)&outb[(long)(vc0+row)*4096 + qG0 + c4] = ov;
  }
}

// ---------- launch ----------
extern "C" void kernel_launch(void* const* d_in, const int* in_sizes, int n_in,
                              void* d_out, int out_size, void* d_ws, size_t ws_size,
                              hipStream_t stream){
  const float* c_x  = (const float*)d_in[0];
  const float* s_x  = (const float*)d_in[1];
  const float* c_1x = (const float*)d_in[2];
  const float* s_1x = (const float*)d_in[3];
  const float* f_w  = (const float*)d_in[4];
  const float* f_b  = (const float*)d_in[5];
  const float* g_w  = (const float*)d_in[6];
  const float* g_b  = (const float*)d_in[7];
  const float* h_w  = (const float*)d_in[8];
  const float* h_b  = (const float*)d_in[9];
  float* out = (float*)d_out;

  char* ws = (char*)d_ws;
  size_t off = 0;
  auto alloc = [&](size_t bytes)->void*{
    void* p = ws + off; off += (bytes + 255) & ~(size_t)255; return p;
  };
  float* meanQ = (float*)alloc(2048*4); float* rstdQ = (float*)alloc(2048*4);
  float* meanK = (float*)alloc(2048*4); float* rstdK = (float*)alloc(2048*4);
  float* meanC = (float*)alloc(2048*4); float* rstdC = (float*)alloc(2048*4);
  float* biasF = (float*)alloc(512*4);  float* biasG = (float*)alloc(512*4);
  unsigned short* Wfh = (unsigned short*)alloc((size_t)512*512*2);
  unsigned short* Wfl = (unsigned short*)alloc((size_t)512*512*2);
  unsigned short* Wgh = (unsigned short*)alloc((size_t)512*512*2);
  unsigned short* Wgl = (unsigned short*)alloc((size_t)512*512*2);
  unsigned short* Whh = (unsigned short*)alloc((size_t)512*512*2);
  unsigned short* Whl = (unsigned short*)alloc((size_t)512*512*2);
  unsigned short* Qf = (unsigned short*)alloc((size_t)4096*512*2);   // fp16
  unsigned short* Kf = (unsigned short*)alloc((size_t)4096*512*2);   // fp16
  unsigned short* vh  = (unsigned short*)alloc((size_t)512*4096*2);
  unsigned short* v2h = (unsigned short*)alloc((size_t)512*4096*2);
  unsigned short* v2l = (unsigned short*)alloc((size_t)512*4096*2);
  unsigned short* S   = (unsigned short*)alloc((size_t)4096*4096*2); // fp16 S; bf16 P in place
  float* inv2 = (float*)alloc(4096*4);
  // total ws ~58 MB

  rowstats3_k<<<dim3(2048,3), 256, 0, stream>>>(c_1x, meanQ, rstdQ,
                                                s_1x, meanK, rstdK,
                                                c_x,  meanC, rstdC);
  wsplit_k<<<1024, 256, 0, stream>>>(h_w, Whh, Whl);

  for (int b = 0; b < 4; ++b){
    long xoff = (long)b * 512 * 4096;
    foldw2_k<<<dim3(512,2), 256, 0, stream>>>(f_w, f_b, meanQ + b*512, rstdQ + b*512, Wfh, Wfl, biasF,
                                              g_w, g_b, meanK + b*512, rstdK + b*512, Wgh, Wgl, biasG);
    conv3all_k<<<dim3(64,4,3), 512, 0, stream>>>(c_1x + xoff, s_1x + xoff, s_x + xoff,
                                                 Wfh, Wfl, biasF,
                                                 Wgh, Wgl, biasG,
                                                 Whh, Whl, h_b,
                                                 Qf, Kf, vh, v2h, v2l);
    sgemm1h_k<<<dim3(32,32), 512, 0, stream>>>(Qf, Kf, S);
    softmax_k<<<4096, 256, 0, stream>>>(S, inv2);
    pv2_k<<<dim3(64,8), 256, 0, stream>>>(S, 4096, vh, v2h, v2l, inv2,
                                          c_x + xoff, meanC + b*512, rstdC + b*512,
                                          out + xoff);
  }
}